// Round 6
// baseline (890.076 us; speedup 1.0000x reference)
//
#include <hip/hip_runtime.h>

#define BB 2
#define SS 1024
#define DD 1024
#define HH 16
#define KVH 4
#define HDD 64
#define EE 16
#define II 1408
#define TT (BB*SS)
#define EPS_ 1e-6f

typedef unsigned short u16;
typedef __bf16 bf16x8 __attribute__((ext_vector_type(8)));
typedef _Float16 f16x8 __attribute__((ext_vector_type(8)));
typedef float f32x4 __attribute__((ext_vector_type(4)));

__device__ __forceinline__ float wred_sum(float v) {
#pragma unroll
  for (int o = 32; o > 0; o >>= 1) v += __shfl_xor(v, o);
  return v;
}

__device__ __forceinline__ u16 f2b(float f) {
  __bf16 h = (__bf16)f;
  return __builtin_bit_cast(u16, h);
}

__device__ __forceinline__ bf16x8 ld_frag(const u16* p) {
  return __builtin_bit_cast(bf16x8, *(const uint4*)p);
}
__device__ __forceinline__ f16x8 ldh(const u16* p) {
  return __builtin_bit_cast(f16x8, *(const uint4*)p);
}

// fp16 split-2 with scaled residual: v ~= h0 + h1 * 2^-11 (error ~2^-22)
__device__ __forceinline__ void split2h(float v, u16* o0, u16* o1) {
  _Float16 a = (_Float16)v;
  float fa = (float)a;
  _Float16 b = (_Float16)((v - fa) * 2048.0f);
  *o0 = __builtin_bit_cast(u16, a);
  *o1 = __builtin_bit_cast(u16, b);
}

// ======== split-2 fp16 GEMM, BK=64, LDS pitch 72 u16 (144B rows: 16B-aligned,
// staging writes and frag reads are bank-conflict-free by construction) ========
#define GPRE64(RA_, RB_, FN_) \
  __shared__ __align__(16) u16 As0[(RA_)*72], As1[(RA_)*72]; \
  __shared__ __align__(16) u16 Bs0[(RB_)*72], Bs1[(RB_)*72]; \
  int tid = threadIdx.x, lane = tid & 63, wvi = tid >> 6; \
  int lr = lane & 15, lkc = lane >> 4; \
  f32x4 accm[4][FN_] = {}; f32x4 accx[4][FN_] = {};

#define GSTEP64(RA_, RB_, FN_, pA0, pA1, sA, pB0, pB1, sB, kk) { \
  uint4 la0[(RA_)/32], la1[(RA_)/32], lb0[(RB_)/32], lb1[(RB_)/32]; \
  _Pragma("unroll") \
  for (int i_ = 0; i_ < (RA_)/32; ++i_) { \
    int idx_ = tid + i_*256, r_ = idx_ >> 3, c_ = (idx_ & 7) * 8; \
    la0[i_] = *(const uint4*)((pA0) + (size_t)r_*(sA) + (kk) + c_); \
    la1[i_] = *(const uint4*)((pA1) + (size_t)r_*(sA) + (kk) + c_); } \
  _Pragma("unroll") \
  for (int i_ = 0; i_ < (RB_)/32; ++i_) { \
    int idx_ = tid + i_*256, r_ = idx_ >> 3, c_ = (idx_ & 7) * 8; \
    lb0[i_] = *(const uint4*)((pB0) + (size_t)r_*(sB) + (kk) + c_); \
    lb1[i_] = *(const uint4*)((pB1) + (size_t)r_*(sB) + (kk) + c_); } \
  __syncthreads(); \
  _Pragma("unroll") \
  for (int i_ = 0; i_ < (RA_)/32; ++i_) { \
    int idx_ = tid + i_*256, r_ = idx_ >> 3, c_ = (idx_ & 7) * 8; \
    *(uint4*)&As0[r_*72 + c_] = la0[i_]; \
    *(uint4*)&As1[r_*72 + c_] = la1[i_]; } \
  _Pragma("unroll") \
  for (int i_ = 0; i_ < (RB_)/32; ++i_) { \
    int idx_ = tid + i_*256, r_ = idx_ >> 3, c_ = (idx_ & 7) * 8; \
    *(uint4*)&Bs0[r_*72 + c_] = lb0[i_]; \
    *(uint4*)&Bs1[r_*72 + c_] = lb1[i_]; } \
  __syncthreads(); \
  _Pragma("unroll") \
  for (int ks_ = 0; ks_ < 2; ++ks_) { \
    f16x8 bq0[FN_], bq1[FN_]; \
    _Pragma("unroll") \
    for (int nf = 0; nf < FN_; ++nf) { \
      bq0[nf] = ldh(&Bs0[(wn + nf*16 + lr)*72 + ks_*32 + lkc*8]); \
      bq1[nf] = ldh(&Bs1[(wn + nf*16 + lr)*72 + ks_*32 + lkc*8]); } \
    _Pragma("unroll") \
    for (int fm = 0; fm < 4; ++fm) { \
      f16x8 a0 = ldh(&As0[(wm + fm*16 + lr)*72 + ks_*32 + lkc*8]); \
      f16x8 a1 = ldh(&As1[(wm + fm*16 + lr)*72 + ks_*32 + lkc*8]); \
      _Pragma("unroll") \
      for (int nf = 0; nf < FN_; ++nf) { \
        accm[fm][nf] = __builtin_amdgcn_mfma_f32_16x16x32_f16(a0, bq0[nf], accm[fm][nf], 0, 0, 0); \
        f32x4 cx = accx[fm][nf]; \
        cx = __builtin_amdgcn_mfma_f32_16x16x32_f16(a0, bq1[nf], cx, 0, 0, 0); \
        cx = __builtin_amdgcn_mfma_f32_16x16x32_f16(a1, bq0[nf], cx, 0, 0, 0); \
        accx[fm][nf] = cx; } } } }

#define CVAL(fm, nf, r) (accm[fm][nf][r] + accx[fm][nf][r] * 4.8828125e-4f)

// ---------------- rmsnorm with split-2 fp16 output ----------------
__global__ __launch_bounds__(256) void k_rmsnorm_split2(const float* __restrict__ x,
    const float* __restrict__ w, u16* __restrict__ o0, u16* __restrict__ o1) {
  int row = blockIdx.x, tid = threadIdx.x;
  float4 v = ((const float4*)(x + (size_t)row * DD))[tid];
  float ss = v.x*v.x + v.y*v.y + v.z*v.z + v.w*v.w;
  ss = wred_sum(ss);
  __shared__ float red[4];
  if ((tid & 63) == 0) red[tid >> 6] = ss;
  __syncthreads();
  float tot = red[0] + red[1] + red[2] + red[3];
  float sc = rsqrtf(tot * (1.0f / DD) + EPS_);
  float4 wv = ((const float4*)w)[tid];
  float vals[4] = {v.x*sc*wv.x, v.y*sc*wv.y, v.z*sc*wv.z, v.w*sc*wv.w};
  ushort4 s0, s1;
  split2h(vals[0], &s0.x, &s1.x);
  split2h(vals[1], &s0.y, &s1.y);
  split2h(vals[2], &s0.z, &s1.z);
  split2h(vals[3], &s0.w, &s1.w);
  size_t base = (size_t)row * DD + tid * 4;
  *(ushort4*)&o0[base] = s0;
  *(ushort4*)&o1[base] = s1;
}

// ---------------- transpose + split2: W[K][N] fp32 -> WT{0,1}[N][K] fp16 ----------------
__global__ __launch_bounds__(256) void k_transpose_split2(const float* __restrict__ Wm,
    u16* __restrict__ T0, u16* __restrict__ T1, int K, int N) {
  int n0 = blockIdx.x * 64, k0 = blockIdx.y * 64;
  __shared__ float tile[64][65];
  int tc = threadIdx.x & 15, tr = threadIdx.x >> 4;
#pragma unroll
  for (int kk = 0; kk < 64; kk += 16) {
    float4 v = *(const float4*)&Wm[(size_t)(k0 + kk + tr) * N + n0 + tc * 4];
    tile[kk + tr][tc*4+0] = v.x; tile[kk + tr][tc*4+1] = v.y;
    tile[kk + tr][tc*4+2] = v.z; tile[kk + tr][tc*4+3] = v.w;
  }
  __syncthreads();
#pragma unroll
  for (int nn = 0; nn < 64; nn += 16) {
    int n = nn + tr;
    ushort4 s0, s1;
    split2h(tile[tc*4+0][n], &s0.x, &s1.x);
    split2h(tile[tc*4+1][n], &s0.y, &s1.y);
    split2h(tile[tc*4+2][n], &s0.z, &s1.z);
    split2h(tile[tc*4+3][n], &s0.w, &s1.w);
    size_t base = (size_t)(n0 + n) * K + k0 + tc * 4;
    *(ushort4*)&T0[base] = s0;
    *(ushort4*)&T1[base] = s1;
  }
}

// ---------------- transpose to bf16 single plane: W[e][K][N] fp32 -> T[e][N][K] bf16 ----------------
__global__ __launch_bounds__(256) void k_transpose_bf16(const float* __restrict__ Wm,
    u16* __restrict__ T, int K, int N) {
  int n0 = blockIdx.x * 64, k0 = blockIdx.y * 64, e = blockIdx.z;
  const float* src = Wm + (size_t)e * K * N;
  u16* dst = T + (size_t)e * N * K;
  __shared__ float tile[64][65];
  int tc = threadIdx.x & 15, tr = threadIdx.x >> 4;
#pragma unroll
  for (int kk = 0; kk < 64; kk += 16) {
    float4 v = *(const float4*)&src[(size_t)(k0 + kk + tr) * N + n0 + tc * 4];
    tile[kk + tr][tc*4+0] = v.x; tile[kk + tr][tc*4+1] = v.y;
    tile[kk + tr][tc*4+2] = v.z; tile[kk + tr][tc*4+3] = v.w;
  }
  __syncthreads();
#pragma unroll
  for (int nn = 0; nn < 64; nn += 16) {
    int n = nn + tr;
    ushort4 s = make_ushort4(f2b(tile[tc*4+0][n]), f2b(tile[tc*4+1][n]),
                             f2b(tile[tc*4+2][n]), f2b(tile[tc*4+3][n]));
    *(ushort4*)&dst[(size_t)(n0 + n) * K + k0 + tc * 4] = s;
  }
}

// ---------------- fused QKV GEMM (split-2 fp16, 128x64 tile, BK=64) ----------------
__global__ __launch_bounds__(256) void k_qkv_s2(
    const u16* __restrict__ h0, const u16* __restrict__ h1,
    const u16* __restrict__ wqt0, const u16* __restrict__ wqt1,
    const u16* __restrict__ wkt0, const u16* __restrict__ wkt1,
    const u16* __restrict__ wvt0, const u16* __restrict__ wvt1,
    float* __restrict__ qb, float* __restrict__ kb, float* __restrict__ vb) {
  int nt = blockIdx.x, m0 = blockIdx.y * 128;
  const u16 *B0, *B1; float* Cm; int Nm, n0;
  if (nt < 16)      { B0 = wqt0; B1 = wqt1; Cm = qb; Nm = 1024; n0 = nt * 64; }
  else if (nt < 20) { B0 = wkt0; B1 = wkt1; Cm = kb; Nm = 256;  n0 = (nt - 16) * 64; }
  else              { B0 = wvt0; B1 = wvt1; Cm = vb; Nm = 256;  n0 = (nt - 20) * 64; }
  GPRE64(128, 64, 2)
  int wm = (wvi & 1) * 64, wn = (wvi >> 1) * 32;
  const u16* a0 = h0 + (size_t)m0 * 1024;
  const u16* a1 = h1 + (size_t)m0 * 1024;
  const u16* b0 = B0 + (size_t)n0 * 1024;
  const u16* b1 = B1 + (size_t)n0 * 1024;
  for (int kk = 0; kk < 1024; kk += 64) {
    GSTEP64(128, 64, 2, a0, a1, 1024, b0, b1, 1024, kk)
  }
#pragma unroll
  for (int fm = 0; fm < 4; ++fm)
#pragma unroll
    for (int nf = 0; nf < 2; ++nf)
#pragma unroll
      for (int r = 0; r < 4; ++r) {
        int row = m0 + wm + fm*16 + lkc*4 + r;
        Cm[(size_t)row * Nm + n0 + wn + nf*16 + lr] = CVAL(fm, nf, r);
      }
}

// ---------------- per-head q/k rmsnorm + rope -> split-2 fp16 ----------------
__global__ __launch_bounds__(256) void k_qknorm_rope_split2(
    const float* __restrict__ qb, const float* __restrict__ kb,
    const float* __restrict__ qnw, const float* __restrict__ knw,
    const float* __restrict__ cosb, const float* __restrict__ sinb,
    u16* __restrict__ q0a, u16* __restrict__ q1a,
    u16* __restrict__ k0a, u16* __restrict__ k1a) {
  int tok = blockIdx.x, grp = blockIdx.y;
  int wv = threadIdx.x >> 6, d = threadIdx.x & 63;
  int s = tok & (SS - 1);
  const float* ptr; const float* wn;
  if (grp < 4) { ptr = qb + (size_t)tok * 1024 + (grp * 4 + wv) * 64; wn = qnw; }
  else         { ptr = kb + (size_t)tok * 256 + wv * 64;              wn = knw; }
  float v = ptr[d];
  float ssum = wred_sum(v * v);
  float rms = rsqrtf(ssum * (1.0f / 64.0f) + EPS_);
  float nv = v * rms * wn[d];
  float pn = __shfl_xor(nv, 32);
  float rot = (d < 32) ? -pn : pn;
  float val = nv * cosb[s * 64 + d] + rot * sinb[s * 64 + d];
  u16 a, b;
  split2h(val, &a, &b);
  if (grp < 4) {
    size_t idx = (size_t)tok * 1024 + (grp * 4 + wv) * 64 + d;
    q0a[idx] = a; q1a[idx] = b;
  } else {
    size_t idx = (size_t)tok * 256 + wv * 64 + d;
    k0a[idx] = a; k1a[idx] = b;
  }
}

// ---------------- v transpose + split2 ----------------
__global__ __launch_bounds__(256) void k_splitv2(const float* __restrict__ vb,
    u16* __restrict__ t0, u16* __restrict__ t1) {
  int k0 = blockIdx.x * 64, bkv = blockIdx.y;
  int b = bkv >> 2, kv = bkv & 3;
  __shared__ float tile[64][65];
  int tc = threadIdx.x & 15, tr = threadIdx.x >> 4;
#pragma unroll
  for (int kk = 0; kk < 64; kk += 16) {
    float4 v = *(const float4*)&vb[(size_t)(b * 1024 + k0 + kk + tr) * 256 + kv * 64 + tc * 4];
    tile[kk + tr][tc*4+0] = v.x; tile[kk + tr][tc*4+1] = v.y;
    tile[kk + tr][tc*4+2] = v.z; tile[kk + tr][tc*4+3] = v.w;
  }
  __syncthreads();
#pragma unroll
  for (int dd = 0; dd < 64; dd += 16) {
    int d = dd + tr;
    ushort4 s0, s1;
    split2h(tile[tc*4+0][d], &s0.x, &s1.x);
    split2h(tile[tc*4+1][d], &s0.y, &s1.y);
    split2h(tile[tc*4+2][d], &s0.z, &s1.z);
    split2h(tile[tc*4+3][d], &s0.w, &s1.w);
    size_t base = (size_t)(bkv * 64 + d) * 1024 + k0 + tc * 4;
    *(ushort4*)&t0[base] = s0;
    *(ushort4*)&t1[base] = s1;
  }
}

// ---------------- scores (split-2 fp16, 128x128 tile, K=64 single step) ----------------
__global__ __launch_bounds__(256) void k_scores_s2(
    const u16* __restrict__ q0a, const u16* __restrict__ q1a,
    const u16* __restrict__ k0a, const u16* __restrict__ k1a,
    float* __restrict__ sc, int bh0) {
  int kt = blockIdx.x, qt = blockIdx.y;
  if (kt > qt) return;
  int bh = bh0 + blockIdx.z, b = bh >> 4, hh = bh & 15, kv = hh >> 2;
  int q0 = qt * 128, kk0 = kt * 128;
  GPRE64(128, 128, 4)
  int wm = (wvi & 1) * 64, wn = (wvi >> 1) * 64;
  const u16* a0 = q0a + (size_t)(b * 1024 + q0) * 1024 + hh * 64;
  const u16* a1 = q1a + (size_t)(b * 1024 + q0) * 1024 + hh * 64;
  const u16* b0 = k0a + (size_t)(b * 1024 + kk0) * 256 + kv * 64;
  const u16* b1 = k1a + (size_t)(b * 1024 + kk0) * 256 + kv * 64;
  GSTEP64(128, 128, 4, a0, a1, 1024, b0, b1, 256, 0)
  float* srow = sc + (size_t)blockIdx.z * SS * SS;
#pragma unroll
  for (int fm = 0; fm < 4; ++fm)
#pragma unroll
    for (int nf = 0; nf < 4; ++nf)
#pragma unroll
      for (int r = 0; r < 4; ++r) {
        int row = q0 + wm + fm*16 + lkc*4 + r;
        srow[(size_t)row * SS + kk0 + wn + nf*16 + lr] = CVAL(fm, nf, r) * 0.125f;
      }
}

// ---------------- row softmax -> split-2 fp16 P ----------------
__global__ __launch_bounds__(256) void k_softmax_split2(const float* __restrict__ sc,
    u16* __restrict__ P0, u16* __restrict__ P1) {
  int q = blockIdx.x, z = blockIdx.y, tid = threadIdx.x;
  const float* row = sc + (size_t)z * SS * SS + (size_t)q * SS;
  int n = q + 1, i4 = tid * 4;
  float4 v4 = ((const float4*)row)[tid];
  float vv[4] = {v4.x, v4.y, v4.z, v4.w};
  float m = -3.4e38f;
#pragma unroll
  for (int j = 0; j < 4; ++j) if (i4 + j < n) m = fmaxf(m, vv[j]);
#pragma unroll
  for (int o = 32; o > 0; o >>= 1) m = fmaxf(m, __shfl_xor(m, o));
  __shared__ float redm[4], reds[4];
  if ((tid & 63) == 0) redm[tid >> 6] = m;
  __syncthreads();
  m = fmaxf(fmaxf(redm[0], redm[1]), fmaxf(redm[2], redm[3]));
  float e[4]; float l = 0.f;
#pragma unroll
  for (int j = 0; j < 4; ++j) {
    e[j] = (i4 + j < n) ? __expf(vv[j] - m) : 0.f;
    l += e[j];
  }
  l = wred_sum(l);
  if ((tid & 63) == 0) reds[tid >> 6] = l;
  __syncthreads();
  l = reds[0] + reds[1] + reds[2] + reds[3];
  float inv = 1.0f / l;
  ushort4 s0, s1;
  split2h(e[0] * inv, &s0.x, &s1.x);
  split2h(e[1] * inv, &s0.y, &s1.y);
  split2h(e[2] * inv, &s0.z, &s1.z);
  split2h(e[3] * inv, &s0.w, &s1.w);
  size_t base = (size_t)z * 1048576 + (size_t)q * 1024 + i4;
  *(ushort4*)&P0[base] = s0;
  *(ushort4*)&P1[base] = s1;
}

// ---------------- PV K-split (128x64 tile, K-chunk=256) -> fp32 partials ----------------
__global__ __launch_bounds__(256) void k_pv_s2(
    const u16* __restrict__ P0, const u16* __restrict__ P1,
    const u16* __restrict__ vt0, const u16* __restrict__ vt1,
    float* __restrict__ pvp, int bh0) {
  int qt = blockIdx.x, z = blockIdx.y, kc = blockIdx.z;
  if (kc * 256 >= (qt + 1) * 128) return;
  int bh = bh0 + z, b = bh >> 4, hh = bh & 15, kv = hh >> 2;
  int bkv = b * 4 + kv;
  int q0 = qt * 128;
  GPRE64(128, 64, 2)
  int wm = (wvi & 1) * 64, wn = (wvi >> 1) * 32;
  const u16* a0 = P0 + (size_t)z * 1048576 + (size_t)q0 * 1024;
  const u16* a1 = P1 + (size_t)z * 1048576 + (size_t)q0 * 1024;
  const u16* b0 = vt0 + (size_t)(bkv * 64) * 1024;
  const u16* b1 = vt1 + (size_t)(bkv * 64) * 1024;
  int kbase = kc * 256;
  for (int kk = kbase; kk < kbase + 256; kk += 64) {
    GSTEP64(128, 64, 2, a0, a1, 1024, b0, b1, 1024, kk)
  }
  float* op = pvp + (size_t)((z * 8 + qt) * 4 + kc) * 8192;
#pragma unroll
  for (int fm = 0; fm < 4; ++fm)
#pragma unroll
    for (int nf = 0; nf < 2; ++nf)
#pragma unroll
      for (int r = 0; r < 4; ++r)
        op[(wm + fm*16 + lkc*4 + r) * 64 + wn + nf*16 + lr] = CVAL(fm, nf, r);
}

// ---------------- PV reduce over k-chunks + split2 store into at0/at1 ----------------
__global__ __launch_bounds__(256) void k_pv_reduce(const float* __restrict__ pvp,
    u16* __restrict__ at0, u16* __restrict__ at1, int bh0) {
  int qt = blockIdx.x, z = blockIdx.y, tid = threadIdx.x;
  int bh = bh0 + z, b = bh >> 4, hh = bh & 15;
  int nkc = (qt + 2) >> 1;
  const float* base = pvp + (size_t)((z * 8 + qt) * 4) * 8192;
#pragma unroll
  for (int t = 0; t < 8; ++t) {
    int lin = t * 256 + tid;
    int row = lin >> 4, c4 = (lin & 15) * 4;
    float4 s = *(const float4*)&base[row * 64 + c4];
    for (int kc = 1; kc < nkc; ++kc) {
      float4 v = *(const float4*)&base[(size_t)kc * 8192 + row * 64 + c4];
      s.x += v.x; s.y += v.y; s.z += v.z; s.w += v.w;
    }
    ushort4 s0, s1;
    split2h(s.x, &s0.x, &s1.x);
    split2h(s.y, &s0.y, &s1.y);
    split2h(s.z, &s0.z, &s1.z);
    split2h(s.w, &s0.w, &s1.w);
    size_t idx = (size_t)(b * 1024 + qt * 128 + row) * 1024 + hh * 64 + c4;
    *(ushort4*)&at0[idx] = s0;
    *(ushort4*)&at1[idx] = s1;
  }
}

// ---------------- Wo GEMM + residual (split-2 fp16, 128x64, BK=64) ----------------
__global__ __launch_bounds__(256) void k_wo_s2(
    const u16* __restrict__ at0, const u16* __restrict__ at1,
    const u16* __restrict__ wot0, const u16* __restrict__ wot1,
    const float* __restrict__ x, float* __restrict__ x2) {
  int n0 = blockIdx.x * 64, m0 = blockIdx.y * 128;
  GPRE64(128, 64, 2)
  int wm = (wvi & 1) * 64, wn = (wvi >> 1) * 32;
  const u16* a0 = at0 + (size_t)m0 * 1024;
  const u16* a1 = at1 + (size_t)m0 * 1024;
  const u16* b0 = wot0 + (size_t)n0 * 1024;
  const u16* b1 = wot1 + (size_t)n0 * 1024;
  for (int kk = 0; kk < 1024; kk += 64) {
    GSTEP64(128, 64, 2, a0, a1, 1024, b0, b1, 1024, kk)
  }
#pragma unroll
  for (int fm = 0; fm < 4; ++fm)
#pragma unroll
    for (int nf = 0; nf < 2; ++nf)
#pragma unroll
      for (int r = 0; r < 4; ++r) {
        int row = m0 + wm + fm*16 + lkc*4 + r;
        int col = n0 + wn + nf*16 + lr;
        x2[(size_t)row * 1024 + col] = CVAL(fm, nf, r) + x[(size_t)row * 1024 + col];
      }
}

// ---------------- fused: rmsnorm(x2) -> tbh(bf16) + router logits (exact r2 arithmetic) ----------------
__global__ __launch_bounds__(256) void k_rmsnorm_logits(const float* __restrict__ x2,
    const float* __restrict__ w, const float* __restrict__ rw,
    u16* __restrict__ tbh, float* __restrict__ logits) {
  int row = blockIdx.x, tid = threadIdx.x;
  __shared__ __align__(16) float tl[1024];
  __shared__ float part[16][16];
  __shared__ float red[4];
  float4 v = ((const float4*)(x2 + (size_t)row * DD))[tid];
  float ss = v.x*v.x + v.y*v.y + v.z*v.z + v.w*v.w;
  ss = wred_sum(ss);
  if ((tid & 63) == 0) red[tid >> 6] = ss;
  __syncthreads();
  float tot = red[0] + red[1] + red[2] + red[3];
  float sc = rsqrtf(tot * (1.0f / DD) + EPS_);
  float4 wv = ((const float4*)w)[tid];
  float4 o = make_float4(v.x*sc*wv.x, v.y*sc*wv.y, v.z*sc*wv.z, v.w*sc*wv.w);
  ((float4*)tl)[tid] = o;
  ushort4 hb = make_ushort4(f2b(o.x), f2b(o.y), f2b(o.z), f2b(o.w));
  *(ushort4*)&tbh[(size_t)row * DD + tid * 4] = hb;
  __syncthreads();
  int e = tid & 15, ch = tid >> 4;
  float p = 0.f;
#pragma unroll 8
  for (int j = 0; j < 64; ++j) p = fmaf(tl[ch * 64 + j], rw[(ch * 64 + j) * EE + e], p);
  part[ch][e] = p;
  __syncthreads();
  if (tid < 16) {
    float s = 0.f;
#pragma unroll
    for (int c = 0; c < 16; ++c) s += part[c][tid];
    logits[(size_t)row * EE + tid] = s;
  }
}

// ---------------- route: softmax16 + top2 per thread ----------------
__global__ __launch_bounds__(256) void k_route(const float* __restrict__ logits,
    int* __restrict__ cnt, int* __restrict__ listTok, int* __restrict__ tokslot,
    float* __restrict__ topw, float* __restrict__ psum) {
  int tid = threadIdx.x;
  int tok = blockIdx.x * 256 + tid;
  __shared__ int lcnt[16], gbase[16];
  __shared__ float lps[16];
  if (tid < 16) { lcnt[tid] = 0; lps[tid] = 0.f; }
  __syncthreads();
  float pr[16];
#pragma unroll
  for (int g = 0; g < 4; ++g) {
    float4 v = *(const float4*)&logits[(size_t)tok * EE + g * 4];
    pr[g*4+0] = v.x; pr[g*4+1] = v.y; pr[g*4+2] = v.z; pr[g*4+3] = v.w;
  }
  float mx = pr[0];
#pragma unroll
  for (int i = 1; i < 16; ++i) mx = fmaxf(mx, pr[i]);
  float s = 0.f;
#pragma unroll
  for (int i = 0; i < 16; ++i) { pr[i] = __expf(pr[i] - mx); s += pr[i]; }
  float inv = 1.0f / s;
#pragma unroll
  for (int i = 0; i < 16; ++i) pr[i] *= inv;
  int i1 = 0; float v1 = pr[0];
#pragma unroll
  for (int i = 1; i < 16; ++i) if (pr[i] > v1) { v1 = pr[i]; i1 = i; }
  int i2 = -1; float v2 = -1.f;
#pragma unroll
  for (int i = 0; i < 16; ++i) if (i != i1 && pr[i] > v2) { v2 = pr[i]; i2 = i; }
  float wsum = v1 + v2;
  int lp1 = atomicAdd(&lcnt[i1], 1);
  int lp2 = atomicAdd(&lcnt[i2], 1);
#pragma unroll
  for (int e = 0; e < 16; ++e) {
    float v = wred_sum(pr[e]);
    if ((tid & 63) == 0) atomicAdd(&lps[e], v);
  }
  __syncthreads();
  if (tid < 16) {
    gbase[tid] = atomicAdd(&cnt[tid], lcnt[tid]);
    atomicAdd(&psum[tid], lps[tid]);
  }
  __syncthreads();
  int p1 = gbase[i1] + lp1, p2 = gbase[i2] + lp2;
  listTok[i1 * 2048 + p1] = tok;
  listTok[i2 * 2048 + p2] = tok;
  tokslot[tok * 2 + 0] = i1 * 2048 + p1;
  tokslot[tok * 2 + 1] = i2 * 2048 + p2;
  topw[tok * 2 + 0] = v1 / wsum;
  topw[tok * 2 + 1] = v2 / wsum;
}

__global__ void k_zero(int* cnt, float* psum) {
  int t = threadIdx.x;
  if (t < 16) { cnt[t] = 0; psum[t] = 0.f; }
}

__global__ void k_prefix(const int* __restrict__ cnt, int* __restrict__ offs) {
  if (threadIdx.x == 0) {
    int s = 0;
    for (int e = 0; e < 16; ++e) { offs[e] = s; s += cnt[e]; }
  }
}

// ---------------- MoE gate/up: bf16 pre-transposed weights, BK=64, pitch 72 ----------------
__global__ __launch_bounds__(256) void k_gu2(const u16* __restrict__ tbh,
    const u16* __restrict__ wgt, const u16* __restrict__ wut,
    const int* __restrict__ cnt, const int* __restrict__ offs,
    const int* __restrict__ listTok, u16* __restrict__ act) {
  int e = blockIdx.z, ce = cnt[e];
  int m0 = blockIdx.y * 128;
  if (m0 >= ce) return;
  int n0 = blockIdx.x * 64;
  __shared__ __align__(16) u16 As[128*72], Gs[64*72], Us[64*72];
  __shared__ int rows[128];
  int tid = threadIdx.x, lane = tid & 63, wvi = tid >> 6;
  int lr = lane & 15, lkc = lane >> 4;
  int wm = (wvi & 1) * 64, wn = (wvi >> 1) * 32;
  if (tid < 128) { int m = m0 + tid; rows[tid] = listTok[e * 2048 + (m < ce ? m : ce - 1)]; }
  __syncthreads();
  const u16* wge = wgt + (size_t)e * II * 1024 + (size_t)n0 * 1024;
  const u16* wue = wut + (size_t)e * II * 1024 + (size_t)n0 * 1024;
  f32x4 accg[4][2] = {}, accu[4][2] = {};
  for (int kk = 0; kk < 1024; kk += 64) {
    uint4 la[4], lg[2], lu[2];
#pragma unroll
    for (int i = 0; i < 4; ++i) {
      int idx = tid + i*256, r = idx >> 3, c = (idx & 7) * 8;
      la[i] = *(const uint4*)(tbh + (size_t)rows[r] * 1024 + kk + c);
    }
#pragma unroll
    for (int i = 0; i < 2; ++i) {
      int idx = tid + i*256, r = idx >> 3, c = (idx & 7) * 8;
      lg[i] = *(const uint4*)(wge + (size_t)r * 1024 + kk + c);
      lu[i] = *(const uint4*)(wue + (size_t)r * 1024 + kk + c);
    }
    __syncthreads();
#pragma unroll
    for (int i = 0; i < 4; ++i) {
      int idx = tid + i*256, r = idx >> 3, c = (idx & 7) * 8;
      *(uint4*)&As[r*72 + c] = la[i];
    }
#pragma unroll
    for (int i = 0; i < 2; ++i) {
      int idx = tid + i*256, r = idx >> 3, c = (idx & 7) * 8;
      *(uint4*)&Gs[r*72 + c] = lg[i];
      *(uint4*)&Us[r*72 + c] = lu[i];
    }
    __syncthreads();
#pragma unroll
    for (int ks = 0; ks < 2; ++ks) {
      bf16x8 bg[2], bu[2];
#pragma unroll
      for (int nf = 0; nf < 2; ++nf) {
        bg[nf] = ld_frag(&Gs[(wn + nf*16 + lr)*72 + ks*32 + lkc*8]);
        bu[nf] = ld_frag(&Us[(wn + nf*16 + lr)*72 + ks*32 + lkc*8]);
      }
#pragma unroll
      for (int fm = 0; fm < 4; ++fm) {
        bf16x8 a = ld_frag(&As[(wm + fm*16 + lr)*72 + ks*32 + lkc*8]);
#pragma unroll
        for (int nf = 0; nf < 2; ++nf) {
          accg[fm][nf] = __builtin_amdgcn_mfma_f32_16x16x32_bf16(a, bg[nf], accg[fm][nf], 0, 0, 0);
          accu[fm][nf] = __builtin_amdgcn_mfma_f32_16x16x32_bf16(a, bu[nf], accu[fm][nf], 0, 0, 0);
        }
      }
    }
  }
  int ob = offs[e];
#pragma unroll
  for (int fm = 0; fm < 4; ++fm)
#pragma unroll
    for (int nf = 0; nf < 2; ++nf)
#pragma unroll
      for (int r = 0; r < 4; ++r) {
        int m = m0 + wm + fm*16 + lkc*4 + r;
        if (m < ce) {
          float g = accg[fm][nf][r], u = accu[fm][nf][r];
          float sv = (g / (1.f + __expf(-g))) * u;
          act[(size_t)(ob + m) * II + n0 + wn + nf*16 + lr] = f2b(sv);
        }
      }
}

// ---------------- MoE down: act(bf16) @ wdt(bf16 [n][k]), K=1408 ----------------
__global__ __launch_bounds__(256) void k_down2(const u16* __restrict__ act,
    const u16* __restrict__ wdt, const int* __restrict__ cnt, const int* __restrict__ offs,
    float* __restrict__ eo) {
  int e = blockIdx.z, ce = cnt[e];
  int m0 = blockIdx.y * 128;
  if (m0 >= ce) return;
  int n0 = blockIdx.x * 64;
  __shared__ __align__(16) u16 As[128*72], Bs[64*72];
  int tid = threadIdx.x, lane = tid & 63, wvi = tid >> 6;
  int lr = lane & 15, lkc = lane >> 4;
  int wm = (wvi & 1) * 64, wn = (wvi >> 1) * 32;
  int ob = offs[e];
  const u16* wde = wdt + (size_t)e * 1024 * II + (size_t)n0 * II;
  f32x4 acc[4][2] = {};
  for (int kk = 0; kk < II; kk += 64) {
    uint4 la[4], lb[2];
#pragma unroll
    for (int i = 0; i < 4; ++i) {
      int idx = tid + i*256, r = idx >> 3, c = (idx & 7) * 8;
      int mr = m0 + r; if (mr >= ce) mr = ce - 1;
      la[i] = *(const uint4*)(act + (size_t)(ob + mr) * II + kk + c);
    }
#pragma unroll
    for (int i = 0; i < 2; ++i) {
      int idx = tid + i*256, r = idx >> 3, c = (idx & 7) * 8;
      lb[i] = *(const uint4*)(wde + (size_t)r * II + kk + c);
    }
    __syncthreads();
#pragma unroll
    for (int i = 0; i < 4; ++i) {
      int idx = tid + i*256, r = idx >> 3, c = (idx & 7) * 8;
      *(uint4*)&As[r*72 + c] = la[i];
    }
#pragma unroll
    for (int i = 0; i < 2; ++i) {
      int idx = tid + i*256, r = idx >> 3, c = (idx & 7) * 8;
      *(uint4*)&Bs[r*72 + c] = lb[i];
    }
    __syncthreads();
#pragma unroll
    for (int ks = 0; ks < 2; ++ks) {
      bf16x8 bb[2];
#pragma unroll
      for (int nf = 0; nf < 2; ++nf)
        bb[nf] = ld_frag(&Bs[(wn + nf*16 + lr)*72 + ks*32 + lkc*8]);
#pragma unroll
      for (int fm = 0; fm < 4; ++fm) {
        bf16x8 a = ld_frag(&As[(wm + fm*16 + lr)*72 + ks*32 + lkc*8]);
#pragma unroll
        for (int nf = 0; nf < 2; ++nf)
          acc[fm][nf] = __builtin_amdgcn_mfma_f32_16x16x32_bf16(a, bb[nf], acc[fm][nf], 0, 0, 0);
      }
    }
  }
#pragma unroll
  for (int fm = 0; fm < 4; ++fm)
#pragma unroll
    for (int nf = 0; nf < 2; ++nf)
#pragma unroll
      for (int r = 0; r < 4; ++r) {
        int m = m0 + wm + fm*16 + lkc*4 + r;
        if (m < ce)
          eo[(size_t)(ob + m) * 1024 + n0 + wn + nf*16 + lr] = acc[fm][nf][r];
      }
}

// ---------------- final combine ----------------
__global__ __launch_bounds__(256) void k_final(const float* __restrict__ x2,
    const float* __restrict__ eo, const int* __restrict__ tokslot,
    const float* __restrict__ topw, const int* __restrict__ offs, float* __restrict__ out) {
  int tok = blockIdx.x, tid = threadIdx.x;
  int c0 = tokslot[tok * 2], c1 = tokslot[tok * 2 + 1];
  int s0 = offs[c0 >> 11] + (c0 & 2047);
  int s1 = offs[c1 >> 11] + (c1 & 2047);
  float w0 = topw[tok * 2], w1 = topw[tok * 2 + 1];
  float4 a = ((const float4*)(x2 + (size_t)tok * DD))[tid];
  float4 e0 = ((const float4*)(eo + (size_t)s0 * DD))[tid];
  float4 e1 = ((const float4*)(eo + (size_t)s1 * DD))[tid];
  float4 o = make_float4(a.x + w0*e0.x + w1*e1.x, a.y + w0*e0.y + w1*e1.y,
                         a.z + w0*e0.z + w1*e1.z, a.w + w0*e0.w + w1*e1.w);
  ((float4*)(out + (size_t)tok * DD))[tid] = o;
}

__global__ void k_aux(const int* __restrict__ cnt, const float* __restrict__ psum,
                      float* __restrict__ out) {
  if (threadIdx.x == 0) {
    float a = 0.f;
    for (int e = 0; e < 16; ++e)
      a += ((float)cnt[e] * (1.0f / 4096.0f)) * (psum[e] * (1.0f / 2048.0f));
    out[(size_t)TT * DD] = 16.0f * a;
  }
}

extern "C" void kernel_launch(void* const* d_in, const int* in_sizes, int n_in,
                              void* d_out, int out_size, void* d_ws, size_t ws_size,
                              hipStream_t stream) {
  const float* x    = (const float*)d_in[0];
  const float* cosb = (const float*)d_in[1];
  const float* sinb = (const float*)d_in[2];
  const float* ln1w = (const float*)d_in[3];
  const float* wq   = (const float*)d_in[4];
  const float* wk   = (const float*)d_in[5];
  const float* wv   = (const float*)d_in[6];
  const float* wo   = (const float*)d_in[7];
  const float* qnw  = (const float*)d_in[8];
  const float* knw  = (const float*)d_in[9];
  const float* ln2w = (const float*)d_in[10];
  const float* rw   = (const float*)d_in[11];
  const float* wg   = (const float*)d_in[12];
  const float* wu   = (const float*)d_in[13];
  const float* wd   = (const float*)d_in[14];
  float* out = (float*)d_out;

  float* W = (float*)d_ws;
  int*   cnt     = (int*)W;
  int*   offs    = (int*)(W + 16);
  float* psum    = W + 32;
  int*   tokslot = (int*)(W + 64);
  float* topw    = W + 4160;
  int*   listTok = (int*)(W + 8256);
  float* logits  = W + 41024;
  size_t o = 81920;
#define ALLOC_F(name, n)   float* name = W + o; o += (n);
#define ALLOC_U16(name, n) u16* name = (u16*)(W + o); o += ((size_t)(n) + 1) / 2;
  ALLOC_U16(h0, 2097152) ALLOC_U16(h1, 2097152)
  ALLOC_F(qb, 2097152) ALLOC_F(kb, 524288) ALLOC_F(vb, 524288)
  ALLOC_U16(wqt0, 1048576) ALLOC_U16(wqt1, 1048576)
  ALLOC_U16(wkt0, 262144) ALLOC_U16(wkt1, 262144)
  ALLOC_U16(wvt0, 262144) ALLOC_U16(wvt1, 262144)
  ALLOC_U16(wot0, 1048576) ALLOC_U16(wot1, 1048576)
  ALLOC_U16(qs0, 2097152) ALLOC_U16(qs1, 2097152)
  ALLOC_U16(ks0, 524288) ALLOC_U16(ks1, 524288)
  ALLOC_U16(vt0, 524288) ALLOC_U16(vt1, 524288)
  ALLOC_U16(at0, 2097152) ALLOC_U16(at1, 2097152)
  ALLOC_F(x2, 2097152)
  ALLOC_U16(tbh, 2097152)
  ALLOC_U16(act, 5767168)
  ALLOC_F(eo, 4194304)
  ALLOC_U16(wgt, 23068672) ALLOC_U16(wut, 23068672) ALLOC_U16(wdt, 23068672)
  long avail = (long)(ws_size / 4) - (long)o;
  int NC = (int)(avail / 2359296L);   // per chunk: sc 1M f + P0,P1 (1M f) + pvp 0.25M f
  if (NC > 32) NC = 32;
  if (NC < 1) NC = 1;
  ALLOC_U16(P0, (size_t)NC * 1048576) ALLOC_U16(P1, (size_t)NC * 1048576)
  ALLOC_F(sc, (size_t)NC * 1048576)
  ALLOC_F(pvp, (size_t)NC * 262144)
#undef ALLOC_F
#undef ALLOC_U16

  k_zero<<<1, 64, 0, stream>>>(cnt, psum);
  k_rmsnorm_split2<<<TT, 256, 0, stream>>>(x, ln1w, h0, h1);
  k_transpose_split2<<<dim3(16, 16), 256, 0, stream>>>(wq, wqt0, wqt1, 1024, 1024);
  k_transpose_split2<<<dim3(4, 16), 256, 0, stream>>>(wk, wkt0, wkt1, 1024, 256);
  k_transpose_split2<<<dim3(4, 16), 256, 0, stream>>>(wv, wvt0, wvt1, 1024, 256);
  k_transpose_split2<<<dim3(16, 16), 256, 0, stream>>>(wo, wot0, wot1, 1024, 1024);
  k_qkv_s2<<<dim3(24, 16), 256, 0, stream>>>(h0, h1,
      wqt0, wqt1, wkt0, wkt1, wvt0, wvt1, qb, kb, vb);
  k_qknorm_rope_split2<<<dim3(TT, 5), 256, 0, stream>>>(qb, kb, qnw, knw, cosb, sinb,
      qs0, qs1, ks0, ks1);
  k_splitv2<<<dim3(16, 8), 256, 0, stream>>>(vb, vt0, vt1);
  for (int bh0 = 0; bh0 < 32; bh0 += NC) {
    int nc = 32 - bh0; if (nc > NC) nc = NC;
    k_scores_s2<<<dim3(8, 8, nc), 256, 0, stream>>>(qs0, qs1, ks0, ks1, sc, bh0);
    k_softmax_split2<<<dim3(SS, nc), 256, 0, stream>>>(sc, P0, P1);
    k_pv_s2<<<dim3(8, nc, 4), 256, 0, stream>>>(P0, P1, vt0, vt1, pvp, bh0);
    k_pv_reduce<<<dim3(8, nc), 256, 0, stream>>>(pvp, at0, at1, bh0);
  }
  k_wo_s2<<<dim3(16, 16), 256, 0, stream>>>(at0, at1, wot0, wot1, x, x2);
  k_rmsnorm_logits<<<TT, 256, 0, stream>>>(x2, ln2w, rw, tbh, logits);
  k_route<<<TT / 256, 256, 0, stream>>>(logits, cnt, listTok, tokslot, topw, psum);
  k_prefix<<<1, 1, 0, stream>>>(cnt, offs);
  k_transpose_bf16<<<dim3(22, 16, 16), 256, 0, stream>>>(wg, wgt, 1024, 1408);
  k_transpose_bf16<<<dim3(22, 16, 16), 256, 0, stream>>>(wu, wut, 1024, 1408);
  k_gu2<<<dim3(22, 16, 16), 256, 0, stream>>>(tbh, wgt, wut, cnt, offs, listTok, act);
  k_transpose_bf16<<<dim3(16, 22, 16), 256, 0, stream>>>(wd, wdt, 1408, 1024);
  k_down2<<<dim3(16, 16, 16), 256, 0, stream>>>(act, wdt, cnt, offs, eo);
  k_final<<<TT, 256, 0, stream>>>(x2, eo, tokslot, topw, offs, out);
  k_aux<<<1, 1, 0, stream>>>(cnt, psum, out);
}

// Round 7
// 686.705 us; speedup vs baseline: 1.2962x; 1.2962x over previous
//
#include <hip/hip_runtime.h>

#define BB 2
#define SS 1024
#define DD 1024
#define HH 16
#define KVH 4
#define HDD 64
#define EE 16
#define II 1408
#define TT (BB*SS)
#define EPS_ 1e-6f

typedef unsigned short u16;
typedef __bf16 bf16x8 __attribute__((ext_vector_type(8)));
typedef _Float16 f16x8 __attribute__((ext_vector_type(8)));
typedef float f32x4 __attribute__((ext_vector_type(4)));

__device__ __forceinline__ float wred_sum(float v) {
#pragma unroll
  for (int o = 32; o > 0; o >>= 1) v += __shfl_xor(v, o);
  return v;
}

__device__ __forceinline__ u16 f2b(float f) {
  __bf16 h = (__bf16)f;
  return __builtin_bit_cast(u16, h);
}

__device__ __forceinline__ bf16x8 ld_frag(const u16* p) {
  return __builtin_bit_cast(bf16x8, *(const uint4*)p);
}
__device__ __forceinline__ f16x8 ldh(const u16* p) {
  return __builtin_bit_cast(f16x8, *(const uint4*)p);
}

// fp16 split-2 with scaled residual: v ~= h0 + h1 * 2^-11 (error ~2^-22)
__device__ __forceinline__ void split2h(float v, u16* o0, u16* o1) {
  _Float16 a = (_Float16)v;
  float fa = (float)a;
  _Float16 b = (_Float16)((v - fa) * 2048.0f);
  *o0 = __builtin_bit_cast(u16, a);
  *o1 = __builtin_bit_cast(u16, b);
}

// ======== split-2 fp16 GEMM, BK=64, LDS pitch 72 u16 ========
#define GPRE64(RA_, RB_, FN_) \
  __shared__ __align__(16) u16 As0[(RA_)*72], As1[(RA_)*72]; \
  __shared__ __align__(16) u16 Bs0[(RB_)*72], Bs1[(RB_)*72]; \
  int tid = threadIdx.x, lane = tid & 63, wvi = tid >> 6; \
  int lr = lane & 15, lkc = lane >> 4; \
  f32x4 accm[4][FN_] = {}; f32x4 accx[4][FN_] = {};

#define GSTEP64(RA_, RB_, FN_, pA0, pA1, sA, pB0, pB1, sB, kk) { \
  uint4 la0[(RA_)/32], la1[(RA_)/32], lb0[(RB_)/32], lb1[(RB_)/32]; \
  _Pragma("unroll") \
  for (int i_ = 0; i_ < (RA_)/32; ++i_) { \
    int idx_ = tid + i_*256, r_ = idx_ >> 3, c_ = (idx_ & 7) * 8; \
    la0[i_] = *(const uint4*)((pA0) + (size_t)r_*(sA) + (kk) + c_); \
    la1[i_] = *(const uint4*)((pA1) + (size_t)r_*(sA) + (kk) + c_); } \
  _Pragma("unroll") \
  for (int i_ = 0; i_ < (RB_)/32; ++i_) { \
    int idx_ = tid + i_*256, r_ = idx_ >> 3, c_ = (idx_ & 7) * 8; \
    lb0[i_] = *(const uint4*)((pB0) + (size_t)r_*(sB) + (kk) + c_); \
    lb1[i_] = *(const uint4*)((pB1) + (size_t)r_*(sB) + (kk) + c_); } \
  __syncthreads(); \
  _Pragma("unroll") \
  for (int i_ = 0; i_ < (RA_)/32; ++i_) { \
    int idx_ = tid + i_*256, r_ = idx_ >> 3, c_ = (idx_ & 7) * 8; \
    *(uint4*)&As0[r_*72 + c_] = la0[i_]; \
    *(uint4*)&As1[r_*72 + c_] = la1[i_]; } \
  _Pragma("unroll") \
  for (int i_ = 0; i_ < (RB_)/32; ++i_) { \
    int idx_ = tid + i_*256, r_ = idx_ >> 3, c_ = (idx_ & 7) * 8; \
    *(uint4*)&Bs0[r_*72 + c_] = lb0[i_]; \
    *(uint4*)&Bs1[r_*72 + c_] = lb1[i_]; } \
  __syncthreads(); \
  _Pragma("unroll") \
  for (int ks_ = 0; ks_ < 2; ++ks_) { \
    f16x8 bq0[FN_], bq1[FN_]; \
    _Pragma("unroll") \
    for (int nf = 0; nf < FN_; ++nf) { \
      bq0[nf] = ldh(&Bs0[(wn + nf*16 + lr)*72 + ks_*32 + lkc*8]); \
      bq1[nf] = ldh(&Bs1[(wn + nf*16 + lr)*72 + ks_*32 + lkc*8]); } \
    _Pragma("unroll") \
    for (int fm = 0; fm < 4; ++fm) { \
      f16x8 a0 = ldh(&As0[(wm + fm*16 + lr)*72 + ks_*32 + lkc*8]); \
      f16x8 a1 = ldh(&As1[(wm + fm*16 + lr)*72 + ks_*32 + lkc*8]); \
      _Pragma("unroll") \
      for (int nf = 0; nf < FN_; ++nf) { \
        accm[fm][nf] = __builtin_amdgcn_mfma_f32_16x16x32_f16(a0, bq0[nf], accm[fm][nf], 0, 0, 0); \
        f32x4 cx = accx[fm][nf]; \
        cx = __builtin_amdgcn_mfma_f32_16x16x32_f16(a0, bq1[nf], cx, 0, 0, 0); \
        cx = __builtin_amdgcn_mfma_f32_16x16x32_f16(a1, bq0[nf], cx, 0, 0, 0); \
        accx[fm][nf] = cx; } } } }

#define CVAL(fm, nf, r) (accm[fm][nf][r] + accx[fm][nf][r] * 4.8828125e-4f)

// ---------------- rmsnorm with split-2 fp16 output ----------------
__global__ __launch_bounds__(256) void k_rmsnorm_split2(const float* __restrict__ x,
    const float* __restrict__ w, u16* __restrict__ o0, u16* __restrict__ o1) {
  int row = blockIdx.x, tid = threadIdx.x;
  float4 v = ((const float4*)(x + (size_t)row * DD))[tid];
  float ss = v.x*v.x + v.y*v.y + v.z*v.z + v.w*v.w;
  ss = wred_sum(ss);
  __shared__ float red[4];
  if ((tid & 63) == 0) red[tid >> 6] = ss;
  __syncthreads();
  float tot = red[0] + red[1] + red[2] + red[3];
  float sc = rsqrtf(tot * (1.0f / DD) + EPS_);
  float4 wv = ((const float4*)w)[tid];
  float vals[4] = {v.x*sc*wv.x, v.y*sc*wv.y, v.z*sc*wv.z, v.w*sc*wv.w};
  ushort4 s0, s1;
  split2h(vals[0], &s0.x, &s1.x);
  split2h(vals[1], &s0.y, &s1.y);
  split2h(vals[2], &s0.z, &s1.z);
  split2h(vals[3], &s0.w, &s1.w);
  size_t base = (size_t)row * DD + tid * 4;
  *(ushort4*)&o0[base] = s0;
  *(ushort4*)&o1[base] = s1;
}

// ---------------- transpose + split2: W[K][N] fp32 -> WT{0,1}[N][K] fp16 ----------------
__global__ __launch_bounds__(256) void k_transpose_split2(const float* __restrict__ Wm,
    u16* __restrict__ T0, u16* __restrict__ T1, int K, int N) {
  int n0 = blockIdx.x * 64, k0 = blockIdx.y * 64;
  __shared__ float tile[64][65];
  int tc = threadIdx.x & 15, tr = threadIdx.x >> 4;
#pragma unroll
  for (int kk = 0; kk < 64; kk += 16) {
    float4 v = *(const float4*)&Wm[(size_t)(k0 + kk + tr) * N + n0 + tc * 4];
    tile[kk + tr][tc*4+0] = v.x; tile[kk + tr][tc*4+1] = v.y;
    tile[kk + tr][tc*4+2] = v.z; tile[kk + tr][tc*4+3] = v.w;
  }
  __syncthreads();
#pragma unroll
  for (int nn = 0; nn < 64; nn += 16) {
    int n = nn + tr;
    ushort4 s0, s1;
    split2h(tile[tc*4+0][n], &s0.x, &s1.x);
    split2h(tile[tc*4+1][n], &s0.y, &s1.y);
    split2h(tile[tc*4+2][n], &s0.z, &s1.z);
    split2h(tile[tc*4+3][n], &s0.w, &s1.w);
    size_t base = (size_t)(n0 + n) * K + k0 + tc * 4;
    *(ushort4*)&T0[base] = s0;
    *(ushort4*)&T1[base] = s1;
  }
}

// ---------------- fused QKV GEMM (split-2 fp16, 128x64 tile, BK=64) ----------------
__global__ __launch_bounds__(256) void k_qkv_s2(
    const u16* __restrict__ h0, const u16* __restrict__ h1,
    const u16* __restrict__ wqt0, const u16* __restrict__ wqt1,
    const u16* __restrict__ wkt0, const u16* __restrict__ wkt1,
    const u16* __restrict__ wvt0, const u16* __restrict__ wvt1,
    float* __restrict__ qb, float* __restrict__ kb, float* __restrict__ vb) {
  int nt = blockIdx.x, m0 = blockIdx.y * 128;
  const u16 *B0, *B1; float* Cm; int Nm, n0;
  if (nt < 16)      { B0 = wqt0; B1 = wqt1; Cm = qb; Nm = 1024; n0 = nt * 64; }
  else if (nt < 20) { B0 = wkt0; B1 = wkt1; Cm = kb; Nm = 256;  n0 = (nt - 16) * 64; }
  else              { B0 = wvt0; B1 = wvt1; Cm = vb; Nm = 256;  n0 = (nt - 20) * 64; }
  GPRE64(128, 64, 2)
  int wm = (wvi & 1) * 64, wn = (wvi >> 1) * 32;
  const u16* a0 = h0 + (size_t)m0 * 1024;
  const u16* a1 = h1 + (size_t)m0 * 1024;
  const u16* b0 = B0 + (size_t)n0 * 1024;
  const u16* b1 = B1 + (size_t)n0 * 1024;
  for (int kk = 0; kk < 1024; kk += 64) {
    GSTEP64(128, 64, 2, a0, a1, 1024, b0, b1, 1024, kk)
  }
#pragma unroll
  for (int fm = 0; fm < 4; ++fm)
#pragma unroll
    for (int nf = 0; nf < 2; ++nf)
#pragma unroll
      for (int r = 0; r < 4; ++r) {
        int row = m0 + wm + fm*16 + lkc*4 + r;
        Cm[(size_t)row * Nm + n0 + wn + nf*16 + lr] = CVAL(fm, nf, r);
      }
}

// ---------------- per-head q/k rmsnorm + rope -> split-2 fp16 ----------------
__global__ __launch_bounds__(256) void k_qknorm_rope_split2(
    const float* __restrict__ qb, const float* __restrict__ kb,
    const float* __restrict__ qnw, const float* __restrict__ knw,
    const float* __restrict__ cosb, const float* __restrict__ sinb,
    u16* __restrict__ q0a, u16* __restrict__ q1a,
    u16* __restrict__ k0a, u16* __restrict__ k1a) {
  int tok = blockIdx.x, grp = blockIdx.y;
  int wv = threadIdx.x >> 6, d = threadIdx.x & 63;
  int s = tok & (SS - 1);
  const float* ptr; const float* wn;
  if (grp < 4) { ptr = qb + (size_t)tok * 1024 + (grp * 4 + wv) * 64; wn = qnw; }
  else         { ptr = kb + (size_t)tok * 256 + wv * 64;              wn = knw; }
  float v = ptr[d];
  float ssum = wred_sum(v * v);
  float rms = rsqrtf(ssum * (1.0f / 64.0f) + EPS_);
  float nv = v * rms * wn[d];
  float pn = __shfl_xor(nv, 32);
  float rot = (d < 32) ? -pn : pn;
  float val = nv * cosb[s * 64 + d] + rot * sinb[s * 64 + d];
  u16 a, b;
  split2h(val, &a, &b);
  if (grp < 4) {
    size_t idx = (size_t)tok * 1024 + (grp * 4 + wv) * 64 + d;
    q0a[idx] = a; q1a[idx] = b;
  } else {
    size_t idx = (size_t)tok * 256 + wv * 64 + d;
    k0a[idx] = a; k1a[idx] = b;
  }
}

// ---------------- v transpose + split2 ----------------
__global__ __launch_bounds__(256) void k_splitv2(const float* __restrict__ vb,
    u16* __restrict__ t0, u16* __restrict__ t1) {
  int k0 = blockIdx.x * 64, bkv = blockIdx.y;
  int b = bkv >> 2, kv = bkv & 3;
  __shared__ float tile[64][65];
  int tc = threadIdx.x & 15, tr = threadIdx.x >> 4;
#pragma unroll
  for (int kk = 0; kk < 64; kk += 16) {
    float4 v = *(const float4*)&vb[(size_t)(b * 1024 + k0 + kk + tr) * 256 + kv * 64 + tc * 4];
    tile[kk + tr][tc*4+0] = v.x; tile[kk + tr][tc*4+1] = v.y;
    tile[kk + tr][tc*4+2] = v.z; tile[kk + tr][tc*4+3] = v.w;
  }
  __syncthreads();
#pragma unroll
  for (int dd = 0; dd < 64; dd += 16) {
    int d = dd + tr;
    ushort4 s0, s1;
    split2h(tile[tc*4+0][d], &s0.x, &s1.x);
    split2h(tile[tc*4+1][d], &s0.y, &s1.y);
    split2h(tile[tc*4+2][d], &s0.z, &s1.z);
    split2h(tile[tc*4+3][d], &s0.w, &s1.w);
    size_t base = (size_t)(bkv * 64 + d) * 1024 + k0 + tc * 4;
    *(ushort4*)&t0[base] = s0;
    *(ushort4*)&t1[base] = s1;
  }
}

// ---------------- scores (split-2 fp16, 128x128 tile, K=64 single step) ----------------
__global__ __launch_bounds__(256) void k_scores_s2(
    const u16* __restrict__ q0a, const u16* __restrict__ q1a,
    const u16* __restrict__ k0a, const u16* __restrict__ k1a,
    float* __restrict__ sc, int bh0) {
  int kt = blockIdx.x, qt = blockIdx.y;
  if (kt > qt) return;
  int bh = bh0 + blockIdx.z, b = bh >> 4, hh = bh & 15, kv = hh >> 2;
  int q0 = qt * 128, kk0 = kt * 128;
  GPRE64(128, 128, 4)
  int wm = (wvi & 1) * 64, wn = (wvi >> 1) * 64;
  const u16* a0 = q0a + (size_t)(b * 1024 + q0) * 1024 + hh * 64;
  const u16* a1 = q1a + (size_t)(b * 1024 + q0) * 1024 + hh * 64;
  const u16* b0 = k0a + (size_t)(b * 1024 + kk0) * 256 + kv * 64;
  const u16* b1 = k1a + (size_t)(b * 1024 + kk0) * 256 + kv * 64;
  GSTEP64(128, 128, 4, a0, a1, 1024, b0, b1, 256, 0)
  float* srow = sc + (size_t)blockIdx.z * SS * SS;
#pragma unroll
  for (int fm = 0; fm < 4; ++fm)
#pragma unroll
    for (int nf = 0; nf < 4; ++nf)
#pragma unroll
      for (int r = 0; r < 4; ++r) {
        int row = q0 + wm + fm*16 + lkc*4 + r;
        srow[(size_t)row * SS + kk0 + wn + nf*16 + lr] = CVAL(fm, nf, r) * 0.125f;
      }
}

// ---------------- row softmax -> split-2 fp16 P ----------------
__global__ __launch_bounds__(256) void k_softmax_split2(const float* __restrict__ sc,
    u16* __restrict__ P0, u16* __restrict__ P1) {
  int q = blockIdx.x, z = blockIdx.y, tid = threadIdx.x;
  const float* row = sc + (size_t)z * SS * SS + (size_t)q * SS;
  int n = q + 1, i4 = tid * 4;
  float4 v4 = ((const float4*)row)[tid];
  float vv[4] = {v4.x, v4.y, v4.z, v4.w};
  float m = -3.4e38f;
#pragma unroll
  for (int j = 0; j < 4; ++j) if (i4 + j < n) m = fmaxf(m, vv[j]);
#pragma unroll
  for (int o = 32; o > 0; o >>= 1) m = fmaxf(m, __shfl_xor(m, o));
  __shared__ float redm[4], reds[4];
  if ((tid & 63) == 0) redm[tid >> 6] = m;
  __syncthreads();
  m = fmaxf(fmaxf(redm[0], redm[1]), fmaxf(redm[2], redm[3]));
  float e[4]; float l = 0.f;
#pragma unroll
  for (int j = 0; j < 4; ++j) {
    e[j] = (i4 + j < n) ? __expf(vv[j] - m) : 0.f;
    l += e[j];
  }
  l = wred_sum(l);
  if ((tid & 63) == 0) reds[tid >> 6] = l;
  __syncthreads();
  l = reds[0] + reds[1] + reds[2] + reds[3];
  float inv = 1.0f / l;
  ushort4 s0, s1;
  split2h(e[0] * inv, &s0.x, &s1.x);
  split2h(e[1] * inv, &s0.y, &s1.y);
  split2h(e[2] * inv, &s0.z, &s1.z);
  split2h(e[3] * inv, &s0.w, &s1.w);
  size_t base = (size_t)z * 1048576 + (size_t)q * 1024 + i4;
  *(ushort4*)&P0[base] = s0;
  *(ushort4*)&P1[base] = s1;
}

// ---------------- PV K-split (128x64 tile, K-chunk=256) -> fp32 partials ----------------
__global__ __launch_bounds__(256) void k_pv_s2(
    const u16* __restrict__ P0, const u16* __restrict__ P1,
    const u16* __restrict__ vt0, const u16* __restrict__ vt1,
    float* __restrict__ pvp, int bh0) {
  int qt = blockIdx.x, z = blockIdx.y, kc = blockIdx.z;
  if (kc * 256 >= (qt + 1) * 128) return;
  int bh = bh0 + z, b = bh >> 4, hh = bh & 15, kv = hh >> 2;
  int bkv = b * 4 + kv;
  int q0 = qt * 128;
  GPRE64(128, 64, 2)
  int wm = (wvi & 1) * 64, wn = (wvi >> 1) * 32;
  const u16* a0 = P0 + (size_t)z * 1048576 + (size_t)q0 * 1024;
  const u16* a1 = P1 + (size_t)z * 1048576 + (size_t)q0 * 1024;
  const u16* b0 = vt0 + (size_t)(bkv * 64) * 1024;
  const u16* b1 = vt1 + (size_t)(bkv * 64) * 1024;
  int kbase = kc * 256;
  for (int kk = kbase; kk < kbase + 256; kk += 64) {
    GSTEP64(128, 64, 2, a0, a1, 1024, b0, b1, 1024, kk)
  }
  float* op = pvp + (size_t)((z * 8 + qt) * 4 + kc) * 8192;
#pragma unroll
  for (int fm = 0; fm < 4; ++fm)
#pragma unroll
    for (int nf = 0; nf < 2; ++nf)
#pragma unroll
      for (int r = 0; r < 4; ++r)
        op[(wm + fm*16 + lkc*4 + r) * 64 + wn + nf*16 + lr] = CVAL(fm, nf, r);
}

// ---------------- PV reduce over k-chunks + split2 store into at0/at1 ----------------
__global__ __launch_bounds__(256) void k_pv_reduce(const float* __restrict__ pvp,
    u16* __restrict__ at0, u16* __restrict__ at1, int bh0) {
  int qt = blockIdx.x, z = blockIdx.y, tid = threadIdx.x;
  int bh = bh0 + z, b = bh >> 4, hh = bh & 15;
  int nkc = (qt + 2) >> 1;
  const float* base = pvp + (size_t)((z * 8 + qt) * 4) * 8192;
#pragma unroll
  for (int t = 0; t < 8; ++t) {
    int lin = t * 256 + tid;
    int row = lin >> 4, c4 = (lin & 15) * 4;
    float4 s = *(const float4*)&base[row * 64 + c4];
    for (int kc = 1; kc < nkc; ++kc) {
      float4 v = *(const float4*)&base[(size_t)kc * 8192 + row * 64 + c4];
      s.x += v.x; s.y += v.y; s.z += v.z; s.w += v.w;
    }
    ushort4 s0, s1;
    split2h(s.x, &s0.x, &s1.x);
    split2h(s.y, &s0.y, &s1.y);
    split2h(s.z, &s0.z, &s1.z);
    split2h(s.w, &s0.w, &s1.w);
    size_t idx = (size_t)(b * 1024 + qt * 128 + row) * 1024 + hh * 64 + c4;
    *(ushort4*)&at0[idx] = s0;
    *(ushort4*)&at1[idx] = s1;
  }
}

// ---------------- Wo GEMM + residual (split-2 fp16, 128x64, BK=64) ----------------
__global__ __launch_bounds__(256) void k_wo_s2(
    const u16* __restrict__ at0, const u16* __restrict__ at1,
    const u16* __restrict__ wot0, const u16* __restrict__ wot1,
    const float* __restrict__ x, float* __restrict__ x2) {
  int n0 = blockIdx.x * 64, m0 = blockIdx.y * 128;
  GPRE64(128, 64, 2)
  int wm = (wvi & 1) * 64, wn = (wvi >> 1) * 32;
  const u16* a0 = at0 + (size_t)m0 * 1024;
  const u16* a1 = at1 + (size_t)m0 * 1024;
  const u16* b0 = wot0 + (size_t)n0 * 1024;
  const u16* b1 = wot1 + (size_t)n0 * 1024;
  for (int kk = 0; kk < 1024; kk += 64) {
    GSTEP64(128, 64, 2, a0, a1, 1024, b0, b1, 1024, kk)
  }
#pragma unroll
  for (int fm = 0; fm < 4; ++fm)
#pragma unroll
    for (int nf = 0; nf < 2; ++nf)
#pragma unroll
      for (int r = 0; r < 4; ++r) {
        int row = m0 + wm + fm*16 + lkc*4 + r;
        int col = n0 + wn + nf*16 + lr;
        x2[(size_t)row * 1024 + col] = CVAL(fm, nf, r) + x[(size_t)row * 1024 + col];
      }
}

// ---------------- fused: rmsnorm(x2) -> tbh(bf16) + router logits ----------------
__global__ __launch_bounds__(256) void k_rmsnorm_logits(const float* __restrict__ x2,
    const float* __restrict__ w, const float* __restrict__ rw,
    u16* __restrict__ tbh, float* __restrict__ logits) {
  int row = blockIdx.x, tid = threadIdx.x;
  __shared__ __align__(16) float tl[1024];
  __shared__ float part[16][16];
  __shared__ float red[4];
  float4 v = ((const float4*)(x2 + (size_t)row * DD))[tid];
  float ss = v.x*v.x + v.y*v.y + v.z*v.z + v.w*v.w;
  ss = wred_sum(ss);
  if ((tid & 63) == 0) red[tid >> 6] = ss;
  __syncthreads();
  float tot = red[0] + red[1] + red[2] + red[3];
  float sc = rsqrtf(tot * (1.0f / DD) + EPS_);
  float4 wv = ((const float4*)w)[tid];
  float4 o = make_float4(v.x*sc*wv.x, v.y*sc*wv.y, v.z*sc*wv.z, v.w*sc*wv.w);
  ((float4*)tl)[tid] = o;
  ushort4 hb = make_ushort4(f2b(o.x), f2b(o.y), f2b(o.z), f2b(o.w));
  *(ushort4*)&tbh[(size_t)row * DD + tid * 4] = hb;
  __syncthreads();
  int e = tid & 15, ch = tid >> 4;
  float p = 0.f;
#pragma unroll 8
  for (int j = 0; j < 64; ++j) p = fmaf(tl[ch * 64 + j], rw[(ch * 64 + j) * EE + e], p);
  part[ch][e] = p;
  __syncthreads();
  if (tid < 16) {
    float s = 0.f;
#pragma unroll
    for (int c = 0; c < 16; ++c) s += part[c][tid];
    logits[(size_t)row * EE + tid] = s;
  }
}

// ---------------- route: softmax16 + top2 per thread ----------------
__global__ __launch_bounds__(256) void k_route(const float* __restrict__ logits,
    int* __restrict__ cnt, int* __restrict__ listTok, int* __restrict__ tokslot,
    float* __restrict__ topw, float* __restrict__ psum) {
  int tid = threadIdx.x;
  int tok = blockIdx.x * 256 + tid;
  __shared__ int lcnt[16], gbase[16];
  __shared__ float lps[16];
  if (tid < 16) { lcnt[tid] = 0; lps[tid] = 0.f; }
  __syncthreads();
  float pr[16];
#pragma unroll
  for (int g = 0; g < 4; ++g) {
    float4 v = *(const float4*)&logits[(size_t)tok * EE + g * 4];
    pr[g*4+0] = v.x; pr[g*4+1] = v.y; pr[g*4+2] = v.z; pr[g*4+3] = v.w;
  }
  float mx = pr[0];
#pragma unroll
  for (int i = 1; i < 16; ++i) mx = fmaxf(mx, pr[i]);
  float s = 0.f;
#pragma unroll
  for (int i = 0; i < 16; ++i) { pr[i] = __expf(pr[i] - mx); s += pr[i]; }
  float inv = 1.0f / s;
#pragma unroll
  for (int i = 0; i < 16; ++i) pr[i] *= inv;
  int i1 = 0; float v1 = pr[0];
#pragma unroll
  for (int i = 1; i < 16; ++i) if (pr[i] > v1) { v1 = pr[i]; i1 = i; }
  int i2 = -1; float v2 = -1.f;
#pragma unroll
  for (int i = 0; i < 16; ++i) if (i != i1 && pr[i] > v2) { v2 = pr[i]; i2 = i; }
  float wsum = v1 + v2;
  int lp1 = atomicAdd(&lcnt[i1], 1);
  int lp2 = atomicAdd(&lcnt[i2], 1);
#pragma unroll
  for (int e = 0; e < 16; ++e) {
    float v = wred_sum(pr[e]);
    if ((tid & 63) == 0) atomicAdd(&lps[e], v);
  }
  __syncthreads();
  if (tid < 16) {
    gbase[tid] = atomicAdd(&cnt[tid], lcnt[tid]);
    atomicAdd(&psum[tid], lps[tid]);
  }
  __syncthreads();
  int p1 = gbase[i1] + lp1, p2 = gbase[i2] + lp2;
  listTok[i1 * 2048 + p1] = tok;
  listTok[i2 * 2048 + p2] = tok;
  tokslot[tok * 2 + 0] = i1 * 2048 + p1;
  tokslot[tok * 2 + 1] = i2 * 2048 + p2;
  topw[tok * 2 + 0] = v1 / wsum;
  topw[tok * 2 + 1] = v2 / wsum;
}

__global__ void k_zero(int* cnt, float* psum) {
  int t = threadIdx.x;
  if (t < 16) { cnt[t] = 0; psum[t] = 0.f; }
}

__global__ void k_prefix(const int* __restrict__ cnt, int* __restrict__ offs) {
  if (threadIdx.x == 0) {
    int s = 0;
    for (int e = 0; e < 16; ++e) { offs[e] = s; s += cnt[e]; }
  }
}

// ---------------- MoE gate/up MFMA: M-tile 256, in-kernel f2b weight staging ----------------
__global__ __launch_bounds__(256) void k_gu_mfma(const u16* __restrict__ tbh,
    const float* __restrict__ wg, const float* __restrict__ wu,
    const int* __restrict__ cnt, const int* __restrict__ offs,
    const int* __restrict__ listTok, u16* __restrict__ act) {
  int e = blockIdx.z;
  int ce = cnt[e];
  int m0 = blockIdx.y * 256;
  if (m0 >= ce) return;
  int n0 = blockIdx.x * 64;
  __shared__ __align__(16) u16 Ah[256 * 56];
  __shared__ __align__(16) u16 Gh[64 * 56];
  __shared__ __align__(16) u16 Uh[64 * 56];
  __shared__ int rows[256];
  int tid = threadIdx.x;
  { int m = m0 + tid; rows[tid] = listTok[e * 2048 + (m < ce ? m : ce - 1)]; }
  __syncthreads();
  int s_nc = (tid & 31) * 2, s_kg = (tid >> 5) * 4;
  const float* wge = wg + (size_t)e * DD * II + n0;
  const float* wue = wu + (size_t)e * DD * II + n0;
  int lane = tid & 63, w = tid >> 6;
  int wm = w * 64;
  int lr = lane & 15, lk = (lane >> 4) * 8;
  f32x4 accg[4][4] = {};
  f32x4 accu[4][4] = {};
  for (int k0 = 0; k0 < DD; k0 += 32) {
    uint4 av[4];
#pragma unroll
    for (int i = 0; i < 4; ++i) {
      int idx = tid + i * 256, r = idx >> 2, c = (idx & 3) * 8;
      av[i] = *(const uint4*)(tbh + (size_t)rows[r] * DD + k0 + c);
    }
    float2 g0 = *(const float2*)&wge[(size_t)(k0 + s_kg + 0) * II + s_nc];
    float2 g1 = *(const float2*)&wge[(size_t)(k0 + s_kg + 1) * II + s_nc];
    float2 g2 = *(const float2*)&wge[(size_t)(k0 + s_kg + 2) * II + s_nc];
    float2 g3 = *(const float2*)&wge[(size_t)(k0 + s_kg + 3) * II + s_nc];
    float2 u0 = *(const float2*)&wue[(size_t)(k0 + s_kg + 0) * II + s_nc];
    float2 u1 = *(const float2*)&wue[(size_t)(k0 + s_kg + 1) * II + s_nc];
    float2 u2 = *(const float2*)&wue[(size_t)(k0 + s_kg + 2) * II + s_nc];
    float2 u3 = *(const float2*)&wue[(size_t)(k0 + s_kg + 3) * II + s_nc];
#pragma unroll
    for (int i = 0; i < 4; ++i) {
      int idx = tid + i * 256, r = idx >> 2, c = (idx & 3) * 8;
      *(uint4*)&Ah[r * 56 + c] = av[i];
    }
    *(ushort4*)&Gh[s_nc * 56 + s_kg]       = make_ushort4(f2b(g0.x), f2b(g1.x), f2b(g2.x), f2b(g3.x));
    *(ushort4*)&Gh[(s_nc + 1) * 56 + s_kg] = make_ushort4(f2b(g0.y), f2b(g1.y), f2b(g2.y), f2b(g3.y));
    *(ushort4*)&Uh[s_nc * 56 + s_kg]       = make_ushort4(f2b(u0.x), f2b(u1.x), f2b(u2.x), f2b(u3.x));
    *(ushort4*)&Uh[(s_nc + 1) * 56 + s_kg] = make_ushort4(f2b(u0.y), f2b(u1.y), f2b(u2.y), f2b(u3.y));
    __syncthreads();
    bf16x8 bg[4], bu[4];
#pragma unroll
    for (int nf = 0; nf < 4; ++nf) {
      bg[nf] = ld_frag(&Gh[(nf * 16 + lr) * 56 + lk]);
      bu[nf] = ld_frag(&Uh[(nf * 16 + lr) * 56 + lk]);
    }
#pragma unroll
    for (int fm = 0; fm < 4; ++fm) {
      bf16x8 a = ld_frag(&Ah[(wm + fm * 16 + lr) * 56 + lk]);
#pragma unroll
      for (int nf = 0; nf < 4; ++nf) {
        accg[fm][nf] = __builtin_amdgcn_mfma_f32_16x16x32_bf16(a, bg[nf], accg[fm][nf], 0, 0, 0);
        accu[fm][nf] = __builtin_amdgcn_mfma_f32_16x16x32_bf16(a, bu[nf], accu[fm][nf], 0, 0, 0);
      }
    }
    __syncthreads();
  }
  int ob = offs[e];
#pragma unroll
  for (int fm = 0; fm < 4; ++fm)
#pragma unroll
    for (int nf = 0; nf < 4; ++nf)
#pragma unroll
      for (int r = 0; r < 4; ++r) {
        int m = m0 + wm + fm * 16 + (lane >> 4) * 4 + r;
        if (m < ce) {
          float g = accg[fm][nf][r], u = accu[fm][nf][r];
          float sv = (g / (1.f + __expf(-g))) * u;
          act[(size_t)(ob + m) * II + n0 + nf * 16 + (lane & 15)] = f2b(sv);
        }
      }
}

// ---------------- MoE down MFMA: M-tile 256, in-kernel f2b weight staging ----------------
__global__ __launch_bounds__(256) void k_down_mfma(const u16* __restrict__ act,
    const float* __restrict__ wd, const int* __restrict__ cnt, const int* __restrict__ offs,
    float* __restrict__ eo) {
  int e = blockIdx.z;
  int ce = cnt[e];
  int m0 = blockIdx.y * 256;
  if (m0 >= ce) return;
  int n0 = blockIdx.x * 64;
  __shared__ __align__(16) u16 Ah[256 * 56];
  __shared__ __align__(16) u16 Bh[64 * 56];
  int tid = threadIdx.x;
  int ob = offs[e];
  int s_nc = (tid & 31) * 2, s_kg = (tid >> 5) * 4;
  const float* wde = wd + (size_t)e * II * DD + n0;
  int lane = tid & 63, w = tid >> 6;
  int wm = w * 64;
  int lr = lane & 15, lk = (lane >> 4) * 8;
  f32x4 acc[4][4] = {};
  for (int k0 = 0; k0 < II; k0 += 32) {
    uint4 av[4];
#pragma unroll
    for (int i = 0; i < 4; ++i) {
      int idx = tid + i * 256, r = idx >> 2, c = (idx & 3) * 8;
      int mr = m0 + r; if (mr >= ce) mr = ce - 1;
      av[i] = *(const uint4*)(act + (size_t)(ob + mr) * II + k0 + c);
    }
    float2 b0 = *(const float2*)&wde[(size_t)(k0 + s_kg + 0) * DD + s_nc];
    float2 b1 = *(const float2*)&wde[(size_t)(k0 + s_kg + 1) * DD + s_nc];
    float2 b2 = *(const float2*)&wde[(size_t)(k0 + s_kg + 2) * DD + s_nc];
    float2 b3 = *(const float2*)&wde[(size_t)(k0 + s_kg + 3) * DD + s_nc];
#pragma unroll
    for (int i = 0; i < 4; ++i) {
      int idx = tid + i * 256, r = idx >> 2, c = (idx & 3) * 8;
      *(uint4*)&Ah[r * 56 + c] = av[i];
    }
    *(ushort4*)&Bh[s_nc * 56 + s_kg]       = make_ushort4(f2b(b0.x), f2b(b1.x), f2b(b2.x), f2b(b3.x));
    *(ushort4*)&Bh[(s_nc + 1) * 56 + s_kg] = make_ushort4(f2b(b0.y), f2b(b1.y), f2b(b2.y), f2b(b3.y));
    __syncthreads();
    bf16x8 bb[4];
#pragma unroll
    for (int nf = 0; nf < 4; ++nf)
      bb[nf] = ld_frag(&Bh[(nf * 16 + lr) * 56 + lk]);
#pragma unroll
    for (int fm = 0; fm < 4; ++fm) {
      bf16x8 a = ld_frag(&Ah[(wm + fm * 16 + lr) * 56 + lk]);
#pragma unroll
      for (int nf = 0; nf < 4; ++nf)
        acc[fm][nf] = __builtin_amdgcn_mfma_f32_16x16x32_bf16(a, bb[nf], acc[fm][nf], 0, 0, 0);
    }
    __syncthreads();
  }
#pragma unroll
  for (int fm = 0; fm < 4; ++fm)
#pragma unroll
    for (int nf = 0; nf < 4; ++nf)
#pragma unroll
      for (int r = 0; r < 4; ++r) {
        int m = m0 + wm + fm * 16 + (lane >> 4) * 4 + r;
        if (m < ce)
          eo[(size_t)(ob + m) * DD + n0 + nf * 16 + (lane & 15)] = acc[fm][nf][r];
      }
}

// ---------------- final combine ----------------
__global__ __launch_bounds__(256) void k_final(const float* __restrict__ x2,
    const float* __restrict__ eo, const int* __restrict__ tokslot,
    const float* __restrict__ topw, const int* __restrict__ offs, float* __restrict__ out) {
  int tok = blockIdx.x, tid = threadIdx.x;
  int c0 = tokslot[tok * 2], c1 = tokslot[tok * 2 + 1];
  int s0 = offs[c0 >> 11] + (c0 & 2047);
  int s1 = offs[c1 >> 11] + (c1 & 2047);
  float w0 = topw[tok * 2], w1 = topw[tok * 2 + 1];
  float4 a = ((const float4*)(x2 + (size_t)tok * DD))[tid];
  float4 e0 = ((const float4*)(eo + (size_t)s0 * DD))[tid];
  float4 e1 = ((const float4*)(eo + (size_t)s1 * DD))[tid];
  float4 o = make_float4(a.x + w0*e0.x + w1*e1.x, a.y + w0*e0.y + w1*e1.y,
                         a.z + w0*e0.z + w1*e1.z, a.w + w0*e0.w + w1*e1.w);
  ((float4*)(out + (size_t)tok * DD))[tid] = o;
}

__global__ void k_aux(const int* __restrict__ cnt, const float* __restrict__ psum,
                      float* __restrict__ out) {
  if (threadIdx.x == 0) {
    float a = 0.f;
    for (int e = 0; e < 16; ++e)
      a += ((float)cnt[e] * (1.0f / 4096.0f)) * (psum[e] * (1.0f / 2048.0f));
    out[(size_t)TT * DD] = 16.0f * a;
  }
}

extern "C" void kernel_launch(void* const* d_in, const int* in_sizes, int n_in,
                              void* d_out, int out_size, void* d_ws, size_t ws_size,
                              hipStream_t stream) {
  const float* x    = (const float*)d_in[0];
  const float* cosb = (const float*)d_in[1];
  const float* sinb = (const float*)d_in[2];
  const float* ln1w = (const float*)d_in[3];
  const float* wq   = (const float*)d_in[4];
  const float* wk   = (const float*)d_in[5];
  const float* wv   = (const float*)d_in[6];
  const float* wo   = (const float*)d_in[7];
  const float* qnw  = (const float*)d_in[8];
  const float* knw  = (const float*)d_in[9];
  const float* ln2w = (const float*)d_in[10];
  const float* rw   = (const float*)d_in[11];
  const float* wg   = (const float*)d_in[12];
  const float* wu   = (const float*)d_in[13];
  const float* wd   = (const float*)d_in[14];
  float* out = (float*)d_out;

  float* W = (float*)d_ws;
  int*   cnt     = (int*)W;
  int*   offs    = (int*)(W + 16);
  float* psum    = W + 32;
  int*   tokslot = (int*)(W + 64);
  float* topw    = W + 4160;
  int*   listTok = (int*)(W + 8256);
  float* logits  = W + 41024;
  size_t o = 81920;
#define ALLOC_F(name, n)   float* name = W + o; o += (n);
#define ALLOC_U16(name, n) u16* name = (u16*)(W + o); o += ((size_t)(n) + 1) / 2;
  ALLOC_U16(h0, 2097152) ALLOC_U16(h1, 2097152)
  ALLOC_F(qb, 2097152) ALLOC_F(kb, 524288) ALLOC_F(vb, 524288)
  ALLOC_U16(wqt0, 1048576) ALLOC_U16(wqt1, 1048576)
  ALLOC_U16(wkt0, 262144) ALLOC_U16(wkt1, 262144)
  ALLOC_U16(wvt0, 262144) ALLOC_U16(wvt1, 262144)
  ALLOC_U16(wot0, 1048576) ALLOC_U16(wot1, 1048576)
  ALLOC_U16(qs0, 2097152) ALLOC_U16(qs1, 2097152)
  ALLOC_U16(ks0, 524288) ALLOC_U16(ks1, 524288)
  ALLOC_U16(vt0, 524288) ALLOC_U16(vt1, 524288)
  ALLOC_U16(at0, 2097152) ALLOC_U16(at1, 2097152)
  ALLOC_F(x2, 2097152)
  ALLOC_U16(tbh, 2097152)
  ALLOC_U16(act, 5767168)
  ALLOC_F(eo, 4194304)
  long avail = (long)(ws_size / 4) - (long)o;
  int NC = (int)(avail / 2359296L);   // per chunk: sc 1M f + P0,P1 (1M f) + pvp 0.25M f
  if (NC > 32) NC = 32;
  if (NC < 1) NC = 1;
  ALLOC_U16(P0, (size_t)NC * 1048576) ALLOC_U16(P1, (size_t)NC * 1048576)
  ALLOC_F(sc, (size_t)NC * 1048576)
  ALLOC_F(pvp, (size_t)NC * 262144)
#undef ALLOC_F
#undef ALLOC_U16

  k_zero<<<1, 64, 0, stream>>>(cnt, psum);
  k_rmsnorm_split2<<<TT, 256, 0, stream>>>(x, ln1w, h0, h1);
  k_transpose_split2<<<dim3(16, 16), 256, 0, stream>>>(wq, wqt0, wqt1, 1024, 1024);
  k_transpose_split2<<<dim3(4, 16), 256, 0, stream>>>(wk, wkt0, wkt1, 1024, 256);
  k_transpose_split2<<<dim3(4, 16), 256, 0, stream>>>(wv, wvt0, wvt1, 1024, 256);
  k_transpose_split2<<<dim3(16, 16), 256, 0, stream>>>(wo, wot0, wot1, 1024, 1024);
  k_qkv_s2<<<dim3(24, 16), 256, 0, stream>>>(h0, h1,
      wqt0, wqt1, wkt0, wkt1, wvt0, wvt1, qb, kb, vb);
  k_qknorm_rope_split2<<<dim3(TT, 5), 256, 0, stream>>>(qb, kb, qnw, knw, cosb, sinb,
      qs0, qs1, ks0, ks1);
  k_splitv2<<<dim3(16, 8), 256, 0, stream>>>(vb, vt0, vt1);
  for (int bh0 = 0; bh0 < 32; bh0 += NC) {
    int nc = 32 - bh0; if (nc > NC) nc = NC;
    k_scores_s2<<<dim3(8, 8, nc), 256, 0, stream>>>(qs0, qs1, ks0, ks1, sc, bh0);
    k_softmax_split2<<<dim3(SS, nc), 256, 0, stream>>>(sc, P0, P1);
    k_pv_s2<<<dim3(8, nc, 4), 256, 0, stream>>>(P0, P1, vt0, vt1, pvp, bh0);
    k_pv_reduce<<<dim3(8, nc), 256, 0, stream>>>(pvp, at0, at1, bh0);
  }
  k_wo_s2<<<dim3(16, 16), 256, 0, stream>>>(at0, at1, wot0, wot1, x, x2);
  k_rmsnorm_logits<<<TT, 256, 0, stream>>>(x2, ln2w, rw, tbh, logits);
  k_route<<<TT / 256, 256, 0, stream>>>(logits, cnt, listTok, tokslot, topw, psum);
  k_prefix<<<1, 1, 0, stream>>>(cnt, offs);
  k_gu_mfma<<<dim3(22, 8, 16), 256, 0, stream>>>(tbh, wg, wu, cnt, offs, listTok, act);
  k_down_mfma<<<dim3(16, 8, 16), 256, 0, stream>>>(act, wd, cnt, offs, eo);
  k_final<<<TT, 256, 0, stream>>>(x2, eo, tokslot, topw, offs, out);
  k_aux<<<1, 1, 0, stream>>>(cnt, psum, out);
}

// Round 8
// 664.457 us; speedup vs baseline: 1.3396x; 1.0335x over previous
//
#include <hip/hip_runtime.h>

#define BB 2
#define SS 1024
#define DD 1024
#define HH 16
#define KVH 4
#define HDD 64
#define EE 16
#define II 1408
#define TT (BB*SS)
#define EPS_ 1e-6f

typedef unsigned short u16;
typedef __bf16 bf16x8 __attribute__((ext_vector_type(8)));
typedef float f32x4 __attribute__((ext_vector_type(4)));

__device__ __forceinline__ float wred_sum(float v) {
#pragma unroll
  for (int o = 32; o > 0; o >>= 1) v += __shfl_xor(v, o);
  return v;
}

__device__ __forceinline__ u16 f2b(float f) {
  __bf16 h = (__bf16)f;
  return __builtin_bit_cast(u16, h);
}

__device__ __forceinline__ bf16x8 ld_frag(const u16* p) {
  return __builtin_bit_cast(bf16x8, *(const uint4*)p);
}

// transposed A-tile scatter store: As[k][m]
#define ASTORE(AS, av) \
  AS[ac4+0][arow]=av.x; AS[ac4+1][arow]=av.y; AS[ac4+2][arow]=av.z; AS[ac4+3][arow]=av.w;

#define INNER16(AS, BS, ACC) \
  _Pragma("unroll") \
  for (int kk_ = 0; kk_ < 16; ++kk_) { \
    float4 a4_ = *(const float4*)&AS[kk_][ty*4]; \
    float4 b4_ = *(const float4*)&BS[kk_][tx*4]; \
    float aa_[4] = {a4_.x, a4_.y, a4_.z, a4_.w}; \
    float bb_[4] = {b4_.x, b4_.y, b4_.z, b4_.w}; \
    _Pragma("unroll") \
    for (int i_ = 0; i_ < 4; ++i_) \
      _Pragma("unroll") \
      for (int j_ = 0; j_ < 4; ++j_) \
        ACC[i_][j_] = fmaf(aa_[i_], bb_[j_], ACC[i_][j_]); \
  }

// ---------------- rmsnorm over D=1024 ----------------
__global__ __launch_bounds__(256) void k_rmsnorm(const float* __restrict__ x,
                                                 const float* __restrict__ w,
                                                 float* __restrict__ out) {
  int row = blockIdx.x, tid = threadIdx.x;
  float4 v = ((const float4*)(x + (size_t)row * DD))[tid];
  float ss = v.x*v.x + v.y*v.y + v.z*v.z + v.w*v.w;
  ss = wred_sum(ss);
  __shared__ float red[4];
  if ((tid & 63) == 0) red[tid >> 6] = ss;
  __syncthreads();
  float tot = red[0] + red[1] + red[2] + red[3];
  float sc = rsqrtf(tot * (1.0f / DD) + EPS_);
  float4 wv = ((const float4*)w)[tid];
  float4 o = make_float4(v.x*sc*wv.x, v.y*sc*wv.y, v.z*sc*wv.z, v.w*sc*wv.w);
  ((float4*)(out + (size_t)row * DD))[tid] = o;
}

// ---------------- fp32 -> bf16 bulk convert ----------------
__global__ __launch_bounds__(256) void k_tobf16(const float* __restrict__ in,
                                                u16* __restrict__ out, int n4) {
  int i = blockIdx.x * 256 + threadIdx.x;
  if (i < n4) {
    float4 v = ((const float4*)in)[i];
    ushort4 o = make_ushort4(f2b(v.x), f2b(v.y), f2b(v.z), f2b(v.w));
    ((ushort4*)out)[i] = o;
  }
}

// ---------------- fused QKV GEMM ----------------
__global__ __launch_bounds__(256) void k_qkv(const float* __restrict__ h,
    const float* __restrict__ wq, const float* __restrict__ wk, const float* __restrict__ wv,
    float* __restrict__ qb, float* __restrict__ kb, float* __restrict__ vb) {
  int nt = blockIdx.x, m0 = blockIdx.y * 64;
  const float* Bm; float* Cm; int Nm, n0;
  if (nt < 16)      { Bm = wq; Cm = qb; Nm = 1024; n0 = nt * 64; }
  else if (nt < 20) { Bm = wk; Cm = kb; Nm = 256;  n0 = (nt - 16) * 64; }
  else              { Bm = wv; Cm = vb; Nm = 256;  n0 = (nt - 20) * 64; }
  __shared__ __align__(16) float As[16][64];
  __shared__ __align__(16) float Bs[16][64];
  int tid = threadIdx.x, tx = tid & 15, ty = tid >> 4;
  int arow = tid >> 2, ac4 = (tid & 3) * 4, brow = tid >> 4, bn4 = (tid & 15) * 4;
  float acc[4][4] = {};
  for (int k0 = 0; k0 < DD; k0 += 16) {
    float4 av = *(const float4*)&h[(size_t)(m0 + arow) * DD + k0 + ac4];
    ASTORE(As, av)
    float4 bv = *(const float4*)&Bm[(size_t)(k0 + brow) * Nm + n0 + bn4];
    *(float4*)&Bs[brow][bn4] = bv;
    __syncthreads();
    INNER16(As, Bs, acc)
    __syncthreads();
  }
#pragma unroll
  for (int i = 0; i < 4; ++i) {
    float4 o = make_float4(acc[i][0], acc[i][1], acc[i][2], acc[i][3]);
    *(float4*)&Cm[(size_t)(m0 + ty*4 + i) * Nm + n0 + tx*4] = o;
  }
}

// ---------------- per-head q/k rmsnorm + rope (in place) ----------------
__global__ __launch_bounds__(256) void k_qknorm_rope(float* __restrict__ qb, float* __restrict__ kb,
    const float* __restrict__ qnw, const float* __restrict__ knw,
    const float* __restrict__ cosb, const float* __restrict__ sinb) {
  int tok = blockIdx.x, grp = blockIdx.y;
  int wv = threadIdx.x >> 6, d = threadIdx.x & 63;
  int s = tok & (SS - 1);
  float* ptr; const float* wn;
  if (grp < 4) { ptr = qb + (size_t)tok * 1024 + (grp * 4 + wv) * 64; wn = qnw; }
  else         { ptr = kb + (size_t)tok * 256 + wv * 64;              wn = knw; }
  float v = ptr[d];
  float ssum = wred_sum(v * v);
  float rms = rsqrtf(ssum * (1.0f / 64.0f) + EPS_);
  float nv = v * rms * wn[d];
  float pn = __shfl_xor(nv, 32);
  float rot = (d < 32) ? -pn : pn;
  ptr[d] = nv * cosb[s * 64 + d] + rot * sinb[s * 64 + d];
}

// ---------------- scores ----------------
__global__ __launch_bounds__(256) void k_scores(const float* __restrict__ qb,
    const float* __restrict__ kb, float* __restrict__ sc, int bh0) {
  int kt = blockIdx.x, qt = blockIdx.y;
  if (kt > qt) return;
  int bh = bh0 + blockIdx.z;
  int b = bh >> 4, hh = bh & 15, kv = hh >> 2;
  int q0 = qt * 64, k0 = kt * 64;
  __shared__ __align__(16) float Qs[16][64];
  __shared__ __align__(16) float Ks[16][64];
  int tid = threadIdx.x, tx = tid & 15, ty = tid >> 4;
  int arow = tid >> 2, ac4 = (tid & 3) * 4;
  float acc[4][4] = {};
  const float* qbase = qb + (size_t)b * SS * 1024 + hh * 64;
  const float* kbase = kb + (size_t)b * SS * 256 + kv * 64;
#pragma unroll
  for (int d0 = 0; d0 < 64; d0 += 16) {
    float4 av = *(const float4*)&qbase[(size_t)(q0 + arow) * 1024 + d0 + ac4];
    ASTORE(Qs, av)
    float4 bv = *(const float4*)&kbase[(size_t)(k0 + arow) * 256 + d0 + ac4];
    Ks[ac4+0][arow]=bv.x; Ks[ac4+1][arow]=bv.y; Ks[ac4+2][arow]=bv.z; Ks[ac4+3][arow]=bv.w;
    __syncthreads();
    INNER16(Qs, Ks, acc)
    __syncthreads();
  }
  float* srow = sc + (size_t)blockIdx.z * SS * SS;
#pragma unroll
  for (int i = 0; i < 4; ++i) {
    float4 o = make_float4(acc[i][0]*0.125f, acc[i][1]*0.125f, acc[i][2]*0.125f, acc[i][3]*0.125f);
    *(float4*)&srow[(size_t)(q0 + ty*4 + i) * SS + k0 + tx*4] = o;
  }
}

// ---------------- row softmax ----------------
__global__ __launch_bounds__(256) void k_softmax(float* __restrict__ sc) {
  int q = blockIdx.x;
  float* row = sc + (size_t)blockIdx.y * SS * SS + (size_t)q * SS;
  int n = q + 1, tid = threadIdx.x;
  float m = -3.4e38f;
  for (int i = tid; i < n; i += 256) m = fmaxf(m, row[i]);
#pragma unroll
  for (int o = 32; o > 0; o >>= 1) m = fmaxf(m, __shfl_xor(m, o));
  __shared__ float redm[4], reds[4];
  if ((tid & 63) == 0) redm[tid >> 6] = m;
  __syncthreads();
  m = fmaxf(fmaxf(redm[0], redm[1]), fmaxf(redm[2], redm[3]));
  float l = 0.f;
  for (int i = tid; i < n; i += 256) { float e = __expf(row[i] - m); row[i] = e; l += e; }
  l = wred_sum(l);
  if ((tid & 63) == 0) reds[tid >> 6] = l;
  __syncthreads();
  l = reds[0] + reds[1] + reds[2] + reds[3];
  float inv = 1.0f / l;
  for (int i = tid; i < n; i += 256) row[i] *= inv;
  for (int i = n + tid; i < SS; i += 256) row[i] = 0.0f;
}

// ---------------- PV ----------------
__global__ __launch_bounds__(256) void k_pv(const float* __restrict__ sc,
    const float* __restrict__ vb, float* __restrict__ attn, int bh0) {
  int qt = blockIdx.x;
  int bh = bh0 + blockIdx.y;
  int b = bh >> 4, hh = bh & 15, kv = hh >> 2;
  int m0 = qt * 64;
  const float* P = sc + (size_t)blockIdx.y * SS * SS;
  const float* vbase = vb + (size_t)b * SS * 256 + kv * 64;
  __shared__ __align__(16) float As[16][64];
  __shared__ __align__(16) float Bs[16][64];
  int tid = threadIdx.x, tx = tid & 15, ty = tid >> 4;
  int arow = tid >> 2, ac4 = (tid & 3) * 4, brow = tid >> 4, bn4 = (tid & 15) * 4;
  float acc[4][4] = {};
  int kend = m0 + 64;
  for (int k0 = 0; k0 < kend; k0 += 16) {
    float4 av = *(const float4*)&P[(size_t)(m0 + arow) * SS + k0 + ac4];
    ASTORE(As, av)
    float4 bv = *(const float4*)&vbase[(size_t)(k0 + brow) * 256 + bn4];
    *(float4*)&Bs[brow][bn4] = bv;
    __syncthreads();
    INNER16(As, Bs, acc)
    __syncthreads();
  }
#pragma unroll
  for (int i = 0; i < 4; ++i) {
    float4 o = make_float4(acc[i][0], acc[i][1], acc[i][2], acc[i][3]);
    *(float4*)&attn[(size_t)(b * SS + m0 + ty*4 + i) * 1024 + hh * 64 + tx*4] = o;
  }
}

// ---------------- Wo GEMM + residual ----------------
__global__ __launch_bounds__(256) void k_wo(const float* __restrict__ attn,
    const float* __restrict__ wo, const float* __restrict__ x, float* __restrict__ x2) {
  int n0 = blockIdx.x * 64, m0 = blockIdx.y * 64;
  __shared__ __align__(16) float As[16][64];
  __shared__ __align__(16) float Bs[16][64];
  int tid = threadIdx.x, tx = tid & 15, ty = tid >> 4;
  int arow = tid >> 2, ac4 = (tid & 3) * 4, brow = tid >> 4, bn4 = (tid & 15) * 4;
  float acc[4][4] = {};
  for (int k0 = 0; k0 < DD; k0 += 16) {
    float4 av = *(const float4*)&attn[(size_t)(m0 + arow) * DD + k0 + ac4];
    ASTORE(As, av)
    float4 bv = *(const float4*)&wo[(size_t)(k0 + brow) * DD + n0 + bn4];
    *(float4*)&Bs[brow][bn4] = bv;
    __syncthreads();
    INNER16(As, Bs, acc)
    __syncthreads();
  }
#pragma unroll
  for (int i = 0; i < 4; ++i) {
    int row = m0 + ty*4 + i;
    float4 xr = *(const float4*)&x[(size_t)row * DD + n0 + tx*4];
    float4 o = make_float4(acc[i][0] + xr.x, acc[i][1] + xr.y, acc[i][2] + xr.z, acc[i][3] + xr.w);
    *(float4*)&x2[(size_t)row * DD + n0 + tx*4] = o;
  }
}

// ---------------- router logits ----------------
__global__ __launch_bounds__(256) void k_logits(const float* __restrict__ tb,
    const float* __restrict__ rw, float* __restrict__ logits) {
  int tok = blockIdx.x, tid = threadIdx.x;
  __shared__ __align__(16) float tl[1024];
  __shared__ float part[16][16];
  ((float4*)tl)[tid] = ((const float4*)(tb + (size_t)tok * DD))[tid];
  __syncthreads();
  int e = tid & 15, ch = tid >> 4;
  float p = 0.f;
#pragma unroll 8
  for (int j = 0; j < 64; ++j) p = fmaf(tl[ch * 64 + j], rw[(ch * 64 + j) * EE + e], p);
  part[ch][e] = p;
  __syncthreads();
  if (tid < 16) {
    float s = 0.f;
#pragma unroll
    for (int c = 0; c < 16; ++c) s += part[c][tid];
    logits[(size_t)tok * EE + tid] = s;
  }
}

// ---------------- route: softmax16 + top2 per thread; few atomics ----------------
__global__ __launch_bounds__(256) void k_route(const float* __restrict__ logits,
    int* __restrict__ cnt, int* __restrict__ listTok, int* __restrict__ tokslot,
    float* __restrict__ topw, float* __restrict__ psum) {
  int tid = threadIdx.x;
  int tok = blockIdx.x * 256 + tid;
  __shared__ int lcnt[16], gbase[16];
  __shared__ float lps[16];
  if (tid < 16) { lcnt[tid] = 0; lps[tid] = 0.f; }
  __syncthreads();
  float pr[16];
#pragma unroll
  for (int g = 0; g < 4; ++g) {
    float4 v = *(const float4*)&logits[(size_t)tok * EE + g * 4];
    pr[g*4+0] = v.x; pr[g*4+1] = v.y; pr[g*4+2] = v.z; pr[g*4+3] = v.w;
  }
  float mx = pr[0];
#pragma unroll
  for (int i = 1; i < 16; ++i) mx = fmaxf(mx, pr[i]);
  float s = 0.f;
#pragma unroll
  for (int i = 0; i < 16; ++i) { pr[i] = __expf(pr[i] - mx); s += pr[i]; }
  float inv = 1.0f / s;
#pragma unroll
  for (int i = 0; i < 16; ++i) pr[i] *= inv;
  int i1 = 0; float v1 = pr[0];
#pragma unroll
  for (int i = 1; i < 16; ++i) if (pr[i] > v1) { v1 = pr[i]; i1 = i; }
  int i2 = -1; float v2 = -1.f;
#pragma unroll
  for (int i = 0; i < 16; ++i) if (i != i1 && pr[i] > v2) { v2 = pr[i]; i2 = i; }
  float wsum = v1 + v2;
  int lp1 = atomicAdd(&lcnt[i1], 1);
  int lp2 = atomicAdd(&lcnt[i2], 1);
#pragma unroll
  for (int e = 0; e < 16; ++e) {
    float v = wred_sum(pr[e]);
    if ((tid & 63) == 0) atomicAdd(&lps[e], v);
  }
  __syncthreads();
  if (tid < 16) {
    gbase[tid] = atomicAdd(&cnt[tid], lcnt[tid]);
    atomicAdd(&psum[tid], lps[tid]);
  }
  __syncthreads();
  int p1 = gbase[i1] + lp1, p2 = gbase[i2] + lp2;
  listTok[i1 * 2048 + p1] = tok;
  listTok[i2 * 2048 + p2] = tok;
  tokslot[tok * 2 + 0] = i1 * 2048 + p1;
  tokslot[tok * 2 + 1] = i2 * 2048 + p2;
  topw[tok * 2 + 0] = v1 / wsum;
  topw[tok * 2 + 1] = v2 / wsum;
}

__global__ void k_zero(int* cnt, float* psum) {
  int t = threadIdx.x;
  if (t < 16) { cnt[t] = 0; psum[t] = 0.f; }
}

__global__ void k_prefix(const int* __restrict__ cnt, int* __restrict__ offs) {
  if (threadIdx.x == 0) {
    int s = 0;
    for (int e = 0; e < 16; ++e) { offs[e] = s; s += cnt[e]; }
  }
}

// ---------------- MoE gate/up MFMA (r2 structure; conflict-free staging maps) ----------------
// A-stage: one row per thread pair-slot (r=tid&127) -> quads 7*lane mod 8 = all 8/phase.
// G/U-stage: n-major (n=tid&63, kg=(tid>>6)*8) -> conflict-free writes, coalesced loads.
__global__ __launch_bounds__(256) void k_gu_mfma(const u16* __restrict__ tbh,
    const float* __restrict__ wg, const float* __restrict__ wu,
    const int* __restrict__ cnt, const int* __restrict__ offs,
    const int* __restrict__ listTok, u16* __restrict__ act) {
  int e = blockIdx.z;
  int ce = cnt[e];
  int m0 = blockIdx.y * 128;
  if (m0 >= ce) return;
  int n0 = blockIdx.x * 64;
  __shared__ __align__(16) u16 Ah[128][56];
  __shared__ __align__(16) u16 Gh[64][56];
  __shared__ __align__(16) u16 Uh[64][56];
  __shared__ int rows[128];
  int tid = threadIdx.x;
  if (tid < 128) {
    int m = m0 + tid;
    rows[tid] = listTok[e * 2048 + (m < ce ? m : ce - 1)];
  }
  __syncthreads();
  // staging indices (conflict-free mappings)
  int s_ar = tid & 127, s_ac = (tid >> 7) * 16;
  int s_n = tid & 63, s_kg = (tid >> 6) * 8;
  const float* wge = wg + (size_t)e * DD * II + n0;
  const float* wue = wu + (size_t)e * DD * II + n0;
  const u16* ap = tbh + (size_t)rows[s_ar] * DD + s_ac;
  // wave/frag indices
  int lane = tid & 63, w = tid >> 6;
  int wm = (w & 1) * 64, wn = (w >> 1) * 32;
  int lr = lane & 15, lk = (lane >> 4) * 8;
  f32x4 accg[4][2] = {};
  f32x4 accu[4][2] = {};
  for (int k0 = 0; k0 < DD; k0 += 32) {
    uint4 av0 = *(const uint4*)(ap + k0);
    uint4 av1 = *(const uint4*)(ap + k0 + 8);
    float gg[8], uu[8];
#pragma unroll
    for (int j = 0; j < 8; ++j) {
      gg[j] = wge[(size_t)(k0 + s_kg + j) * II + s_n];
      uu[j] = wue[(size_t)(k0 + s_kg + j) * II + s_n];
    }
    *(uint4*)&Ah[s_ar][s_ac]     = av0;
    *(uint4*)&Ah[s_ar][s_ac + 8] = av1;
    *(ushort4*)&Gh[s_n][s_kg]     = make_ushort4(f2b(gg[0]), f2b(gg[1]), f2b(gg[2]), f2b(gg[3]));
    *(ushort4*)&Gh[s_n][s_kg + 4] = make_ushort4(f2b(gg[4]), f2b(gg[5]), f2b(gg[6]), f2b(gg[7]));
    *(ushort4*)&Uh[s_n][s_kg]     = make_ushort4(f2b(uu[0]), f2b(uu[1]), f2b(uu[2]), f2b(uu[3]));
    *(ushort4*)&Uh[s_n][s_kg + 4] = make_ushort4(f2b(uu[4]), f2b(uu[5]), f2b(uu[6]), f2b(uu[7]));
    __syncthreads();
    bf16x8 af[4];
#pragma unroll
    for (int fm = 0; fm < 4; ++fm) af[fm] = ld_frag(&Ah[wm + fm*16 + lr][lk]);
#pragma unroll
    for (int nf = 0; nf < 2; ++nf) {
      bf16x8 bg = ld_frag(&Gh[wn + nf*16 + lr][lk]);
      bf16x8 bu = ld_frag(&Uh[wn + nf*16 + lr][lk]);
#pragma unroll
      for (int fm = 0; fm < 4; ++fm) {
        accg[fm][nf] = __builtin_amdgcn_mfma_f32_16x16x32_bf16(af[fm], bg, accg[fm][nf], 0, 0, 0);
        accu[fm][nf] = __builtin_amdgcn_mfma_f32_16x16x32_bf16(af[fm], bu, accu[fm][nf], 0, 0, 0);
      }
    }
    __syncthreads();
  }
  int ob = offs[e];
#pragma unroll
  for (int fm = 0; fm < 4; ++fm)
#pragma unroll
    for (int nf = 0; nf < 2; ++nf)
#pragma unroll
      for (int r = 0; r < 4; ++r) {
        int m = m0 + wm + fm*16 + (lane >> 4) * 4 + r;
        if (m < ce) {
          float g = accg[fm][nf][r], u = accu[fm][nf][r];
          float sv = (g / (1.f + __expf(-g))) * u;
          act[(size_t)(ob + m) * II + n0 + wn + nf*16 + (lane & 15)] = f2b(sv);
        }
      }
}

// ---------------- MoE down MFMA (r2 structure; conflict-free staging maps) ----------------
__global__ __launch_bounds__(256) void k_down_mfma(const u16* __restrict__ act,
    const float* __restrict__ wd, const int* __restrict__ cnt, const int* __restrict__ offs,
    float* __restrict__ eo) {
  int e = blockIdx.z;
  int ce = cnt[e];
  int m0 = blockIdx.y * 128;
  if (m0 >= ce) return;
  int n0 = blockIdx.x * 64;
  __shared__ __align__(16) u16 Ah[128][56];
  __shared__ __align__(16) u16 Bh[64][56];
  int tid = threadIdx.x;
  int ob = offs[e];
  int s_ar = tid & 127, s_ac = (tid >> 7) * 16;
  int s_n = tid & 63, s_kg = (tid >> 6) * 8;
  int mrow = m0 + s_ar; if (mrow >= ce) mrow = ce - 1;
  const u16* ap = act + (size_t)(ob + mrow) * II + s_ac;
  const float* wde = wd + (size_t)e * II * DD + n0;
  int lane = tid & 63, w = tid >> 6;
  int wm = (w & 1) * 64, wn = (w >> 1) * 32;
  int lr = lane & 15, lk = (lane >> 4) * 8;
  f32x4 acc[4][2] = {};
  for (int k0 = 0; k0 < II; k0 += 32) {
    uint4 av0 = *(const uint4*)(ap + k0);
    uint4 av1 = *(const uint4*)(ap + k0 + 8);
    float bb[8];
#pragma unroll
    for (int j = 0; j < 8; ++j)
      bb[j] = wde[(size_t)(k0 + s_kg + j) * DD + s_n];
    *(uint4*)&Ah[s_ar][s_ac]     = av0;
    *(uint4*)&Ah[s_ar][s_ac + 8] = av1;
    *(ushort4*)&Bh[s_n][s_kg]     = make_ushort4(f2b(bb[0]), f2b(bb[1]), f2b(bb[2]), f2b(bb[3]));
    *(ushort4*)&Bh[s_n][s_kg + 4] = make_ushort4(f2b(bb[4]), f2b(bb[5]), f2b(bb[6]), f2b(bb[7]));
    __syncthreads();
    bf16x8 af[4];
#pragma unroll
    for (int fm = 0; fm < 4; ++fm) af[fm] = ld_frag(&Ah[wm + fm*16 + lr][lk]);
#pragma unroll
    for (int nf = 0; nf < 2; ++nf) {
      bf16x8 bv = ld_frag(&Bh[wn + nf*16 + lr][lk]);
#pragma unroll
      for (int fm = 0; fm < 4; ++fm)
        acc[fm][nf] = __builtin_amdgcn_mfma_f32_16x16x32_bf16(af[fm], bv, acc[fm][nf], 0, 0, 0);
    }
    __syncthreads();
  }
#pragma unroll
  for (int fm = 0; fm < 4; ++fm)
#pragma unroll
    for (int nf = 0; nf < 2; ++nf)
#pragma unroll
      for (int r = 0; r < 4; ++r) {
        int m = m0 + wm + fm*16 + (lane >> 4) * 4 + r;
        if (m < ce)
          eo[(size_t)(ob + m) * DD + n0 + wn + nf*16 + (lane & 15)] = acc[fm][nf][r];
      }
}

// ---------------- final combine ----------------
__global__ __launch_bounds__(256) void k_final(const float* __restrict__ x2,
    const float* __restrict__ eo, const int* __restrict__ tokslot,
    const float* __restrict__ topw, const int* __restrict__ offs, float* __restrict__ out) {
  int tok = blockIdx.x, tid = threadIdx.x;
  int c0 = tokslot[tok * 2], c1 = tokslot[tok * 2 + 1];
  int s0 = offs[c0 >> 11] + (c0 & 2047);
  int s1 = offs[c1 >> 11] + (c1 & 2047);
  float w0 = topw[tok * 2], w1 = topw[tok * 2 + 1];
  float4 a = ((const float4*)(x2 + (size_t)tok * DD))[tid];
  float4 e0 = ((const float4*)(eo + (size_t)s0 * DD))[tid];
  float4 e1 = ((const float4*)(eo + (size_t)s1 * DD))[tid];
  float4 o = make_float4(a.x + w0*e0.x + w1*e1.x, a.y + w0*e0.y + w1*e1.y,
                         a.z + w0*e0.z + w1*e1.z, a.w + w0*e0.w + w1*e1.w);
  ((float4*)(out + (size_t)tok * DD))[tid] = o;
}

__global__ void k_aux(const int* __restrict__ cnt, const float* __restrict__ psum,
                      float* __restrict__ out) {
  if (threadIdx.x == 0) {
    float a = 0.f;
    for (int e = 0; e < 16; ++e)
      a += ((float)cnt[e] * (1.0f / 4096.0f)) * (psum[e] * (1.0f / 2048.0f));
    out[(size_t)TT * DD] = 16.0f * a;
  }
}

extern "C" void kernel_launch(void* const* d_in, const int* in_sizes, int n_in,
                              void* d_out, int out_size, void* d_ws, size_t ws_size,
                              hipStream_t stream) {
  const float* x    = (const float*)d_in[0];
  const float* cosb = (const float*)d_in[1];
  const float* sinb = (const float*)d_in[2];
  const float* ln1w = (const float*)d_in[3];
  const float* wq   = (const float*)d_in[4];
  const float* wk   = (const float*)d_in[5];
  const float* wv   = (const float*)d_in[6];
  const float* wo   = (const float*)d_in[7];
  const float* qnw  = (const float*)d_in[8];
  const float* knw  = (const float*)d_in[9];
  const float* ln2w = (const float*)d_in[10];
  const float* rw   = (const float*)d_in[11];
  const float* wg   = (const float*)d_in[12];
  const float* wu   = (const float*)d_in[13];
  const float* wd   = (const float*)d_in[14];
  float* out = (float*)d_out;

  float* W = (float*)d_ws;
  int*   cnt     = (int*)W;
  int*   offs    = (int*)(W + 16);
  float* psum    = W + 32;
  int*   tokslot = (int*)(W + 64);
  float* topw    = W + 4160;
  int*   listTok = (int*)(W + 8256);
  float* logits  = W + 41024;
  size_t o = 81920;
  float* h    = W + o; o += (size_t)TT * DD;
  float* qb   = W + o; o += (size_t)TT * 1024;
  float* kb   = W + o; o += (size_t)TT * 256;
  float* vb   = W + o; o += (size_t)TT * 256;
  float* attn = W + o; o += (size_t)TT * 1024;
  float* x2   = W + o; o += (size_t)TT * DD;
  float* tb   = W + o; o += (size_t)TT * DD;
  u16*   tbh  = (u16*)(W + o); o += (size_t)TT * DD / 2;
  u16*   act  = (u16*)(W + o); o += (size_t)4096 * II / 2;
  float* eo   = W + o; o += (size_t)4096 * DD;
  float* sc   = W + o;
  long avail = (long)(ws_size / 4) - (long)o;
  int NC = (int)(avail / ((long)SS * SS));
  if (NC > 32) NC = 32;
  if (NC < 1) NC = 1;

  k_zero<<<1, 64, 0, stream>>>(cnt, psum);
  k_rmsnorm<<<TT, 256, 0, stream>>>(x, ln1w, h);
  k_qkv<<<dim3(24, 32), 256, 0, stream>>>(h, wq, wk, wv, qb, kb, vb);
  k_qknorm_rope<<<dim3(TT, 5), 256, 0, stream>>>(qb, kb, qnw, knw, cosb, sinb);
  for (int bh0 = 0; bh0 < 32; bh0 += NC) {
    int nc = 32 - bh0; if (nc > NC) nc = NC;
    k_scores<<<dim3(16, 16, nc), 256, 0, stream>>>(qb, kb, sc, bh0);
    k_softmax<<<dim3(SS, nc), 256, 0, stream>>>(sc);
    k_pv<<<dim3(16, nc), 256, 0, stream>>>(sc, vb, attn, bh0);
  }
  k_wo<<<dim3(16, 32), 256, 0, stream>>>(attn, wo, x, x2);
  k_rmsnorm<<<TT, 256, 0, stream>>>(x2, ln2w, tb);
  k_tobf16<<<(TT * DD / 4 + 255) / 256, 256, 0, stream>>>(tb, tbh, TT * DD / 4);
  k_logits<<<TT, 256, 0, stream>>>(tb, rw, logits);
  k_route<<<TT / 256, 256, 0, stream>>>(logits, cnt, listTok, tokslot, topw, psum);
  k_prefix<<<1, 1, 0, stream>>>(cnt, offs);
  k_gu_mfma<<<dim3(22, 16, 16), 256, 0, stream>>>(tbh, wg, wu, cnt, offs, listTok, act);
  k_down_mfma<<<dim3(16, 16, 16), 256, 0, stream>>>(act, wd, cnt, offs, eo);
  k_final<<<TT, 256, 0, stream>>>(x2, eo, tokslot, topw, offs, out);
  k_aux<<<1, 1, 0, stream>>>(cnt, psum, out);
}

// Round 9
// 480.937 us; speedup vs baseline: 1.8507x; 1.3816x over previous
//
#include <hip/hip_runtime.h>

#define BB 2
#define SS 1024
#define DD 1024
#define HH 16
#define KVH 4
#define HDD 64
#define EE 16
#define II 1408
#define TT (BB*SS)
#define EPS_ 1e-6f

typedef unsigned short u16;
typedef __bf16 bf16x8 __attribute__((ext_vector_type(8)));
typedef _Float16 f16x8 __attribute__((ext_vector_type(8)));
typedef float f32x4 __attribute__((ext_vector_type(4)));

__device__ __forceinline__ float wred_sum(float v) {
#pragma unroll
  for (int o = 32; o > 0; o >>= 1) v += __shfl_xor(v, o);
  return v;
}

__device__ __forceinline__ u16 f2b(float f) {
  __bf16 h = (__bf16)f;
  return __builtin_bit_cast(u16, h);
}

__device__ __forceinline__ bf16x8 ld_frag(const u16* p) {
  return __builtin_bit_cast(bf16x8, *(const uint4*)p);
}
__device__ __forceinline__ f16x8 ldh(const u16* p) {
  return __builtin_bit_cast(f16x8, *(const uint4*)p);
}

// fp16 split-2 with scaled residual: v ~= h0 + h1 * 2^-11 (error ~2^-22)
__device__ __forceinline__ void split2h(float v, u16* o0, u16* o1) {
  _Float16 a = (_Float16)v;
  float fa = (float)a;
  _Float16 b = (_Float16)((v - fa) * 2048.0f);
  *o0 = __builtin_bit_cast(u16, a);
  *o1 = __builtin_bit_cast(u16, b);
}

// transposed A-tile scatter store: As[k][m]
#define ASTORE(AS, av) \
  AS[ac4+0][arow]=av.x; AS[ac4+1][arow]=av.y; AS[ac4+2][arow]=av.z; AS[ac4+3][arow]=av.w;

#define INNER16(AS, BS, ACC) \
  _Pragma("unroll") \
  for (int kk_ = 0; kk_ < 16; ++kk_) { \
    float4 a4_ = *(const float4*)&AS[kk_][ty*4]; \
    float4 b4_ = *(const float4*)&BS[kk_][tx*4]; \
    float aa_[4] = {a4_.x, a4_.y, a4_.z, a4_.w}; \
    float bb_[4] = {b4_.x, b4_.y, b4_.z, b4_.w}; \
    _Pragma("unroll") \
    for (int i_ = 0; i_ < 4; ++i_) \
      _Pragma("unroll") \
      for (int j_ = 0; j_ < 4; ++j_) \
        ACC[i_][j_] = fmaf(aa_[i_], bb_[j_], ACC[i_][j_]); \
  }

// ---------------- rmsnorm over D=1024 ----------------
__global__ __launch_bounds__(256) void k_rmsnorm(const float* __restrict__ x,
                                                 const float* __restrict__ w,
                                                 float* __restrict__ out) {
  int row = blockIdx.x, tid = threadIdx.x;
  float4 v = ((const float4*)(x + (size_t)row * DD))[tid];
  float ss = v.x*v.x + v.y*v.y + v.z*v.z + v.w*v.w;
  ss = wred_sum(ss);
  __shared__ float red[4];
  if ((tid & 63) == 0) red[tid >> 6] = ss;
  __syncthreads();
  float tot = red[0] + red[1] + red[2] + red[3];
  float sc = rsqrtf(tot * (1.0f / DD) + EPS_);
  float4 wv = ((const float4*)w)[tid];
  float4 o = make_float4(v.x*sc*wv.x, v.y*sc*wv.y, v.z*sc*wv.z, v.w*sc*wv.w);
  ((float4*)(out + (size_t)row * DD))[tid] = o;
}

// ---------------- fp32 -> bf16 bulk convert ----------------
__global__ __launch_bounds__(256) void k_tobf16(const float* __restrict__ in,
                                                u16* __restrict__ out, int n4) {
  int i = blockIdx.x * 256 + threadIdx.x;
  if (i < n4) {
    float4 v = ((const float4*)in)[i];
    ushort4 o = make_ushort4(f2b(v.x), f2b(v.y), f2b(v.z), f2b(v.w));
    ((ushort4*)out)[i] = o;
  }
}

// ---------------- fused QKV GEMM (r2 fp32) ----------------
__global__ __launch_bounds__(256) void k_qkv(const float* __restrict__ h,
    const float* __restrict__ wq, const float* __restrict__ wk, const float* __restrict__ wv,
    float* __restrict__ qb, float* __restrict__ kb, float* __restrict__ vb) {
  int nt = blockIdx.x, m0 = blockIdx.y * 64;
  const float* Bm; float* Cm; int Nm, n0;
  if (nt < 16)      { Bm = wq; Cm = qb; Nm = 1024; n0 = nt * 64; }
  else if (nt < 20) { Bm = wk; Cm = kb; Nm = 256;  n0 = (nt - 16) * 64; }
  else              { Bm = wv; Cm = vb; Nm = 256;  n0 = (nt - 20) * 64; }
  __shared__ __align__(16) float As[16][64];
  __shared__ __align__(16) float Bs[16][64];
  int tid = threadIdx.x, tx = tid & 15, ty = tid >> 4;
  int arow = tid >> 2, ac4 = (tid & 3) * 4, brow = tid >> 4, bn4 = (tid & 15) * 4;
  float acc[4][4] = {};
  for (int k0 = 0; k0 < DD; k0 += 16) {
    float4 av = *(const float4*)&h[(size_t)(m0 + arow) * DD + k0 + ac4];
    ASTORE(As, av)
    float4 bv = *(const float4*)&Bm[(size_t)(k0 + brow) * Nm + n0 + bn4];
    *(float4*)&Bs[brow][bn4] = bv;
    __syncthreads();
    INNER16(As, Bs, acc)
    __syncthreads();
  }
#pragma unroll
  for (int i = 0; i < 4; ++i) {
    float4 o = make_float4(acc[i][0], acc[i][1], acc[i][2], acc[i][3]);
    *(float4*)&Cm[(size_t)(m0 + ty*4 + i) * Nm + n0 + tx*4] = o;
  }
}

// ---------------- per-head q/k rmsnorm + rope -> split-2 fp16 planes ----------------
__global__ __launch_bounds__(256) void k_qknorm_rope_split2(
    const float* __restrict__ qb, const float* __restrict__ kb,
    const float* __restrict__ qnw, const float* __restrict__ knw,
    const float* __restrict__ cosb, const float* __restrict__ sinb,
    u16* __restrict__ q0a, u16* __restrict__ q1a,
    u16* __restrict__ k0a, u16* __restrict__ k1a) {
  int tok = blockIdx.x, grp = blockIdx.y;
  int wv = threadIdx.x >> 6, d = threadIdx.x & 63;
  int s = tok & (SS - 1);
  const float* ptr; const float* wn;
  if (grp < 4) { ptr = qb + (size_t)tok * 1024 + (grp * 4 + wv) * 64; wn = qnw; }
  else         { ptr = kb + (size_t)tok * 256 + wv * 64;              wn = knw; }
  float v = ptr[d];
  float ssum = wred_sum(v * v);
  float rms = rsqrtf(ssum * (1.0f / 64.0f) + EPS_);
  float nv = v * rms * wn[d];
  float pn = __shfl_xor(nv, 32);
  float rot = (d < 32) ? -pn : pn;
  float val = nv * cosb[s * 64 + d] + rot * sinb[s * 64 + d];
  u16 a, b;
  split2h(val, &a, &b);
  if (grp < 4) {
    size_t idx = (size_t)tok * 1024 + (grp * 4 + wv) * 64 + d;
    q0a[idx] = a; q1a[idx] = b;
  } else {
    size_t idx = (size_t)tok * 256 + wv * 64 + d;
    k0a[idx] = a; k1a[idx] = b;
  }
}

// ---------------- v transpose + split2: vt[bkv*64+d][key 0..1023] ----------------
__global__ __launch_bounds__(256) void k_splitv2(const float* __restrict__ vb,
    u16* __restrict__ t0, u16* __restrict__ t1) {
  int k0 = blockIdx.x * 64, bkv = blockIdx.y;
  int b = bkv >> 2, kv = bkv & 3;
  __shared__ float tile[64][65];
  int tc = threadIdx.x & 15, tr = threadIdx.x >> 4;
#pragma unroll
  for (int kk = 0; kk < 64; kk += 16) {
    float4 v = *(const float4*)&vb[(size_t)(b * 1024 + k0 + kk + tr) * 256 + kv * 64 + tc * 4];
    tile[kk + tr][tc*4+0] = v.x; tile[kk + tr][tc*4+1] = v.y;
    tile[kk + tr][tc*4+2] = v.z; tile[kk + tr][tc*4+3] = v.w;
  }
  __syncthreads();
#pragma unroll
  for (int dd = 0; dd < 64; dd += 16) {
    int d = dd + tr;
    ushort4 s0, s1;
    split2h(tile[tc*4+0][d], &s0.x, &s1.x);
    split2h(tile[tc*4+1][d], &s0.y, &s1.y);
    split2h(tile[tc*4+2][d], &s0.z, &s1.z);
    split2h(tile[tc*4+3][d], &s0.w, &s1.w);
    size_t base = (size_t)(bkv * 64 + d) * 1024 + k0 + tc * 4;
    *(ushort4*)&t0[base] = s0;
    *(ushort4*)&t1[base] = s1;
  }
}

// ---------------- flash attention: grid (8 pairs, 32 bh), 256 thr = 4 waves ----------------
// Block does q-tiles qt=pair and qt=15-pair (17 kv-steps total, balanced).
// Wave w owns q-rows w*16..w*16+15 of the 64-row tile. Split-2 fp16 QK^T and PV,
// fp32 online softmax in C-layout registers.
__global__ __launch_bounds__(256) void k_flash(
    const u16* __restrict__ qs0, const u16* __restrict__ qs1,
    const u16* __restrict__ ks0, const u16* __restrict__ ks1,
    const u16* __restrict__ vt0, const u16* __restrict__ vt1,
    float* __restrict__ attn) {
  int pair = blockIdx.x, bh = blockIdx.y;
  int b = bh >> 4, hh = bh & 15, kv = hh >> 2;
  int bkv = b * 4 + kv;
  __shared__ __align__(16) u16 Qs0[64*72], Qs1[64*72];
  __shared__ __align__(16) u16 Ks0[64*72], Ks1[64*72];
  __shared__ __align__(16) u16 Vs0[64*72], Vs1[64*72];
  __shared__ __align__(16) u16 Ps0[64*72], Ps1[64*72];
  int tid = threadIdx.x, lane = tid & 63, w = tid >> 6;
  int lr = lane & 15, g = lane >> 4;
  int wq0 = w * 16;
  const float c2 = 4.8828125e-4f;  // 2^-11
#pragma unroll 1
  for (int half = 0; half < 2; ++half) {
    int qt = (half == 0) ? pair : (15 - pair);
    int q0 = qt * 64;
    // stage Q (64 rows x 64 d split-2)
#pragma unroll
    for (int i = 0; i < 2; ++i) {
      int idx = tid + i * 256, r = idx >> 3, c = (idx & 7) * 8;
      size_t off = (size_t)(b * 1024 + q0 + r) * 1024 + hh * 64 + c;
      *(uint4*)&Qs0[r*72 + c] = *(const uint4*)(qs0 + off);
      *(uint4*)&Qs1[r*72 + c] = *(const uint4*)(qs1 + off);
    }
    f32x4 Om[4] = {}, Ox[4] = {};
    float mrow[4] = {-3.4e38f, -3.4e38f, -3.4e38f, -3.4e38f};
    float lrow[4] = {};
    __syncthreads();
    for (int kt = 0; kt <= qt; ++kt) {
      int k0 = kt * 64;
      // stage K tile and V^T tile
#pragma unroll
      for (int i = 0; i < 2; ++i) {
        int idx = tid + i * 256, r = idx >> 3, c = (idx & 7) * 8;
        size_t koff = (size_t)(b * 1024 + k0 + r) * 256 + kv * 64 + c;
        *(uint4*)&Ks0[r*72 + c] = *(const uint4*)(ks0 + koff);
        *(uint4*)&Ks1[r*72 + c] = *(const uint4*)(ks1 + koff);
        size_t voff = (size_t)(bkv * 64 + r) * 1024 + k0 + c;
        *(uint4*)&Vs0[r*72 + c] = *(const uint4*)(vt0 + voff);
        *(uint4*)&Vs1[r*72 + c] = *(const uint4*)(vt1 + voff);
      }
      __syncthreads();
      // QK^T split-2
      f32x4 Sm[4] = {}, Sx[4] = {};
#pragma unroll
      for (int ks = 0; ks < 2; ++ks) {
        f16x8 a0 = ldh(&Qs0[(wq0 + lr)*72 + ks*32 + g*8]);
        f16x8 a1 = ldh(&Qs1[(wq0 + lr)*72 + ks*32 + g*8]);
#pragma unroll
        for (int nt = 0; nt < 4; ++nt) {
          f16x8 b0 = ldh(&Ks0[(nt*16 + lr)*72 + ks*32 + g*8]);
          f16x8 b1 = ldh(&Ks1[(nt*16 + lr)*72 + ks*32 + g*8]);
          Sm[nt] = __builtin_amdgcn_mfma_f32_16x16x32_f16(a0, b0, Sm[nt], 0, 0, 0);
          f32x4 cx = Sx[nt];
          cx = __builtin_amdgcn_mfma_f32_16x16x32_f16(a0, b1, cx, 0, 0, 0);
          cx = __builtin_amdgcn_mfma_f32_16x16x32_f16(a1, b0, cx, 0, 0, 0);
          Sx[nt] = cx;
        }
      }
      // online softmax (rows g*4+r, cols nt*16+lr)
      bool diag = (kt == qt);
      float pvv[4][4], scl[4];
#pragma unroll
      for (int r = 0; r < 4; ++r) {
        int rowloc = wq0 + g*4 + r;
        float rm = -3.4e38f;
#pragma unroll
        for (int nt = 0; nt < 4; ++nt) {
          float s = (Sm[nt][r] + Sx[nt][r] * c2) * 0.125f;
          bool valid = (!diag) || (nt*16 + lr <= rowloc);
          s = valid ? s : -3.4e38f;
          pvv[r][nt] = s;
          rm = fmaxf(rm, s);
        }
#pragma unroll
        for (int o = 1; o < 16; o <<= 1) rm = fmaxf(rm, __shfl_xor(rm, o));
        float mn = fmaxf(mrow[r], rm);
        scl[r] = __expf(mrow[r] - mn);
        mrow[r] = mn;
        float rs = 0.f;
#pragma unroll
        for (int nt = 0; nt < 4; ++nt) {
          float p = (pvv[r][nt] > -3.0e38f) ? __expf(pvv[r][nt] - mn) : 0.f;
          pvv[r][nt] = p;
          rs += p;
        }
#pragma unroll
        for (int o = 1; o < 16; o <<= 1) rs += __shfl_xor(rs, o);
        lrow[r] = lrow[r] * scl[r] + rs;
      }
#pragma unroll
      for (int nt = 0; nt < 4; ++nt)
#pragma unroll
        for (int r = 0; r < 4; ++r) { Om[nt][r] *= scl[r]; Ox[nt][r] *= scl[r]; }
      // store P split-2 (wave-private rows)
#pragma unroll
      for (int r = 0; r < 4; ++r)
#pragma unroll
        for (int nt = 0; nt < 4; ++nt) {
          u16 pa, pb;
          split2h(pvv[r][nt], &pa, &pb);
          int addr = (wq0 + g*4 + r)*72 + nt*16 + lr;
          Ps0[addr] = pa; Ps1[addr] = pb;
        }
      // PV split-2 (wave reads its own P rows; Vs shared)
#pragma unroll
      for (int ks = 0; ks < 2; ++ks) {
        f16x8 p0 = ldh(&Ps0[(wq0 + lr)*72 + ks*32 + g*8]);
        f16x8 p1 = ldh(&Ps1[(wq0 + lr)*72 + ks*32 + g*8]);
#pragma unroll
        for (int nt = 0; nt < 4; ++nt) {
          f16x8 v0 = ldh(&Vs0[(nt*16 + lr)*72 + ks*32 + g*8]);
          f16x8 v1 = ldh(&Vs1[(nt*16 + lr)*72 + ks*32 + g*8]);
          Om[nt] = __builtin_amdgcn_mfma_f32_16x16x32_f16(p0, v0, Om[nt], 0, 0, 0);
          f32x4 cx = Ox[nt];
          cx = __builtin_amdgcn_mfma_f32_16x16x32_f16(p0, v1, cx, 0, 0, 0);
          cx = __builtin_amdgcn_mfma_f32_16x16x32_f16(p1, v0, cx, 0, 0, 0);
          Ox[nt] = cx;
        }
      }
      __syncthreads();
    }
    // epilogue: normalize and write attn fp32
#pragma unroll
    for (int nt = 0; nt < 4; ++nt)
#pragma unroll
      for (int r = 0; r < 4; ++r) {
        float val = (Om[nt][r] + Ox[nt][r] * c2) / lrow[r];
        attn[(size_t)(b * 1024 + q0 + wq0 + g*4 + r) * 1024 + hh * 64 + nt*16 + lr] = val;
      }
    __syncthreads();
  }
}

// ---------------- Wo GEMM + residual (r2 fp32) ----------------
__global__ __launch_bounds__(256) void k_wo(const float* __restrict__ attn,
    const float* __restrict__ wo, const float* __restrict__ x, float* __restrict__ x2) {
  int n0 = blockIdx.x * 64, m0 = blockIdx.y * 64;
  __shared__ __align__(16) float As[16][64];
  __shared__ __align__(16) float Bs[16][64];
  int tid = threadIdx.x, tx = tid & 15, ty = tid >> 4;
  int arow = tid >> 2, ac4 = (tid & 3) * 4, brow = tid >> 4, bn4 = (tid & 15) * 4;
  float acc[4][4] = {};
  for (int k0 = 0; k0 < DD; k0 += 16) {
    float4 av = *(const float4*)&attn[(size_t)(m0 + arow) * DD + k0 + ac4];
    ASTORE(As, av)
    float4 bv = *(const float4*)&wo[(size_t)(k0 + brow) * DD + n0 + bn4];
    *(float4*)&Bs[brow][bn4] = bv;
    __syncthreads();
    INNER16(As, Bs, acc)
    __syncthreads();
  }
#pragma unroll
  for (int i = 0; i < 4; ++i) {
    int row = m0 + ty*4 + i;
    float4 xr = *(const float4*)&x[(size_t)row * DD + n0 + tx*4];
    float4 o = make_float4(acc[i][0] + xr.x, acc[i][1] + xr.y, acc[i][2] + xr.z, acc[i][3] + xr.w);
    *(float4*)&x2[(size_t)row * DD + n0 + tx*4] = o;
  }
}

// ---------------- router logits ----------------
__global__ __launch_bounds__(256) void k_logits(const float* __restrict__ tb,
    const float* __restrict__ rw, float* __restrict__ logits) {
  int tok = blockIdx.x, tid = threadIdx.x;
  __shared__ __align__(16) float tl[1024];
  __shared__ float part[16][16];
  ((float4*)tl)[tid] = ((const float4*)(tb + (size_t)tok * DD))[tid];
  __syncthreads();
  int e = tid & 15, ch = tid >> 4;
  float p = 0.f;
#pragma unroll 8
  for (int j = 0; j < 64; ++j) p = fmaf(tl[ch * 64 + j], rw[(ch * 64 + j) * EE + e], p);
  part[ch][e] = p;
  __syncthreads();
  if (tid < 16) {
    float s = 0.f;
#pragma unroll
    for (int c = 0; c < 16; ++c) s += part[c][tid];
    logits[(size_t)tok * EE + tid] = s;
  }
}

// ---------------- route ----------------
__global__ __launch_bounds__(256) void k_route(const float* __restrict__ logits,
    int* __restrict__ cnt, int* __restrict__ listTok, int* __restrict__ tokslot,
    float* __restrict__ topw, float* __restrict__ psum) {
  int tid = threadIdx.x;
  int tok = blockIdx.x * 256 + tid;
  __shared__ int lcnt[16], gbase[16];
  __shared__ float lps[16];
  if (tid < 16) { lcnt[tid] = 0; lps[tid] = 0.f; }
  __syncthreads();
  float pr[16];
#pragma unroll
  for (int g = 0; g < 4; ++g) {
    float4 v = *(const float4*)&logits[(size_t)tok * EE + g * 4];
    pr[g*4+0] = v.x; pr[g*4+1] = v.y; pr[g*4+2] = v.z; pr[g*4+3] = v.w;
  }
  float mx = pr[0];
#pragma unroll
  for (int i = 1; i < 16; ++i) mx = fmaxf(mx, pr[i]);
  float s = 0.f;
#pragma unroll
  for (int i = 0; i < 16; ++i) { pr[i] = __expf(pr[i] - mx); s += pr[i]; }
  float inv = 1.0f / s;
#pragma unroll
  for (int i = 0; i < 16; ++i) pr[i] *= inv;
  int i1 = 0; float v1 = pr[0];
#pragma unroll
  for (int i = 1; i < 16; ++i) if (pr[i] > v1) { v1 = pr[i]; i1 = i; }
  int i2 = -1; float v2 = -1.f;
#pragma unroll
  for (int i = 0; i < 16; ++i) if (i != i1 && pr[i] > v2) { v2 = pr[i]; i2 = i; }
  float wsum = v1 + v2;
  int lp1 = atomicAdd(&lcnt[i1], 1);
  int lp2 = atomicAdd(&lcnt[i2], 1);
#pragma unroll
  for (int e = 0; e < 16; ++e) {
    float v = wred_sum(pr[e]);
    if ((tid & 63) == 0) atomicAdd(&lps[e], v);
  }
  __syncthreads();
  if (tid < 16) {
    gbase[tid] = atomicAdd(&cnt[tid], lcnt[tid]);
    atomicAdd(&psum[tid], lps[tid]);
  }
  __syncthreads();
  int p1 = gbase[i1] + lp1, p2 = gbase[i2] + lp2;
  listTok[i1 * 2048 + p1] = tok;
  listTok[i2 * 2048 + p2] = tok;
  tokslot[tok * 2 + 0] = i1 * 2048 + p1;
  tokslot[tok * 2 + 1] = i2 * 2048 + p2;
  topw[tok * 2 + 0] = v1 / wsum;
  topw[tok * 2 + 1] = v2 / wsum;
}

__global__ void k_zero(int* cnt, float* psum) {
  int t = threadIdx.x;
  if (t < 16) { cnt[t] = 0; psum[t] = 0.f; }
}

__global__ void k_prefix(const int* __restrict__ cnt, int* __restrict__ offs) {
  if (threadIdx.x == 0) {
    int s = 0;
    for (int e = 0; e < 16; ++e) { offs[e] = s; s += cnt[e]; }
  }
}

// ---------------- MoE gate/up MFMA (r2 verbatim) ----------------
__global__ __launch_bounds__(256) void k_gu_mfma(const u16* __restrict__ tbh,
    const float* __restrict__ wg, const float* __restrict__ wu,
    const int* __restrict__ cnt, const int* __restrict__ offs,
    const int* __restrict__ listTok, u16* __restrict__ act) {
  int e = blockIdx.z;
  int ce = cnt[e];
  int m0 = blockIdx.y * 128;
  if (m0 >= ce) return;
  int n0 = blockIdx.x * 64;
  __shared__ __align__(16) u16 Ah[128][56];
  __shared__ __align__(16) u16 Gh[64][56];
  __shared__ __align__(16) u16 Uh[64][56];
  __shared__ int rows[128];
  int tid = threadIdx.x;
  if (tid < 128) {
    int m = m0 + tid;
    rows[tid] = listTok[e * 2048 + (m < ce ? m : ce - 1)];
  }
  __syncthreads();
  int s_arow = tid >> 1, s_acol = (tid & 1) * 16;
  int s_nc = (tid & 31) * 2, s_kg = (tid >> 5) * 4;
  const float* wge = wg + (size_t)e * DD * II + n0;
  const float* wue = wu + (size_t)e * DD * II + n0;
  const u16* ap = tbh + (size_t)rows[s_arow] * DD + s_acol;
  int lane = tid & 63, w = tid >> 6;
  int wm = (w & 1) * 64, wn = (w >> 1) * 32;
  int lr = lane & 15, lk = (lane >> 4) * 8;
  f32x4 accg[4][2] = {};
  f32x4 accu[4][2] = {};
  for (int k0 = 0; k0 < DD; k0 += 32) {
    uint4 av0 = *(const uint4*)(ap + k0);
    uint4 av1 = *(const uint4*)(ap + k0 + 8);
    float2 g0 = *(const float2*)&wge[(size_t)(k0 + s_kg + 0) * II + s_nc];
    float2 g1 = *(const float2*)&wge[(size_t)(k0 + s_kg + 1) * II + s_nc];
    float2 g2 = *(const float2*)&wge[(size_t)(k0 + s_kg + 2) * II + s_nc];
    float2 g3 = *(const float2*)&wge[(size_t)(k0 + s_kg + 3) * II + s_nc];
    float2 u0 = *(const float2*)&wue[(size_t)(k0 + s_kg + 0) * II + s_nc];
    float2 u1 = *(const float2*)&wue[(size_t)(k0 + s_kg + 1) * II + s_nc];
    float2 u2 = *(const float2*)&wue[(size_t)(k0 + s_kg + 2) * II + s_nc];
    float2 u3 = *(const float2*)&wue[(size_t)(k0 + s_kg + 3) * II + s_nc];
    *(uint4*)&Ah[s_arow][s_acol]     = av0;
    *(uint4*)&Ah[s_arow][s_acol + 8] = av1;
    *(ushort4*)&Gh[s_nc][s_kg]     = make_ushort4(f2b(g0.x), f2b(g1.x), f2b(g2.x), f2b(g3.x));
    *(ushort4*)&Gh[s_nc + 1][s_kg] = make_ushort4(f2b(g0.y), f2b(g1.y), f2b(g2.y), f2b(g3.y));
    *(ushort4*)&Uh[s_nc][s_kg]     = make_ushort4(f2b(u0.x), f2b(u1.x), f2b(u2.x), f2b(u3.x));
    *(ushort4*)&Uh[s_nc + 1][s_kg] = make_ushort4(f2b(u0.y), f2b(u1.y), f2b(u2.y), f2b(u3.y));
    __syncthreads();
    bf16x8 af[4];
#pragma unroll
    for (int fm = 0; fm < 4; ++fm) af[fm] = ld_frag(&Ah[wm + fm*16 + lr][lk]);
#pragma unroll
    for (int nf = 0; nf < 2; ++nf) {
      bf16x8 bg = ld_frag(&Gh[wn + nf*16 + lr][lk]);
      bf16x8 bu = ld_frag(&Uh[wn + nf*16 + lr][lk]);
#pragma unroll
      for (int fm = 0; fm < 4; ++fm) {
        accg[fm][nf] = __builtin_amdgcn_mfma_f32_16x16x32_bf16(af[fm], bg, accg[fm][nf], 0, 0, 0);
        accu[fm][nf] = __builtin_amdgcn_mfma_f32_16x16x32_bf16(af[fm], bu, accu[fm][nf], 0, 0, 0);
      }
    }
    __syncthreads();
  }
  int ob = offs[e];
#pragma unroll
  for (int fm = 0; fm < 4; ++fm)
#pragma unroll
    for (int nf = 0; nf < 2; ++nf)
#pragma unroll
      for (int r = 0; r < 4; ++r) {
        int m = m0 + wm + fm*16 + (lane >> 4) * 4 + r;
        if (m < ce) {
          float g = accg[fm][nf][r], u = accu[fm][nf][r];
          float sv = (g / (1.f + __expf(-g))) * u;
          act[(size_t)(ob + m) * II + n0 + wn + nf*16 + (lane & 15)] = f2b(sv);
        }
      }
}

// ---------------- MoE down MFMA (r2 verbatim) ----------------
__global__ __launch_bounds__(256) void k_down_mfma(const u16* __restrict__ act,
    const float* __restrict__ wd, const int* __restrict__ cnt, const int* __restrict__ offs,
    float* __restrict__ eo) {
  int e = blockIdx.z;
  int ce = cnt[e];
  int m0 = blockIdx.y * 128;
  if (m0 >= ce) return;
  int n0 = blockIdx.x * 64;
  __shared__ __align__(16) u16 Ah[128][56];
  __shared__ __align__(16) u16 Bh[64][56];
  int tid = threadIdx.x;
  int ob = offs[e];
  int s_arow = tid >> 1, s_acol = (tid & 1) * 16;
  int s_nc = (tid & 31) * 2, s_kg = (tid >> 5) * 4;
  int mrow = m0 + s_arow; if (mrow >= ce) mrow = ce - 1;
  const u16* ap = act + (size_t)(ob + mrow) * II + s_acol;
  const float* wde = wd + (size_t)e * II * DD + n0;
  int lane = tid & 63, w = tid >> 6;
  int wm = (w & 1) * 64, wn = (w >> 1) * 32;
  int lr = lane & 15, lk = (lane >> 4) * 8;
  f32x4 acc[4][2] = {};
  for (int k0 = 0; k0 < II; k0 += 32) {
    uint4 av0 = *(const uint4*)(ap + k0);
    uint4 av1 = *(const uint4*)(ap + k0 + 8);
    float2 b0 = *(const float2*)&wde[(size_t)(k0 + s_kg + 0) * DD + s_nc];
    float2 b1 = *(const float2*)&wde[(size_t)(k0 + s_kg + 1) * DD + s_nc];
    float2 b2 = *(const float2*)&wde[(size_t)(k0 + s_kg + 2) * DD + s_nc];
    float2 b3 = *(const float2*)&wde[(size_t)(k0 + s_kg + 3) * DD + s_nc];
    *(uint4*)&Ah[s_arow][s_acol]     = av0;
    *(uint4*)&Ah[s_arow][s_acol + 8] = av1;
    *(ushort4*)&Bh[s_nc][s_kg]     = make_ushort4(f2b(b0.x), f2b(b1.x), f2b(b2.x), f2b(b3.x));
    *(ushort4*)&Bh[s_nc + 1][s_kg] = make_ushort4(f2b(b0.y), f2b(b1.y), f2b(b2.y), f2b(b3.y));
    __syncthreads();
    bf16x8 af[4];
#pragma unroll
    for (int fm = 0; fm < 4; ++fm) af[fm] = ld_frag(&Ah[wm + fm*16 + lr][lk]);
#pragma unroll
    for (int nf = 0; nf < 2; ++nf) {
      bf16x8 bb = ld_frag(&Bh[wn + nf*16 + lr][lk]);
#pragma unroll
      for (int fm = 0; fm < 4; ++fm)
        acc[fm][nf] = __builtin_amdgcn_mfma_f32_16x16x32_bf16(af[fm], bb, acc[fm][nf], 0, 0, 0);
    }
    __syncthreads();
  }
#pragma unroll
  for (int fm = 0; fm < 4; ++fm)
#pragma unroll
    for (int nf = 0; nf < 2; ++nf)
#pragma unroll
      for (int r = 0; r < 4; ++r) {
        int m = m0 + wm + fm*16 + (lane >> 4) * 4 + r;
        if (m < ce)
          eo[(size_t)(ob + m) * DD + n0 + wn + nf*16 + (lane & 15)] = acc[fm][nf][r];
      }
}

// ---------------- final combine ----------------
__global__ __launch_bounds__(256) void k_final(const float* __restrict__ x2,
    const float* __restrict__ eo, const int* __restrict__ tokslot,
    const float* __restrict__ topw, const int* __restrict__ offs, float* __restrict__ out) {
  int tok = blockIdx.x, tid = threadIdx.x;
  int c0 = tokslot[tok * 2], c1 = tokslot[tok * 2 + 1];
  int s0 = offs[c0 >> 11] + (c0 & 2047);
  int s1 = offs[c1 >> 11] + (c1 & 2047);
  float w0 = topw[tok * 2], w1 = topw[tok * 2 + 1];
  float4 a = ((const float4*)(x2 + (size_t)tok * DD))[tid];
  float4 e0 = ((const float4*)(eo + (size_t)s0 * DD))[tid];
  float4 e1 = ((const float4*)(eo + (size_t)s1 * DD))[tid];
  float4 o = make_float4(a.x + w0*e0.x + w1*e1.x, a.y + w0*e0.y + w1*e1.y,
                         a.z + w0*e0.z + w1*e1.z, a.w + w0*e0.w + w1*e1.w);
  ((float4*)(out + (size_t)tok * DD))[tid] = o;
}

__global__ void k_aux(const int* __restrict__ cnt, const float* __restrict__ psum,
                      float* __restrict__ out) {
  if (threadIdx.x == 0) {
    float a = 0.f;
    for (int e = 0; e < 16; ++e)
      a += ((float)cnt[e] * (1.0f / 4096.0f)) * (psum[e] * (1.0f / 2048.0f));
    out[(size_t)TT * DD] = 16.0f * a;
  }
}

extern "C" void kernel_launch(void* const* d_in, const int* in_sizes, int n_in,
                              void* d_out, int out_size, void* d_ws, size_t ws_size,
                              hipStream_t stream) {
  const float* x    = (const float*)d_in[0];
  const float* cosb = (const float*)d_in[1];
  const float* sinb = (const float*)d_in[2];
  const float* ln1w = (const float*)d_in[3];
  const float* wq   = (const float*)d_in[4];
  const float* wk   = (const float*)d_in[5];
  const float* wv   = (const float*)d_in[6];
  const float* wo   = (const float*)d_in[7];
  const float* qnw  = (const float*)d_in[8];
  const float* knw  = (const float*)d_in[9];
  const float* ln2w = (const float*)d_in[10];
  const float* rw   = (const float*)d_in[11];
  const float* wg   = (const float*)d_in[12];
  const float* wu   = (const float*)d_in[13];
  const float* wd   = (const float*)d_in[14];
  float* out = (float*)d_out;

  float* W = (float*)d_ws;
  int*   cnt     = (int*)W;
  int*   offs    = (int*)(W + 16);
  float* psum    = W + 32;
  int*   tokslot = (int*)(W + 64);
  float* topw    = W + 4160;
  int*   listTok = (int*)(W + 8256);
  float* logits  = W + 41024;
  size_t o = 81920;
#define ALLOC_F(name, n)   float* name = W + o; o += (n);
#define ALLOC_U16(name, n) u16* name = (u16*)(W + o); o += ((size_t)(n) + 1) / 2;
  ALLOC_F(h, 2097152)
  ALLOC_F(qb, 2097152) ALLOC_F(kb, 524288) ALLOC_F(vb, 524288)
  ALLOC_U16(qs0, 2097152) ALLOC_U16(qs1, 2097152)
  ALLOC_U16(ks0, 524288) ALLOC_U16(ks1, 524288)
  ALLOC_U16(vt0, 524288) ALLOC_U16(vt1, 524288)
  ALLOC_F(attn, 2097152)
  ALLOC_F(x2, 2097152) ALLOC_F(tb, 2097152)
  ALLOC_U16(tbh, 2097152)
  ALLOC_U16(act, 5767168)
  ALLOC_F(eo, 4194304)
#undef ALLOC_F
#undef ALLOC_U16

  k_zero<<<1, 64, 0, stream>>>(cnt, psum);
  k_rmsnorm<<<TT, 256, 0, stream>>>(x, ln1w, h);
  k_qkv<<<dim3(24, 32), 256, 0, stream>>>(h, wq, wk, wv, qb, kb, vb);
  k_qknorm_rope_split2<<<dim3(TT, 5), 256, 0, stream>>>(qb, kb, qnw, knw, cosb, sinb,
      qs0, qs1, ks0, ks1);
  k_splitv2<<<dim3(16, 8), 256, 0, stream>>>(vb, vt0, vt1);
  k_flash<<<dim3(8, 32), 256, 0, stream>>>(qs0, qs1, ks0, ks1, vt0, vt1, attn);
  k_wo<<<dim3(16, 32), 256, 0, stream>>>(attn, wo, x, x2);
  k_rmsnorm<<<TT, 256, 0, stream>>>(x2, ln2w, tb);
  k_tobf16<<<(TT * DD / 4 + 255) / 256, 256, 0, stream>>>(tb, tbh, TT * DD / 4);
  k_logits<<<TT, 256, 0, stream>>>(tb, rw, logits);
  k_route<<<TT / 256, 256, 0, stream>>>(logits, cnt, listTok, tokslot, topw, psum);
  k_prefix<<<1, 1, 0, stream>>>(cnt, offs);
  k_gu_mfma<<<dim3(22, 16, 16), 256, 0, stream>>>(tbh, wg, wu, cnt, offs, listTok, act);
  k_down_mfma<<<dim3(16, 16, 16), 256, 0, stream>>>(act, wd, cnt, offs, eo);
  k_final<<<TT, 256, 0, stream>>>(x2, eo, tokslot, topw, offs, out);
  k_aux<<<1, 1, 0, stream>>>(cnt, psum, out);
}

// Round 10
// 459.069 us; speedup vs baseline: 1.9389x; 1.0476x over previous
//
#include <hip/hip_runtime.h>

#define BB 2
#define SS 1024
#define DD 1024
#define HH 16
#define KVH 4
#define HDD 64
#define EE 16
#define II 1408
#define TT (BB*SS)
#define EPS_ 1e-6f

typedef unsigned short u16;
typedef __bf16 bf16x8 __attribute__((ext_vector_type(8)));
typedef _Float16 f16x8 __attribute__((ext_vector_type(8)));
typedef float f32x4 __attribute__((ext_vector_type(4)));

__device__ __forceinline__ float wred_sum(float v) {
#pragma unroll
  for (int o = 32; o > 0; o >>= 1) v += __shfl_xor(v, o);
  return v;
}

__device__ __forceinline__ u16 f2b(float f) {
  __bf16 h = (__bf16)f;
  return __builtin_bit_cast(u16, h);
}

__device__ __forceinline__ bf16x8 ld_frag(const u16* p) {
  return __builtin_bit_cast(bf16x8, *(const uint4*)p);
}
__device__ __forceinline__ f16x8 ldh(const u16* p) {
  return __builtin_bit_cast(f16x8, *(const uint4*)p);
}

// fp16 split-2 with scaled residual: v ~= h0 + h1 * 2^-11 (error ~2^-22)
__device__ __forceinline__ void split2h(float v, u16* o0, u16* o1) {
  _Float16 a = (_Float16)v;
  float fa = (float)a;
  _Float16 b = (_Float16)((v - fa) * 2048.0f);
  *o0 = __builtin_bit_cast(u16, a);
  *o1 = __builtin_bit_cast(u16, b);
}

// ======== split-2 fp16 GEMM, BK=64, LDS pitch 72 u16 (r6 template, passed) ========
#define GPRE64(RA_, RB_, FN_) \
  __shared__ __align__(16) u16 As0[(RA_)*72], As1[(RA_)*72]; \
  __shared__ __align__(16) u16 Bs0[(RB_)*72], Bs1[(RB_)*72]; \
  int tid = threadIdx.x, lane = tid & 63, wvi = tid >> 6; \
  int lr = lane & 15, lkc = lane >> 4; \
  f32x4 accm[4][FN_] = {}; f32x4 accx[4][FN_] = {};

#define GSTEP64(RA_, RB_, FN_, pA0, pA1, sA, pB0, pB1, sB, kk) { \
  uint4 la0[(RA_)/32], la1[(RA_)/32], lb0[(RB_)/32], lb1[(RB_)/32]; \
  _Pragma("unroll") \
  for (int i_ = 0; i_ < (RA_)/32; ++i_) { \
    int idx_ = tid + i_*256, r_ = idx_ >> 3, c_ = (idx_ & 7) * 8; \
    la0[i_] = *(const uint4*)((pA0) + (size_t)r_*(sA) + (kk) + c_); \
    la1[i_] = *(const uint4*)((pA1) + (size_t)r_*(sA) + (kk) + c_); } \
  _Pragma("unroll") \
  for (int i_ = 0; i_ < (RB_)/32; ++i_) { \
    int idx_ = tid + i_*256, r_ = idx_ >> 3, c_ = (idx_ & 7) * 8; \
    lb0[i_] = *(const uint4*)((pB0) + (size_t)r_*(sB) + (kk) + c_); \
    lb1[i_] = *(const uint4*)((pB1) + (size_t)r_*(sB) + (kk) + c_); } \
  __syncthreads(); \
  _Pragma("unroll") \
  for (int i_ = 0; i_ < (RA_)/32; ++i_) { \
    int idx_ = tid + i_*256, r_ = idx_ >> 3, c_ = (idx_ & 7) * 8; \
    *(uint4*)&As0[r_*72 + c_] = la0[i_]; \
    *(uint4*)&As1[r_*72 + c_] = la1[i_]; } \
  _Pragma("unroll") \
  for (int i_ = 0; i_ < (RB_)/32; ++i_) { \
    int idx_ = tid + i_*256, r_ = idx_ >> 3, c_ = (idx_ & 7) * 8; \
    *(uint4*)&Bs0[r_*72 + c_] = lb0[i_]; \
    *(uint4*)&Bs1[r_*72 + c_] = lb1[i_]; } \
  __syncthreads(); \
  _Pragma("unroll") \
  for (int ks_ = 0; ks_ < 2; ++ks_) { \
    f16x8 bq0[FN_], bq1[FN_]; \
    _Pragma("unroll") \
    for (int nf = 0; nf < FN_; ++nf) { \
      bq0[nf] = ldh(&Bs0[(wn + nf*16 + lr)*72 + ks_*32 + lkc*8]); \
      bq1[nf] = ldh(&Bs1[(wn + nf*16 + lr)*72 + ks_*32 + lkc*8]); } \
    _Pragma("unroll") \
    for (int fm = 0; fm < 4; ++fm) { \
      f16x8 a0 = ldh(&As0[(wm + fm*16 + lr)*72 + ks_*32 + lkc*8]); \
      f16x8 a1 = ldh(&As1[(wm + fm*16 + lr)*72 + ks_*32 + lkc*8]); \
      _Pragma("unroll") \
      for (int nf = 0; nf < FN_; ++nf) { \
        accm[fm][nf] = __builtin_amdgcn_mfma_f32_16x16x32_f16(a0, bq0[nf], accm[fm][nf], 0, 0, 0); \
        f32x4 cx = accx[fm][nf]; \
        cx = __builtin_amdgcn_mfma_f32_16x16x32_f16(a0, bq1[nf], cx, 0, 0, 0); \
        cx = __builtin_amdgcn_mfma_f32_16x16x32_f16(a1, bq0[nf], cx, 0, 0, 0); \
        accx[fm][nf] = cx; } } } }

#define CVAL(fm, nf, r) (accm[fm][nf][r] + accx[fm][nf][r] * 4.8828125e-4f)

// ---------------- rmsnorm over D=1024 (fp32 out) ----------------
__global__ __launch_bounds__(256) void k_rmsnorm(const float* __restrict__ x,
                                                 const float* __restrict__ w,
                                                 float* __restrict__ out) {
  int row = blockIdx.x, tid = threadIdx.x;
  float4 v = ((const float4*)(x + (size_t)row * DD))[tid];
  float ss = v.x*v.x + v.y*v.y + v.z*v.z + v.w*v.w;
  ss = wred_sum(ss);
  __shared__ float red[4];
  if ((tid & 63) == 0) red[tid >> 6] = ss;
  __syncthreads();
  float tot = red[0] + red[1] + red[2] + red[3];
  float sc = rsqrtf(tot * (1.0f / DD) + EPS_);
  float4 wv = ((const float4*)w)[tid];
  float4 o = make_float4(v.x*sc*wv.x, v.y*sc*wv.y, v.z*sc*wv.z, v.w*sc*wv.w);
  ((float4*)(out + (size_t)row * DD))[tid] = o;
}

// ---------------- rmsnorm with split-2 fp16 output ----------------
__global__ __launch_bounds__(256) void k_rmsnorm_split2(const float* __restrict__ x,
    const float* __restrict__ w, u16* __restrict__ o0, u16* __restrict__ o1) {
  int row = blockIdx.x, tid = threadIdx.x;
  float4 v = ((const float4*)(x + (size_t)row * DD))[tid];
  float ss = v.x*v.x + v.y*v.y + v.z*v.z + v.w*v.w;
  ss = wred_sum(ss);
  __shared__ float red[4];
  if ((tid & 63) == 0) red[tid >> 6] = ss;
  __syncthreads();
  float tot = red[0] + red[1] + red[2] + red[3];
  float sc = rsqrtf(tot * (1.0f / DD) + EPS_);
  float4 wv = ((const float4*)w)[tid];
  float vals[4] = {v.x*sc*wv.x, v.y*sc*wv.y, v.z*sc*wv.z, v.w*sc*wv.w};
  ushort4 s0, s1;
  split2h(vals[0], &s0.x, &s1.x);
  split2h(vals[1], &s0.y, &s1.y);
  split2h(vals[2], &s0.z, &s1.z);
  split2h(vals[3], &s0.w, &s1.w);
  size_t base = (size_t)row * DD + tid * 4;
  *(ushort4*)&o0[base] = s0;
  *(ushort4*)&o1[base] = s1;
}

// ---------------- transpose + split2: W[K][N] fp32 -> WT{0,1}[N][K] fp16 ----------------
__global__ __launch_bounds__(256) void k_transpose_split2(const float* __restrict__ Wm,
    u16* __restrict__ T0, u16* __restrict__ T1, int K, int N) {
  int n0 = blockIdx.x * 64, k0 = blockIdx.y * 64;
  __shared__ float tile[64][65];
  int tc = threadIdx.x & 15, tr = threadIdx.x >> 4;
#pragma unroll
  for (int kk = 0; kk < 64; kk += 16) {
    float4 v = *(const float4*)&Wm[(size_t)(k0 + kk + tr) * N + n0 + tc * 4];
    tile[kk + tr][tc*4+0] = v.x; tile[kk + tr][tc*4+1] = v.y;
    tile[kk + tr][tc*4+2] = v.z; tile[kk + tr][tc*4+3] = v.w;
  }
  __syncthreads();
#pragma unroll
  for (int nn = 0; nn < 64; nn += 16) {
    int n = nn + tr;
    ushort4 s0, s1;
    split2h(tile[tc*4+0][n], &s0.x, &s1.x);
    split2h(tile[tc*4+1][n], &s0.y, &s1.y);
    split2h(tile[tc*4+2][n], &s0.z, &s1.z);
    split2h(tile[tc*4+3][n], &s0.w, &s1.w);
    size_t base = (size_t)(n0 + n) * K + k0 + tc * 4;
    *(ushort4*)&T0[base] = s0;
    *(ushort4*)&T1[base] = s1;
  }
}

// ---------------- fused QKV GEMM (split-2 fp16, 128x64 tile, BK=64; r6 verbatim) ----------------
__global__ __launch_bounds__(256) void k_qkv_s2(
    const u16* __restrict__ h0, const u16* __restrict__ h1,
    const u16* __restrict__ wqt0, const u16* __restrict__ wqt1,
    const u16* __restrict__ wkt0, const u16* __restrict__ wkt1,
    const u16* __restrict__ wvt0, const u16* __restrict__ wvt1,
    float* __restrict__ qb, float* __restrict__ kb, float* __restrict__ vb) {
  int nt = blockIdx.x, m0 = blockIdx.y * 128;
  const u16 *B0, *B1; float* Cm; int Nm, n0;
  if (nt < 16)      { B0 = wqt0; B1 = wqt1; Cm = qb; Nm = 1024; n0 = nt * 64; }
  else if (nt < 20) { B0 = wkt0; B1 = wkt1; Cm = kb; Nm = 256;  n0 = (nt - 16) * 64; }
  else              { B0 = wvt0; B1 = wvt1; Cm = vb; Nm = 256;  n0 = (nt - 20) * 64; }
  GPRE64(128, 64, 2)
  int wm = (wvi & 1) * 64, wn = (wvi >> 1) * 32;
  const u16* a0 = h0 + (size_t)m0 * 1024;
  const u16* a1 = h1 + (size_t)m0 * 1024;
  const u16* b0 = B0 + (size_t)n0 * 1024;
  const u16* b1 = B1 + (size_t)n0 * 1024;
  for (int kk = 0; kk < 1024; kk += 64) {
    GSTEP64(128, 64, 2, a0, a1, 1024, b0, b1, 1024, kk)
  }
#pragma unroll
  for (int fm = 0; fm < 4; ++fm)
#pragma unroll
    for (int nf = 0; nf < 2; ++nf)
#pragma unroll
      for (int r = 0; r < 4; ++r) {
        int row = m0 + wm + fm*16 + lkc*4 + r;
        Cm[(size_t)row * Nm + n0 + wn + nf*16 + lr] = CVAL(fm, nf, r);
      }
}

// ---------------- per-head q/k rmsnorm + rope -> split-2 fp16 planes ----------------
__global__ __launch_bounds__(256) void k_qknorm_rope_split2(
    const float* __restrict__ qb, const float* __restrict__ kb,
    const float* __restrict__ qnw, const float* __restrict__ knw,
    const float* __restrict__ cosb, const float* __restrict__ sinb,
    u16* __restrict__ q0a, u16* __restrict__ q1a,
    u16* __restrict__ k0a, u16* __restrict__ k1a) {
  int tok = blockIdx.x, grp = blockIdx.y;
  int wv = threadIdx.x >> 6, d = threadIdx.x & 63;
  int s = tok & (SS - 1);
  const float* ptr; const float* wn;
  if (grp < 4) { ptr = qb + (size_t)tok * 1024 + (grp * 4 + wv) * 64; wn = qnw; }
  else         { ptr = kb + (size_t)tok * 256 + wv * 64;              wn = knw; }
  float v = ptr[d];
  float ssum = wred_sum(v * v);
  float rms = rsqrtf(ssum * (1.0f / 64.0f) + EPS_);
  float nv = v * rms * wn[d];
  float pn = __shfl_xor(nv, 32);
  float rot = (d < 32) ? -pn : pn;
  float val = nv * cosb[s * 64 + d] + rot * sinb[s * 64 + d];
  u16 a, b;
  split2h(val, &a, &b);
  if (grp < 4) {
    size_t idx = (size_t)tok * 1024 + (grp * 4 + wv) * 64 + d;
    q0a[idx] = a; q1a[idx] = b;
  } else {
    size_t idx = (size_t)tok * 256 + wv * 64 + d;
    k0a[idx] = a; k1a[idx] = b;
  }
}

// ---------------- v transpose + split2 ----------------
__global__ __launch_bounds__(256) void k_splitv2(const float* __restrict__ vb,
    u16* __restrict__ t0, u16* __restrict__ t1) {
  int k0 = blockIdx.x * 64, bkv = blockIdx.y;
  int b = bkv >> 2, kv = bkv & 3;
  __shared__ float tile[64][65];
  int tc = threadIdx.x & 15, tr = threadIdx.x >> 4;
#pragma unroll
  for (int kk = 0; kk < 64; kk += 16) {
    float4 v = *(const float4*)&vb[(size_t)(b * 1024 + k0 + kk + tr) * 256 + kv * 64 + tc * 4];
    tile[kk + tr][tc*4+0] = v.x; tile[kk + tr][tc*4+1] = v.y;
    tile[kk + tr][tc*4+2] = v.z; tile[kk + tr][tc*4+3] = v.w;
  }
  __syncthreads();
#pragma unroll
  for (int dd = 0; dd < 64; dd += 16) {
    int d = dd + tr;
    ushort4 s0, s1;
    split2h(tile[tc*4+0][d], &s0.x, &s1.x);
    split2h(tile[tc*4+1][d], &s0.y, &s1.y);
    split2h(tile[tc*4+2][d], &s0.z, &s1.z);
    split2h(tile[tc*4+3][d], &s0.w, &s1.w);
    size_t base = (size_t)(bkv * 64 + d) * 1024 + k0 + tc * 4;
    *(ushort4*)&t0[base] = s0;
    *(ushort4*)&t1[base] = s1;
  }
}

// ---------------- flash attention (r9) -> split-2 attn planes ----------------
__global__ __launch_bounds__(256) void k_flash(
    const u16* __restrict__ qs0, const u16* __restrict__ qs1,
    const u16* __restrict__ ks0, const u16* __restrict__ ks1,
    const u16* __restrict__ vt0, const u16* __restrict__ vt1,
    u16* __restrict__ at0, u16* __restrict__ at1) {
  int pair = blockIdx.x, bh = blockIdx.y;
  int b = bh >> 4, hh = bh & 15, kv = hh >> 2;
  int bkv = b * 4 + kv;
  __shared__ __align__(16) u16 Qs0[64*72], Qs1[64*72];
  __shared__ __align__(16) u16 Ks0[64*72], Ks1[64*72];
  __shared__ __align__(16) u16 Vs0[64*72], Vs1[64*72];
  __shared__ __align__(16) u16 Ps0[64*72], Ps1[64*72];
  int tid = threadIdx.x, lane = tid & 63, w = tid >> 6;
  int lr = lane & 15, g = lane >> 4;
  int wq0 = w * 16;
  const float c2 = 4.8828125e-4f;
#pragma unroll 1
  for (int half = 0; half < 2; ++half) {
    int qt = (half == 0) ? pair : (15 - pair);
    int q0 = qt * 64;
#pragma unroll
    for (int i = 0; i < 2; ++i) {
      int idx = tid + i * 256, r = idx >> 3, c = (idx & 7) * 8;
      size_t off = (size_t)(b * 1024 + q0 + r) * 1024 + hh * 64 + c;
      *(uint4*)&Qs0[r*72 + c] = *(const uint4*)(qs0 + off);
      *(uint4*)&Qs1[r*72 + c] = *(const uint4*)(qs1 + off);
    }
    f32x4 Om[4] = {}, Ox[4] = {};
    float mrow[4] = {-3.4e38f, -3.4e38f, -3.4e38f, -3.4e38f};
    float lrow[4] = {};
    __syncthreads();
    for (int kt = 0; kt <= qt; ++kt) {
      int k0 = kt * 64;
#pragma unroll
      for (int i = 0; i < 2; ++i) {
        int idx = tid + i * 256, r = idx >> 3, c = (idx & 7) * 8;
        size_t koff = (size_t)(b * 1024 + k0 + r) * 256 + kv * 64 + c;
        *(uint4*)&Ks0[r*72 + c] = *(const uint4*)(ks0 + koff);
        *(uint4*)&Ks1[r*72 + c] = *(const uint4*)(ks1 + koff);
        size_t voff = (size_t)(bkv * 64 + r) * 1024 + k0 + c;
        *(uint4*)&Vs0[r*72 + c] = *(const uint4*)(vt0 + voff);
        *(uint4*)&Vs1[r*72 + c] = *(const uint4*)(vt1 + voff);
      }
      __syncthreads();
      f32x4 Sm[4] = {}, Sx[4] = {};
#pragma unroll
      for (int ks = 0; ks < 2; ++ks) {
        f16x8 a0 = ldh(&Qs0[(wq0 + lr)*72 + ks*32 + g*8]);
        f16x8 a1 = ldh(&Qs1[(wq0 + lr)*72 + ks*32 + g*8]);
#pragma unroll
        for (int nt = 0; nt < 4; ++nt) {
          f16x8 b0 = ldh(&Ks0[(nt*16 + lr)*72 + ks*32 + g*8]);
          f16x8 b1 = ldh(&Ks1[(nt*16 + lr)*72 + ks*32 + g*8]);
          Sm[nt] = __builtin_amdgcn_mfma_f32_16x16x32_f16(a0, b0, Sm[nt], 0, 0, 0);
          f32x4 cx = Sx[nt];
          cx = __builtin_amdgcn_mfma_f32_16x16x32_f16(a0, b1, cx, 0, 0, 0);
          cx = __builtin_amdgcn_mfma_f32_16x16x32_f16(a1, b0, cx, 0, 0, 0);
          Sx[nt] = cx;
        }
      }
      bool diag = (kt == qt);
      float pvv[4][4], scl[4];
#pragma unroll
      for (int r = 0; r < 4; ++r) {
        int rowloc = wq0 + g*4 + r;
        float rm = -3.4e38f;
#pragma unroll
        for (int nt = 0; nt < 4; ++nt) {
          float s = (Sm[nt][r] + Sx[nt][r] * c2) * 0.125f;
          bool valid = (!diag) || (nt*16 + lr <= rowloc);
          s = valid ? s : -3.4e38f;
          pvv[r][nt] = s;
          rm = fmaxf(rm, s);
        }
#pragma unroll
        for (int o = 1; o < 16; o <<= 1) rm = fmaxf(rm, __shfl_xor(rm, o));
        float mn = fmaxf(mrow[r], rm);
        scl[r] = __expf(mrow[r] - mn);
        mrow[r] = mn;
        float rs = 0.f;
#pragma unroll
        for (int nt = 0; nt < 4; ++nt) {
          float p = (pvv[r][nt] > -3.0e38f) ? __expf(pvv[r][nt] - mn) : 0.f;
          pvv[r][nt] = p;
          rs += p;
        }
#pragma unroll
        for (int o = 1; o < 16; o <<= 1) rs += __shfl_xor(rs, o);
        lrow[r] = lrow[r] * scl[r] + rs;
      }
#pragma unroll
      for (int nt = 0; nt < 4; ++nt)
#pragma unroll
        for (int r = 0; r < 4; ++r) { Om[nt][r] *= scl[r]; Ox[nt][r] *= scl[r]; }
#pragma unroll
      for (int r = 0; r < 4; ++r)
#pragma unroll
        for (int nt = 0; nt < 4; ++nt) {
          u16 pa, pb;
          split2h(pvv[r][nt], &pa, &pb);
          int addr = (wq0 + g*4 + r)*72 + nt*16 + lr;
          Ps0[addr] = pa; Ps1[addr] = pb;
        }
#pragma unroll
      for (int ks = 0; ks < 2; ++ks) {
        f16x8 p0 = ldh(&Ps0[(wq0 + lr)*72 + ks*32 + g*8]);
        f16x8 p1 = ldh(&Ps1[(wq0 + lr)*72 + ks*32 + g*8]);
#pragma unroll
        for (int nt = 0; nt < 4; ++nt) {
          f16x8 v0 = ldh(&Vs0[(nt*16 + lr)*72 + ks*32 + g*8]);
          f16x8 v1 = ldh(&Vs1[(nt*16 + lr)*72 + ks*32 + g*8]);
          Om[nt] = __builtin_amdgcn_mfma_f32_16x16x32_f16(p0, v0, Om[nt], 0, 0, 0);
          f32x4 cx = Ox[nt];
          cx = __builtin_amdgcn_mfma_f32_16x16x32_f16(p0, v1, cx, 0, 0, 0);
          cx = __builtin_amdgcn_mfma_f32_16x16x32_f16(p1, v0, cx, 0, 0, 0);
          Ox[nt] = cx;
        }
      }
      __syncthreads();
    }
    // epilogue: normalize, split-2 store
#pragma unroll
    for (int nt = 0; nt < 4; ++nt)
#pragma unroll
      for (int r = 0; r < 4; ++r) {
        float val = (Om[nt][r] + Ox[nt][r] * c2) / lrow[r];
        u16 sa, sb;
        split2h(val, &sa, &sb);
        size_t idx = (size_t)(b * 1024 + q0 + wq0 + g*4 + r) * 1024 + hh * 64 + nt*16 + lr;
        at0[idx] = sa; at1[idx] = sb;
      }
    __syncthreads();
  }
}

// ---------------- Wo GEMM + residual (split-2 fp16, 128x64, BK=64; r6 verbatim) ----------------
__global__ __launch_bounds__(256) void k_wo_s2(
    const u16* __restrict__ at0, const u16* __restrict__ at1,
    const u16* __restrict__ wot0, const u16* __restrict__ wot1,
    const float* __restrict__ x, float* __restrict__ x2) {
  int n0 = blockIdx.x * 64, m0 = blockIdx.y * 128;
  GPRE64(128, 64, 2)
  int wm = (wvi & 1) * 64, wn = (wvi >> 1) * 32;
  const u16* a0 = at0 + (size_t)m0 * 1024;
  const u16* a1 = at1 + (size_t)m0 * 1024;
  const u16* b0 = wot0 + (size_t)n0 * 1024;
  const u16* b1 = wot1 + (size_t)n0 * 1024;
  for (int kk = 0; kk < 1024; kk += 64) {
    GSTEP64(128, 64, 2, a0, a1, 1024, b0, b1, 1024, kk)
  }
#pragma unroll
  for (int fm = 0; fm < 4; ++fm)
#pragma unroll
    for (int nf = 0; nf < 2; ++nf)
#pragma unroll
      for (int r = 0; r < 4; ++r) {
        int row = m0 + wm + fm*16 + lkc*4 + r;
        int col = n0 + wn + nf*16 + lr;
        x2[(size_t)row * 1024 + col] = CVAL(fm, nf, r) + x[(size_t)row * 1024 + col];
      }
}

// ---------------- fused: rmsnorm(x2) -> tbh(bf16) + router logits (r6 verbatim) ----------------
__global__ __launch_bounds__(256) void k_rmsnorm_logits(const float* __restrict__ x2,
    const float* __restrict__ w, const float* __restrict__ rw,
    u16* __restrict__ tbh, float* __restrict__ logits) {
  int row = blockIdx.x, tid = threadIdx.x;
  __shared__ __align__(16) float tl[1024];
  __shared__ float part[16][16];
  __shared__ float red[4];
  float4 v = ((const float4*)(x2 + (size_t)row * DD))[tid];
  float ss = v.x*v.x + v.y*v.y + v.z*v.z + v.w*v.w;
  ss = wred_sum(ss);
  if ((tid & 63) == 0) red[tid >> 6] = ss;
  __syncthreads();
  float tot = red[0] + red[1] + red[2] + red[3];
  float sc = rsqrtf(tot * (1.0f / DD) + EPS_);
  float4 wv = ((const float4*)w)[tid];
  float4 o = make_float4(v.x*sc*wv.x, v.y*sc*wv.y, v.z*sc*wv.z, v.w*sc*wv.w);
  ((float4*)tl)[tid] = o;
  ushort4 hb = make_ushort4(f2b(o.x), f2b(o.y), f2b(o.z), f2b(o.w));
  *(ushort4*)&tbh[(size_t)row * DD + tid * 4] = hb;
  __syncthreads();
  int e = tid & 15, ch = tid >> 4;
  float p = 0.f;
#pragma unroll 8
  for (int j = 0; j < 64; ++j) p = fmaf(tl[ch * 64 + j], rw[(ch * 64 + j) * EE + e], p);
  part[ch][e] = p;
  __syncthreads();
  if (tid < 16) {
    float s = 0.f;
#pragma unroll
    for (int c = 0; c < 16; ++c) s += part[c][tid];
    logits[(size_t)row * EE + tid] = s;
  }
}

// ---------------- route ----------------
__global__ __launch_bounds__(256) void k_route(const float* __restrict__ logits,
    int* __restrict__ cnt, int* __restrict__ listTok, int* __restrict__ tokslot,
    float* __restrict__ topw, float* __restrict__ psum) {
  int tid = threadIdx.x;
  int tok = blockIdx.x * 256 + tid;
  __shared__ int lcnt[16], gbase[16];
  __shared__ float lps[16];
  if (tid < 16) { lcnt[tid] = 0; lps[tid] = 0.f; }
  __syncthreads();
  float pr[16];
#pragma unroll
  for (int g = 0; g < 4; ++g) {
    float4 v = *(const float4*)&logits[(size_t)tok * EE + g * 4];
    pr[g*4+0] = v.x; pr[g*4+1] = v.y; pr[g*4+2] = v.z; pr[g*4+3] = v.w;
  }
  float mx = pr[0];
#pragma unroll
  for (int i = 1; i < 16; ++i) mx = fmaxf(mx, pr[i]);
  float s = 0.f;
#pragma unroll
  for (int i = 0; i < 16; ++i) { pr[i] = __expf(pr[i] - mx); s += pr[i]; }
  float inv = 1.0f / s;
#pragma unroll
  for (int i = 0; i < 16; ++i) pr[i] *= inv;
  int i1 = 0; float v1 = pr[0];
#pragma unroll
  for (int i = 1; i < 16; ++i) if (pr[i] > v1) { v1 = pr[i]; i1 = i; }
  int i2 = -1; float v2 = -1.f;
#pragma unroll
  for (int i = 0; i < 16; ++i) if (i != i1 && pr[i] > v2) { v2 = pr[i]; i2 = i; }
  float wsum = v1 + v2;
  int lp1 = atomicAdd(&lcnt[i1], 1);
  int lp2 = atomicAdd(&lcnt[i2], 1);
#pragma unroll
  for (int e = 0; e < 16; ++e) {
    float v = wred_sum(pr[e]);
    if ((tid & 63) == 0) atomicAdd(&lps[e], v);
  }
  __syncthreads();
  if (tid < 16) {
    gbase[tid] = atomicAdd(&cnt[tid], lcnt[tid]);
    atomicAdd(&psum[tid], lps[tid]);
  }
  __syncthreads();
  int p1 = gbase[i1] + lp1, p2 = gbase[i2] + lp2;
  listTok[i1 * 2048 + p1] = tok;
  listTok[i2 * 2048 + p2] = tok;
  tokslot[tok * 2 + 0] = i1 * 2048 + p1;
  tokslot[tok * 2 + 1] = i2 * 2048 + p2;
  topw[tok * 2 + 0] = v1 / wsum;
  topw[tok * 2 + 1] = v2 / wsum;
}

__global__ void k_zero(int* cnt, float* psum) {
  int t = threadIdx.x;
  if (t < 16) { cnt[t] = 0; psum[t] = 0.f; }
}

__global__ void k_prefix(const int* __restrict__ cnt, int* __restrict__ offs) {
  if (threadIdx.x == 0) {
    int s = 0;
    for (int e = 0; e < 16; ++e) { offs[e] = s; s += cnt[e]; }
  }
}

// ---------------- MoE gate/up MFMA (r2 + register-prefetch 2-phase) ----------------
__global__ __launch_bounds__(256) void k_gu_mfma(const u16* __restrict__ tbh,
    const float* __restrict__ wg, const float* __restrict__ wu,
    const int* __restrict__ cnt, const int* __restrict__ offs,
    const int* __restrict__ listTok, u16* __restrict__ act) {
  int e = blockIdx.z;
  int ce = cnt[e];
  int m0 = blockIdx.y * 128;
  if (m0 >= ce) return;
  int n0 = blockIdx.x * 64;
  __shared__ __align__(16) u16 Ah[128][56];
  __shared__ __align__(16) u16 Gh[64][56];
  __shared__ __align__(16) u16 Uh[64][56];
  __shared__ int rows[128];
  int tid = threadIdx.x;
  if (tid < 128) {
    int m = m0 + tid;
    rows[tid] = listTok[e * 2048 + (m < ce ? m : ce - 1)];
  }
  __syncthreads();
  int s_arow = tid >> 1, s_acol = (tid & 1) * 16;
  int s_nc = (tid & 31) * 2, s_kg = (tid >> 5) * 4;
  const float* wge = wg + (size_t)e * DD * II + n0;
  const float* wue = wu + (size_t)e * DD * II + n0;
  const u16* ap = tbh + (size_t)rows[s_arow] * DD + s_acol;
  int lane = tid & 63, w = tid >> 6;
  int wm = (w & 1) * 64, wn = (w >> 1) * 32;
  int lr = lane & 15, lk = (lane >> 4) * 8;
  f32x4 accg[4][2] = {};
  f32x4 accu[4][2] = {};
  uint4 av0, av1;
  float2 g0, g1, g2, g3, u0, u1, u2, u3;
#define GU_LOADK(K0) \
  av0 = *(const uint4*)(ap + (K0)); \
  av1 = *(const uint4*)(ap + (K0) + 8); \
  g0 = *(const float2*)&wge[(size_t)((K0) + s_kg + 0) * II + s_nc]; \
  g1 = *(const float2*)&wge[(size_t)((K0) + s_kg + 1) * II + s_nc]; \
  g2 = *(const float2*)&wge[(size_t)((K0) + s_kg + 2) * II + s_nc]; \
  g3 = *(const float2*)&wge[(size_t)((K0) + s_kg + 3) * II + s_nc]; \
  u0 = *(const float2*)&wue[(size_t)((K0) + s_kg + 0) * II + s_nc]; \
  u1 = *(const float2*)&wue[(size_t)((K0) + s_kg + 1) * II + s_nc]; \
  u2 = *(const float2*)&wue[(size_t)((K0) + s_kg + 2) * II + s_nc]; \
  u3 = *(const float2*)&wue[(size_t)((K0) + s_kg + 3) * II + s_nc];
  GU_LOADK(0)
  for (int k0 = 0; k0 < DD; k0 += 32) {
    *(uint4*)&Ah[s_arow][s_acol]     = av0;
    *(uint4*)&Ah[s_arow][s_acol + 8] = av1;
    *(ushort4*)&Gh[s_nc][s_kg]     = make_ushort4(f2b(g0.x), f2b(g1.x), f2b(g2.x), f2b(g3.x));
    *(ushort4*)&Gh[s_nc + 1][s_kg] = make_ushort4(f2b(g0.y), f2b(g1.y), f2b(g2.y), f2b(g3.y));
    *(ushort4*)&Uh[s_nc][s_kg]     = make_ushort4(f2b(u0.x), f2b(u1.x), f2b(u2.x), f2b(u3.x));
    *(ushort4*)&Uh[s_nc + 1][s_kg] = make_ushort4(f2b(u0.y), f2b(u1.y), f2b(u2.y), f2b(u3.y));
    __syncthreads();
    if (k0 + 32 < DD) { GU_LOADK(k0 + 32) }   // prefetch: latency hides under MFMA below
    bf16x8 af[4];
#pragma unroll
    for (int fm = 0; fm < 4; ++fm) af[fm] = ld_frag(&Ah[wm + fm*16 + lr][lk]);
#pragma unroll
    for (int nf = 0; nf < 2; ++nf) {
      bf16x8 bg = ld_frag(&Gh[wn + nf*16 + lr][lk]);
      bf16x8 bu = ld_frag(&Uh[wn + nf*16 + lr][lk]);
#pragma unroll
      for (int fm = 0; fm < 4; ++fm) {
        accg[fm][nf] = __builtin_amdgcn_mfma_f32_16x16x32_bf16(af[fm], bg, accg[fm][nf], 0, 0, 0);
        accu[fm][nf] = __builtin_amdgcn_mfma_f32_16x16x32_bf16(af[fm], bu, accu[fm][nf], 0, 0, 0);
      }
    }
    __syncthreads();
  }
#undef GU_LOADK
  int ob = offs[e];
#pragma unroll
  for (int fm = 0; fm < 4; ++fm)
#pragma unroll
    for (int nf = 0; nf < 2; ++nf)
#pragma unroll
      for (int r = 0; r < 4; ++r) {
        int m = m0 + wm + fm*16 + (lane >> 4) * 4 + r;
        if (m < ce) {
          float g = accg[fm][nf][r], u = accu[fm][nf][r];
          float sv = (g / (1.f + __expf(-g))) * u;
          act[(size_t)(ob + m) * II + n0 + wn + nf*16 + (lane & 15)] = f2b(sv);
        }
      }
}

// ---------------- MoE down MFMA (r2 + register-prefetch 2-phase) ----------------
__global__ __launch_bounds__(256) void k_down_mfma(const u16* __restrict__ act,
    const float* __restrict__ wd, const int* __restrict__ cnt, const int* __restrict__ offs,
    float* __restrict__ eo) {
  int e = blockIdx.z;
  int ce = cnt[e];
  int m0 = blockIdx.y * 128;
  if (m0 >= ce) return;
  int n0 = blockIdx.x * 64;
  __shared__ __align__(16) u16 Ah[128][56];
  __shared__ __align__(16) u16 Bh[64][56];
  int tid = threadIdx.x;
  int ob = offs[e];
  int s_arow = tid >> 1, s_acol = (tid & 1) * 16;
  int s_nc = (tid & 31) * 2, s_kg = (tid >> 5) * 4;
  int mrow = m0 + s_arow; if (mrow >= ce) mrow = ce - 1;
  const u16* ap = act + (size_t)(ob + mrow) * II + s_acol;
  const float* wde = wd + (size_t)e * II * DD + n0;
  int lane = tid & 63, w = tid >> 6;
  int wm = (w & 1) * 64, wn = (w >> 1) * 32;
  int lr = lane & 15, lk = (lane >> 4) * 8;
  f32x4 acc[4][2] = {};
  uint4 av0, av1;
  float2 b0, b1, b2, b3;
#define DN_LOADK(K0) \
  av0 = *(const uint4*)(ap + (K0)); \
  av1 = *(const uint4*)(ap + (K0) + 8); \
  b0 = *(const float2*)&wde[(size_t)((K0) + s_kg + 0) * DD + s_nc]; \
  b1 = *(const float2*)&wde[(size_t)((K0) + s_kg + 1) * DD + s_nc]; \
  b2 = *(const float2*)&wde[(size_t)((K0) + s_kg + 2) * DD + s_nc]; \
  b3 = *(const float2*)&wde[(size_t)((K0) + s_kg + 3) * DD + s_nc];
  DN_LOADK(0)
  for (int k0 = 0; k0 < II; k0 += 32) {
    *(uint4*)&Ah[s_arow][s_acol]     = av0;
    *(uint4*)&Ah[s_arow][s_acol + 8] = av1;
    *(ushort4*)&Bh[s_nc][s_kg]     = make_ushort4(f2b(b0.x), f2b(b1.x), f2b(b2.x), f2b(b3.x));
    *(ushort4*)&Bh[s_nc + 1][s_kg] = make_ushort4(f2b(b0.y), f2b(b1.y), f2b(b2.y), f2b(b3.y));
    __syncthreads();
    if (k0 + 32 < II) { DN_LOADK(k0 + 32) }
    bf16x8 af[4];
#pragma unroll
    for (int fm = 0; fm < 4; ++fm) af[fm] = ld_frag(&Ah[wm + fm*16 + lr][lk]);
#pragma unroll
    for (int nf = 0; nf < 2; ++nf) {
      bf16x8 bb = ld_frag(&Bh[wn + nf*16 + lr][lk]);
#pragma unroll
      for (int fm = 0; fm < 4; ++fm)
        acc[fm][nf] = __builtin_amdgcn_mfma_f32_16x16x32_bf16(af[fm], bb, acc[fm][nf], 0, 0, 0);
    }
    __syncthreads();
  }
#undef DN_LOADK
#pragma unroll
  for (int fm = 0; fm < 4; ++fm)
#pragma unroll
    for (int nf = 0; nf < 2; ++nf)
#pragma unroll
      for (int r = 0; r < 4; ++r) {
        int m = m0 + wm + fm*16 + (lane >> 4) * 4 + r;
        if (m < ce)
          eo[(size_t)(ob + m) * DD + n0 + wn + nf*16 + (lane & 15)] = acc[fm][nf][r];
      }
}

// ---------------- final combine ----------------
__global__ __launch_bounds__(256) void k_final(const float* __restrict__ x2,
    const float* __restrict__ eo, const int* __restrict__ tokslot,
    const float* __restrict__ topw, const int* __restrict__ offs, float* __restrict__ out) {
  int tok = blockIdx.x, tid = threadIdx.x;
  int c0 = tokslot[tok * 2], c1 = tokslot[tok * 2 + 1];
  int s0 = offs[c0 >> 11] + (c0 & 2047);
  int s1 = offs[c1 >> 11] + (c1 & 2047);
  float w0 = topw[tok * 2], w1 = topw[tok * 2 + 1];
  float4 a = ((const float4*)(x2 + (size_t)tok * DD))[tid];
  float4 e0 = ((const float4*)(eo + (size_t)s0 * DD))[tid];
  float4 e1 = ((const float4*)(eo + (size_t)s1 * DD))[tid];
  float4 o = make_float4(a.x + w0*e0.x + w1*e1.x, a.y + w0*e0.y + w1*e1.y,
                         a.z + w0*e0.z + w1*e1.z, a.w + w0*e0.w + w1*e1.w);
  ((float4*)(out + (size_t)tok * DD))[tid] = o;
}

__global__ void k_aux(const int* __restrict__ cnt, const float* __restrict__ psum,
                      float* __restrict__ out) {
  if (threadIdx.x == 0) {
    float a = 0.f;
    for (int e = 0; e < 16; ++e)
      a += ((float)cnt[e] * (1.0f / 4096.0f)) * (psum[e] * (1.0f / 2048.0f));
    out[(size_t)TT * DD] = 16.0f * a;
  }
}

extern "C" void kernel_launch(void* const* d_in, const int* in_sizes, int n_in,
                              void* d_out, int out_size, void* d_ws, size_t ws_size,
                              hipStream_t stream) {
  const float* x    = (const float*)d_in[0];
  const float* cosb = (const float*)d_in[1];
  const float* sinb = (const float*)d_in[2];
  const float* ln1w = (const float*)d_in[3];
  const float* wq   = (const float*)d_in[4];
  const float* wk   = (const float*)d_in[5];
  const float* wv   = (const float*)d_in[6];
  const float* wo   = (const float*)d_in[7];
  const float* qnw  = (const float*)d_in[8];
  const float* knw  = (const float*)d_in[9];
  const float* ln2w = (const float*)d_in[10];
  const float* rw   = (const float*)d_in[11];
  const float* wg   = (const float*)d_in[12];
  const float* wu   = (const float*)d_in[13];
  const float* wd   = (const float*)d_in[14];
  float* out = (float*)d_out;

  float* W = (float*)d_ws;
  int*   cnt     = (int*)W;
  int*   offs    = (int*)(W + 16);
  float* psum    = W + 32;
  int*   tokslot = (int*)(W + 64);
  float* topw    = W + 4160;
  int*   listTok = (int*)(W + 8256);
  float* logits  = W + 41024;
  size_t o = 81920;
#define ALLOC_F(name, n)   float* name = W + o; o += (n);
#define ALLOC_U16(name, n) u16* name = (u16*)(W + o); o += ((size_t)(n) + 1) / 2;
  ALLOC_U16(h0, 2097152) ALLOC_U16(h1, 2097152)
  ALLOC_F(qb, 2097152) ALLOC_F(kb, 524288) ALLOC_F(vb, 524288)
  ALLOC_U16(wqt0, 1048576) ALLOC_U16(wqt1, 1048576)
  ALLOC_U16(wkt0, 262144) ALLOC_U16(wkt1, 262144)
  ALLOC_U16(wvt0, 262144) ALLOC_U16(wvt1, 262144)
  ALLOC_U16(wot0, 1048576) ALLOC_U16(wot1, 1048576)
  ALLOC_U16(qs0, 2097152) ALLOC_U16(qs1, 2097152)
  ALLOC_U16(ks0, 524288) ALLOC_U16(ks1, 524288)
  ALLOC_U16(vt0, 524288) ALLOC_U16(vt1, 524288)
  ALLOC_U16(at0, 2097152) ALLOC_U16(at1, 2097152)
  ALLOC_F(x2, 2097152)
  ALLOC_U16(tbh, 2097152)
  ALLOC_U16(act, 5767168)
  ALLOC_F(eo, 4194304)
#undef ALLOC_F
#undef ALLOC_U16

  k_zero<<<1, 64, 0, stream>>>(cnt, psum);
  k_rmsnorm_split2<<<TT, 256, 0, stream>>>(x, ln1w, h0, h1);
  k_transpose_split2<<<dim3(16, 16), 256, 0, stream>>>(wq, wqt0, wqt1, 1024, 1024);
  k_transpose_split2<<<dim3(4, 16), 256, 0, stream>>>(wk, wkt0, wkt1, 1024, 256);
  k_transpose_split2<<<dim3(4, 16), 256, 0, stream>>>(wv, wvt0, wvt1, 1024, 256);
  k_transpose_split2<<<dim3(16, 16), 256, 0, stream>>>(wo, wot0, wot1, 1024, 1024);
  k_qkv_s2<<<dim3(24, 16), 256, 0, stream>>>(h0, h1,
      wqt0, wqt1, wkt0, wkt1, wvt0, wvt1, qb, kb, vb);
  k_qknorm_rope_split2<<<dim3(TT, 5), 256, 0, stream>>>(qb, kb, qnw, knw, cosb, sinb,
      qs0, qs1, ks0, ks1);
  k_splitv2<<<dim3(16, 8), 256, 0, stream>>>(vb, vt0, vt1);
  k_flash<<<dim3(8, 32), 256, 0, stream>>>(qs0, qs1, ks0, ks1, vt0, vt1, at0, at1);
  k_wo_s2<<<dim3(16, 16), 256, 0, stream>>>(at0, at1, wot0, wot1, x, x2);
  k_rmsnorm_logits<<<TT, 256, 0, stream>>>(x2, ln2w, rw, tbh, logits);
  k_route<<<TT / 256, 256, 0, stream>>>(logits, cnt, listTok, tokslot, topw, psum);
  k_prefix<<<1, 1, 0, stream>>>(cnt, offs);
  k_gu_mfma<<<dim3(22, 16, 16), 256, 0, stream>>>(tbh, wg, wu, cnt, offs, listTok, act);
  k_down_mfma<<<dim3(16, 16, 16), 256, 0, stream>>>(act, wd, cnt, offs, eo);
  k_final<<<TT, 256, 0, stream>>>(x2, eo, tokslot, topw, offs, out);
  k_aux<<<1, 1, 0, stream>>>(cnt, psum, out);
}

// Round 11
// 388.558 us; speedup vs baseline: 2.2907x; 1.1815x over previous
//
#include <hip/hip_runtime.h>

#define BB 2
#define SS 1024
#define DD 1024
#define HH 16
#define KVH 4
#define HDD 64
#define EE 16
#define II 1408
#define TT (BB*SS)
#define EPS_ 1e-6f

typedef unsigned short u16;
typedef __bf16 bf16x8 __attribute__((ext_vector_type(8)));
typedef _Float16 f16x8 __attribute__((ext_vector_type(8)));
typedef float f32x4 __attribute__((ext_vector_type(4)));

__device__ __forceinline__ float wred_sum(float v) {
#pragma unroll
  for (int o = 32; o > 0; o >>= 1) v += __shfl_xor(v, o);
  return v;
}

__device__ __forceinline__ u16 f2b(float f) {
  __bf16 h = (__bf16)f;
  return __builtin_bit_cast(u16, h);
}

__device__ __forceinline__ bf16x8 ld_frag(const u16* p) {
  return __builtin_bit_cast(bf16x8, *(const uint4*)p);
}
__device__ __forceinline__ f16x8 ldh(const u16* p) {
  return __builtin_bit_cast(f16x8, *(const uint4*)p);
}

// fp16 split-2 with scaled residual: v ~= h0 + h1 * 2^-11 (error ~2^-22)
__device__ __forceinline__ void split2h(float v, u16* o0, u16* o1) {
  _Float16 a = (_Float16)v;
  float fa = (float)a;
  _Float16 b = (_Float16)((v - fa) * 2048.0f);
  *o0 = __builtin_bit_cast(u16, a);
  *o1 = __builtin_bit_cast(u16, b);
}

#define CVAL(fm, nf, r) (accm[fm][nf][r] + accx[fm][nf][r] * 4.8828125e-4f)

// ---------------- rmsnorm with split-2 fp16 output ----------------
__global__ __launch_bounds__(256) void k_rmsnorm_split2(const float* __restrict__ x,
    const float* __restrict__ w, u16* __restrict__ o0, u16* __restrict__ o1) {
  int row = blockIdx.x, tid = threadIdx.x;
  float4 v = ((const float4*)(x + (size_t)row * DD))[tid];
  float ss = v.x*v.x + v.y*v.y + v.z*v.z + v.w*v.w;
  ss = wred_sum(ss);
  __shared__ float red[4];
  if ((tid & 63) == 0) red[tid >> 6] = ss;
  __syncthreads();
  float tot = red[0] + red[1] + red[2] + red[3];
  float sc = rsqrtf(tot * (1.0f / DD) + EPS_);
  float4 wv = ((const float4*)w)[tid];
  float vals[4] = {v.x*sc*wv.x, v.y*sc*wv.y, v.z*sc*wv.z, v.w*sc*wv.w};
  ushort4 s0, s1;
  split2h(vals[0], &s0.x, &s1.x);
  split2h(vals[1], &s0.y, &s1.y);
  split2h(vals[2], &s0.z, &s1.z);
  split2h(vals[3], &s0.w, &s1.w);
  size_t base = (size_t)row * DD + tid * 4;
  *(ushort4*)&o0[base] = s0;
  *(ushort4*)&o1[base] = s1;
}

// ---------------- transpose + split2: W[K][N] fp32 -> WT{0,1}[N][K] fp16 ----------------
__global__ __launch_bounds__(256) void k_transpose_split2(const float* __restrict__ Wm,
    u16* __restrict__ T0, u16* __restrict__ T1, int K, int N) {
  int n0 = blockIdx.x * 64, k0 = blockIdx.y * 64;
  __shared__ float tile[64][65];
  int tc = threadIdx.x & 15, tr = threadIdx.x >> 4;
#pragma unroll
  for (int kk = 0; kk < 64; kk += 16) {
    float4 v = *(const float4*)&Wm[(size_t)(k0 + kk + tr) * N + n0 + tc * 4];
    tile[kk + tr][tc*4+0] = v.x; tile[kk + tr][tc*4+1] = v.y;
    tile[kk + tr][tc*4+2] = v.z; tile[kk + tr][tc*4+3] = v.w;
  }
  __syncthreads();
#pragma unroll
  for (int nn = 0; nn < 64; nn += 16) {
    int n = nn + tr;
    ushort4 s0, s1;
    split2h(tile[tc*4+0][n], &s0.x, &s1.x);
    split2h(tile[tc*4+1][n], &s0.y, &s1.y);
    split2h(tile[tc*4+2][n], &s0.z, &s1.z);
    split2h(tile[tc*4+3][n], &s0.w, &s1.w);
    size_t base = (size_t)(n0 + n) * K + k0 + tc * 4;
    *(ushort4*)&T0[base] = s0;
    *(ushort4*)&T1[base] = s1;
  }
}

// ======== split-2 fp16 GEMM body, gu skeleton: 128x64 tile, BK=32, pitch 56 ========
// Staging: 6 uint4/thread live only between load and LDS write (no barrier-crossing regs).
// LDS = (128+128+64+64)*56*2B = 42 KB -> 3 blocks/CU. acc 64 VGPR + transient frags.
#define S2GEMM_BODY(a0p, a1p, b0p, b1p, KTOT) \
  __shared__ __align__(16) u16 A0s[128][56], A1s[128][56]; \
  __shared__ __align__(16) u16 B0s[64][56], B1s[64][56]; \
  int tid = threadIdx.x, lane = tid & 63, w = tid >> 6; \
  int wm = (w & 1) * 64, wn = (w >> 1) * 32; \
  int lr = lane & 15, lk = (lane >> 4) * 8; \
  int br = tid >> 2, bc = (tid & 3) * 8; \
  f32x4 accm[4][2] = {}, accx[4][2] = {}; \
  for (int k0 = 0; k0 < (KTOT); k0 += 32) { \
    uint4 a0v0 = *(const uint4*)((a0p) + (size_t)br * (KTOT) + k0 + bc); \
    uint4 a0v1 = *(const uint4*)((a0p) + (size_t)(64 + br) * (KTOT) + k0 + bc); \
    uint4 a1v0 = *(const uint4*)((a1p) + (size_t)br * (KTOT) + k0 + bc); \
    uint4 a1v1 = *(const uint4*)((a1p) + (size_t)(64 + br) * (KTOT) + k0 + bc); \
    uint4 b0v = *(const uint4*)((b0p) + (size_t)br * (KTOT) + k0 + bc); \
    uint4 b1v = *(const uint4*)((b1p) + (size_t)br * (KTOT) + k0 + bc); \
    __syncthreads(); \
    *(uint4*)&A0s[br][bc] = a0v0; \
    *(uint4*)&A0s[64 + br][bc] = a0v1; \
    *(uint4*)&A1s[br][bc] = a1v0; \
    *(uint4*)&A1s[64 + br][bc] = a1v1; \
    *(uint4*)&B0s[br][bc] = b0v; \
    *(uint4*)&B1s[br][bc] = b1v; \
    __syncthreads(); \
    f16x8 bq0[2], bq1[2]; \
    _Pragma("unroll") \
    for (int nf = 0; nf < 2; ++nf) { \
      bq0[nf] = ldh(&B0s[wn + nf*16 + lr][lk]); \
      bq1[nf] = ldh(&B1s[wn + nf*16 + lr][lk]); } \
    _Pragma("unroll") \
    for (int fm = 0; fm < 4; ++fm) { \
      f16x8 a0 = ldh(&A0s[wm + fm*16 + lr][lk]); \
      f16x8 a1 = ldh(&A1s[wm + fm*16 + lr][lk]); \
      _Pragma("unroll") \
      for (int nf = 0; nf < 2; ++nf) { \
        accm[fm][nf] = __builtin_amdgcn_mfma_f32_16x16x32_f16(a0, bq0[nf], accm[fm][nf], 0, 0, 0); \
        f32x4 cx = accx[fm][nf]; \
        cx = __builtin_amdgcn_mfma_f32_16x16x32_f16(a0, bq1[nf], cx, 0, 0, 0); \
        cx = __builtin_amdgcn_mfma_f32_16x16x32_f16(a1, bq0[nf], cx, 0, 0, 0); \
        accx[fm][nf] = cx; } } \
  }

// ---------------- fused QKV GEMM (split-2 fp16, gu skeleton) ----------------
__global__ __launch_bounds__(256) void k_qkv_s2(
    const u16* __restrict__ h0, const u16* __restrict__ h1,
    const u16* __restrict__ wqt0, const u16* __restrict__ wqt1,
    const u16* __restrict__ wkt0, const u16* __restrict__ wkt1,
    const u16* __restrict__ wvt0, const u16* __restrict__ wvt1,
    float* __restrict__ qb, float* __restrict__ kb, float* __restrict__ vb) {
  int nt = blockIdx.x, m0 = blockIdx.y * 128;
  const u16 *B0, *B1; float* Cm; int Nm, n0;
  if (nt < 16)      { B0 = wqt0; B1 = wqt1; Cm = qb; Nm = 1024; n0 = nt * 64; }
  else if (nt < 20) { B0 = wkt0; B1 = wkt1; Cm = kb; Nm = 256;  n0 = (nt - 16) * 64; }
  else              { B0 = wvt0; B1 = wvt1; Cm = vb; Nm = 256;  n0 = (nt - 20) * 64; }
  const u16* a0p = h0 + (size_t)m0 * 1024;
  const u16* a1p = h1 + (size_t)m0 * 1024;
  const u16* b0p = B0 + (size_t)n0 * 1024;
  const u16* b1p = B1 + (size_t)n0 * 1024;
  S2GEMM_BODY(a0p, a1p, b0p, b1p, 1024)
#pragma unroll
  for (int fm = 0; fm < 4; ++fm)
#pragma unroll
    for (int nf = 0; nf < 2; ++nf)
#pragma unroll
      for (int r = 0; r < 4; ++r) {
        int row = m0 + wm + fm*16 + (lane >> 4) * 4 + r;
        Cm[(size_t)row * Nm + n0 + wn + nf*16 + lr] = CVAL(fm, nf, r);
      }
}

// ---------------- per-head q/k rmsnorm + rope -> split-2 fp16 planes ----------------
__global__ __launch_bounds__(256) void k_qknorm_rope_split2(
    const float* __restrict__ qb, const float* __restrict__ kb,
    const float* __restrict__ qnw, const float* __restrict__ knw,
    const float* __restrict__ cosb, const float* __restrict__ sinb,
    u16* __restrict__ q0a, u16* __restrict__ q1a,
    u16* __restrict__ k0a, u16* __restrict__ k1a) {
  int tok = blockIdx.x, grp = blockIdx.y;
  int wv = threadIdx.x >> 6, d = threadIdx.x & 63;
  int s = tok & (SS - 1);
  const float* ptr; const float* wn;
  if (grp < 4) { ptr = qb + (size_t)tok * 1024 + (grp * 4 + wv) * 64; wn = qnw; }
  else         { ptr = kb + (size_t)tok * 256 + wv * 64;              wn = knw; }
  float v = ptr[d];
  float ssum = wred_sum(v * v);
  float rms = rsqrtf(ssum * (1.0f / 64.0f) + EPS_);
  float nv = v * rms * wn[d];
  float pn = __shfl_xor(nv, 32);
  float rot = (d < 32) ? -pn : pn;
  float val = nv * cosb[s * 64 + d] + rot * sinb[s * 64 + d];
  u16 a, b;
  split2h(val, &a, &b);
  if (grp < 4) {
    size_t idx = (size_t)tok * 1024 + (grp * 4 + wv) * 64 + d;
    q0a[idx] = a; q1a[idx] = b;
  } else {
    size_t idx = (size_t)tok * 256 + wv * 64 + d;
    k0a[idx] = a; k1a[idx] = b;
  }
}

// ---------------- v transpose + split2 ----------------
__global__ __launch_bounds__(256) void k_splitv2(const float* __restrict__ vb,
    u16* __restrict__ t0, u16* __restrict__ t1) {
  int k0 = blockIdx.x * 64, bkv = blockIdx.y;
  int b = bkv >> 2, kv = bkv & 3;
  __shared__ float tile[64][65];
  int tc = threadIdx.x & 15, tr = threadIdx.x >> 4;
#pragma unroll
  for (int kk = 0; kk < 64; kk += 16) {
    float4 v = *(const float4*)&vb[(size_t)(b * 1024 + k0 + kk + tr) * 256 + kv * 64 + tc * 4];
    tile[kk + tr][tc*4+0] = v.x; tile[kk + tr][tc*4+1] = v.y;
    tile[kk + tr][tc*4+2] = v.z; tile[kk + tr][tc*4+3] = v.w;
  }
  __syncthreads();
#pragma unroll
  for (int dd = 0; dd < 64; dd += 16) {
    int d = dd + tr;
    ushort4 s0, s1;
    split2h(tile[tc*4+0][d], &s0.x, &s1.x);
    split2h(tile[tc*4+1][d], &s0.y, &s1.y);
    split2h(tile[tc*4+2][d], &s0.z, &s1.z);
    split2h(tile[tc*4+3][d], &s0.w, &s1.w);
    size_t base = (size_t)(bkv * 64 + d) * 1024 + k0 + tc * 4;
    *(ushort4*)&t0[base] = s0;
    *(ushort4*)&t1[base] = s1;
  }
}

// ---------------- flash attention (r9/r10) -> split-2 attn planes ----------------
__global__ __launch_bounds__(256) void k_flash(
    const u16* __restrict__ qs0, const u16* __restrict__ qs1,
    const u16* __restrict__ ks0, const u16* __restrict__ ks1,
    const u16* __restrict__ vt0, const u16* __restrict__ vt1,
    u16* __restrict__ at0, u16* __restrict__ at1) {
  int pair = blockIdx.x, bh = blockIdx.y;
  int b = bh >> 4, hh = bh & 15, kv = hh >> 2;
  int bkv = b * 4 + kv;
  __shared__ __align__(16) u16 Qs0[64*72], Qs1[64*72];
  __shared__ __align__(16) u16 Ks0[64*72], Ks1[64*72];
  __shared__ __align__(16) u16 Vs0[64*72], Vs1[64*72];
  __shared__ __align__(16) u16 Ps0[64*72], Ps1[64*72];
  int tid = threadIdx.x, lane = tid & 63, w = tid >> 6;
  int lr = lane & 15, g = lane >> 4;
  int wq0 = w * 16;
  const float c2 = 4.8828125e-4f;
#pragma unroll 1
  for (int half = 0; half < 2; ++half) {
    int qt = (half == 0) ? pair : (15 - pair);
    int q0 = qt * 64;
#pragma unroll
    for (int i = 0; i < 2; ++i) {
      int idx = tid + i * 256, r = idx >> 3, c = (idx & 7) * 8;
      size_t off = (size_t)(b * 1024 + q0 + r) * 1024 + hh * 64 + c;
      *(uint4*)&Qs0[r*72 + c] = *(const uint4*)(qs0 + off);
      *(uint4*)&Qs1[r*72 + c] = *(const uint4*)(qs1 + off);
    }
    f32x4 Om[4] = {}, Ox[4] = {};
    float mrow[4] = {-3.4e38f, -3.4e38f, -3.4e38f, -3.4e38f};
    float lrow[4] = {};
    __syncthreads();
    for (int kt = 0; kt <= qt; ++kt) {
      int k0 = kt * 64;
#pragma unroll
      for (int i = 0; i < 2; ++i) {
        int idx = tid + i * 256, r = idx >> 3, c = (idx & 7) * 8;
        size_t koff = (size_t)(b * 1024 + k0 + r) * 256 + kv * 64 + c;
        *(uint4*)&Ks0[r*72 + c] = *(const uint4*)(ks0 + koff);
        *(uint4*)&Ks1[r*72 + c] = *(const uint4*)(ks1 + koff);
        size_t voff = (size_t)(bkv * 64 + r) * 1024 + k0 + c;
        *(uint4*)&Vs0[r*72 + c] = *(const uint4*)(vt0 + voff);
        *(uint4*)&Vs1[r*72 + c] = *(const uint4*)(vt1 + voff);
      }
      __syncthreads();
      f32x4 Sm[4] = {}, Sx[4] = {};
#pragma unroll
      for (int ks = 0; ks < 2; ++ks) {
        f16x8 a0 = ldh(&Qs0[(wq0 + lr)*72 + ks*32 + g*8]);
        f16x8 a1 = ldh(&Qs1[(wq0 + lr)*72 + ks*32 + g*8]);
#pragma unroll
        for (int nt = 0; nt < 4; ++nt) {
          f16x8 b0 = ldh(&Ks0[(nt*16 + lr)*72 + ks*32 + g*8]);
          f16x8 b1 = ldh(&Ks1[(nt*16 + lr)*72 + ks*32 + g*8]);
          Sm[nt] = __builtin_amdgcn_mfma_f32_16x16x32_f16(a0, b0, Sm[nt], 0, 0, 0);
          f32x4 cx = Sx[nt];
          cx = __builtin_amdgcn_mfma_f32_16x16x32_f16(a0, b1, cx, 0, 0, 0);
          cx = __builtin_amdgcn_mfma_f32_16x16x32_f16(a1, b0, cx, 0, 0, 0);
          Sx[nt] = cx;
        }
      }
      bool diag = (kt == qt);
      float pvv[4][4], scl[4];
#pragma unroll
      for (int r = 0; r < 4; ++r) {
        int rowloc = wq0 + g*4 + r;
        float rm = -3.4e38f;
#pragma unroll
        for (int nt = 0; nt < 4; ++nt) {
          float s = (Sm[nt][r] + Sx[nt][r] * c2) * 0.125f;
          bool valid = (!diag) || (nt*16 + lr <= rowloc);
          s = valid ? s : -3.4e38f;
          pvv[r][nt] = s;
          rm = fmaxf(rm, s);
        }
#pragma unroll
        for (int o = 1; o < 16; o <<= 1) rm = fmaxf(rm, __shfl_xor(rm, o));
        float mn = fmaxf(mrow[r], rm);
        scl[r] = __expf(mrow[r] - mn);
        mrow[r] = mn;
        float rs = 0.f;
#pragma unroll
        for (int nt = 0; nt < 4; ++nt) {
          float p = (pvv[r][nt] > -3.0e38f) ? __expf(pvv[r][nt] - mn) : 0.f;
          pvv[r][nt] = p;
          rs += p;
        }
#pragma unroll
        for (int o = 1; o < 16; o <<= 1) rs += __shfl_xor(rs, o);
        lrow[r] = lrow[r] * scl[r] + rs;
      }
#pragma unroll
      for (int nt = 0; nt < 4; ++nt)
#pragma unroll
        for (int r = 0; r < 4; ++r) { Om[nt][r] *= scl[r]; Ox[nt][r] *= scl[r]; }
#pragma unroll
      for (int r = 0; r < 4; ++r)
#pragma unroll
        for (int nt = 0; nt < 4; ++nt) {
          u16 pa, pb;
          split2h(pvv[r][nt], &pa, &pb);
          int addr = (wq0 + g*4 + r)*72 + nt*16 + lr;
          Ps0[addr] = pa; Ps1[addr] = pb;
        }
#pragma unroll
      for (int ks = 0; ks < 2; ++ks) {
        f16x8 p0 = ldh(&Ps0[(wq0 + lr)*72 + ks*32 + g*8]);
        f16x8 p1 = ldh(&Ps1[(wq0 + lr)*72 + ks*32 + g*8]);
#pragma unroll
        for (int nt = 0; nt < 4; ++nt) {
          f16x8 v0 = ldh(&Vs0[(nt*16 + lr)*72 + ks*32 + g*8]);
          f16x8 v1 = ldh(&Vs1[(nt*16 + lr)*72 + ks*32 + g*8]);
          Om[nt] = __builtin_amdgcn_mfma_f32_16x16x32_f16(p0, v0, Om[nt], 0, 0, 0);
          f32x4 cx = Ox[nt];
          cx = __builtin_amdgcn_mfma_f32_16x16x32_f16(p0, v1, cx, 0, 0, 0);
          cx = __builtin_amdgcn_mfma_f32_16x16x32_f16(p1, v0, cx, 0, 0, 0);
          Ox[nt] = cx;
        }
      }
      __syncthreads();
    }
#pragma unroll
    for (int nt = 0; nt < 4; ++nt)
#pragma unroll
      for (int r = 0; r < 4; ++r) {
        float val = (Om[nt][r] + Ox[nt][r] * c2) / lrow[r];
        u16 sa, sb;
        split2h(val, &sa, &sb);
        size_t idx = (size_t)(b * 1024 + q0 + wq0 + g*4 + r) * 1024 + hh * 64 + nt*16 + lr;
        at0[idx] = sa; at1[idx] = sb;
      }
    __syncthreads();
  }
}

// ---------------- Wo GEMM + residual (split-2 fp16, gu skeleton) ----------------
__global__ __launch_bounds__(256) void k_wo_s2(
    const u16* __restrict__ at0, const u16* __restrict__ at1,
    const u16* __restrict__ wot0, const u16* __restrict__ wot1,
    const float* __restrict__ x, float* __restrict__ x2) {
  int n0 = blockIdx.x * 64, m0 = blockIdx.y * 128;
  const u16* a0p = at0 + (size_t)m0 * 1024;
  const u16* a1p = at1 + (size_t)m0 * 1024;
  const u16* b0p = wot0 + (size_t)n0 * 1024;
  const u16* b1p = wot1 + (size_t)n0 * 1024;
  S2GEMM_BODY(a0p, a1p, b0p, b1p, 1024)
#pragma unroll
  for (int fm = 0; fm < 4; ++fm)
#pragma unroll
    for (int nf = 0; nf < 2; ++nf)
#pragma unroll
      for (int r = 0; r < 4; ++r) {
        int row = m0 + wm + fm*16 + (lane >> 4) * 4 + r;
        int col = n0 + wn + nf*16 + lr;
        x2[(size_t)row * 1024 + col] = CVAL(fm, nf, r) + x[(size_t)row * 1024 + col];
      }
}

// ---------------- fused: rmsnorm(x2) -> tbh(bf16) + router logits ----------------
__global__ __launch_bounds__(256) void k_rmsnorm_logits(const float* __restrict__ x2,
    const float* __restrict__ w, const float* __restrict__ rw,
    u16* __restrict__ tbh, float* __restrict__ logits) {
  int row = blockIdx.x, tid = threadIdx.x;
  __shared__ __align__(16) float tl[1024];
  __shared__ float part[16][16];
  __shared__ float red[4];
  float4 v = ((const float4*)(x2 + (size_t)row * DD))[tid];
  float ss = v.x*v.x + v.y*v.y + v.z*v.z + v.w*v.w;
  ss = wred_sum(ss);
  if ((tid & 63) == 0) red[tid >> 6] = ss;
  __syncthreads();
  float tot = red[0] + red[1] + red[2] + red[3];
  float sc = rsqrtf(tot * (1.0f / DD) + EPS_);
  float4 wv = ((const float4*)w)[tid];
  float4 o = make_float4(v.x*sc*wv.x, v.y*sc*wv.y, v.z*sc*wv.z, v.w*sc*wv.w);
  ((float4*)tl)[tid] = o;
  ushort4 hb = make_ushort4(f2b(o.x), f2b(o.y), f2b(o.z), f2b(o.w));
  *(ushort4*)&tbh[(size_t)row * DD + tid * 4] = hb;
  __syncthreads();
  int e = tid & 15, ch = tid >> 4;
  float p = 0.f;
#pragma unroll 8
  for (int j = 0; j < 64; ++j) p = fmaf(tl[ch * 64 + j], rw[(ch * 64 + j) * EE + e], p);
  part[ch][e] = p;
  __syncthreads();
  if (tid < 16) {
    float s = 0.f;
#pragma unroll
    for (int c = 0; c < 16; ++c) s += part[c][tid];
    logits[(size_t)row * EE + tid] = s;
  }
}

// ---------------- route ----------------
__global__ __launch_bounds__(256) void k_route(const float* __restrict__ logits,
    int* __restrict__ cnt, int* __restrict__ listTok, int* __restrict__ tokslot,
    float* __restrict__ topw, float* __restrict__ psum) {
  int tid = threadIdx.x;
  int tok = blockIdx.x * 256 + tid;
  __shared__ int lcnt[16], gbase[16];
  __shared__ float lps[16];
  if (tid < 16) { lcnt[tid] = 0; lps[tid] = 0.f; }
  __syncthreads();
  float pr[16];
#pragma unroll
  for (int g = 0; g < 4; ++g) {
    float4 v = *(const float4*)&logits[(size_t)tok * EE + g * 4];
    pr[g*4+0] = v.x; pr[g*4+1] = v.y; pr[g*4+2] = v.z; pr[g*4+3] = v.w;
  }
  float mx = pr[0];
#pragma unroll
  for (int i = 1; i < 16; ++i) mx = fmaxf(mx, pr[i]);
  float s = 0.f;
#pragma unroll
  for (int i = 0; i < 16; ++i) { pr[i] = __expf(pr[i] - mx); s += pr[i]; }
  float inv = 1.0f / s;
#pragma unroll
  for (int i = 0; i < 16; ++i) pr[i] *= inv;
  int i1 = 0; float v1 = pr[0];
#pragma unroll
  for (int i = 1; i < 16; ++i) if (pr[i] > v1) { v1 = pr[i]; i1 = i; }
  int i2 = -1; float v2 = -1.f;
#pragma unroll
  for (int i = 0; i < 16; ++i) if (i != i1 && pr[i] > v2) { v2 = pr[i]; i2 = i; }
  float wsum = v1 + v2;
  int lp1 = atomicAdd(&lcnt[i1], 1);
  int lp2 = atomicAdd(&lcnt[i2], 1);
#pragma unroll
  for (int e = 0; e < 16; ++e) {
    float v = wred_sum(pr[e]);
    if ((tid & 63) == 0) atomicAdd(&lps[e], v);
  }
  __syncthreads();
  if (tid < 16) {
    gbase[tid] = atomicAdd(&cnt[tid], lcnt[tid]);
    atomicAdd(&psum[tid], lps[tid]);
  }
  __syncthreads();
  int p1 = gbase[i1] + lp1, p2 = gbase[i2] + lp2;
  listTok[i1 * 2048 + p1] = tok;
  listTok[i2 * 2048 + p2] = tok;
  tokslot[tok * 2 + 0] = i1 * 2048 + p1;
  tokslot[tok * 2 + 1] = i2 * 2048 + p2;
  topw[tok * 2 + 0] = v1 / wsum;
  topw[tok * 2 + 1] = v2 / wsum;
}

__global__ void k_zero(int* cnt, float* psum) {
  int t = threadIdx.x;
  if (t < 16) { cnt[t] = 0; psum[t] = 0.f; }
}

__global__ void k_prefix(const int* __restrict__ cnt, int* __restrict__ offs) {
  if (threadIdx.x == 0) {
    int s = 0;
    for (int e = 0; e < 16; ++e) { offs[e] = s; s += cnt[e]; }
  }
}

// ---------------- MoE gate/up MFMA (r2 verbatim — best measured) ----------------
__global__ __launch_bounds__(256) void k_gu_mfma(const u16* __restrict__ tbh,
    const float* __restrict__ wg, const float* __restrict__ wu,
    const int* __restrict__ cnt, const int* __restrict__ offs,
    const int* __restrict__ listTok, u16* __restrict__ act) {
  int e = blockIdx.z;
  int ce = cnt[e];
  int m0 = blockIdx.y * 128;
  if (m0 >= ce) return;
  int n0 = blockIdx.x * 64;
  __shared__ __align__(16) u16 Ah[128][56];
  __shared__ __align__(16) u16 Gh[64][56];
  __shared__ __align__(16) u16 Uh[64][56];
  __shared__ int rows[128];
  int tid = threadIdx.x;
  if (tid < 128) {
    int m = m0 + tid;
    rows[tid] = listTok[e * 2048 + (m < ce ? m : ce - 1)];
  }
  __syncthreads();
  int s_arow = tid >> 1, s_acol = (tid & 1) * 16;
  int s_nc = (tid & 31) * 2, s_kg = (tid >> 5) * 4;
  const float* wge = wg + (size_t)e * DD * II + n0;
  const float* wue = wu + (size_t)e * DD * II + n0;
  const u16* ap = tbh + (size_t)rows[s_arow] * DD + s_acol;
  int lane = tid & 63, w = tid >> 6;
  int wm = (w & 1) * 64, wn = (w >> 1) * 32;
  int lr = lane & 15, lk = (lane >> 4) * 8;
  f32x4 accg[4][2] = {};
  f32x4 accu[4][2] = {};
  for (int k0 = 0; k0 < DD; k0 += 32) {
    uint4 av0 = *(const uint4*)(ap + k0);
    uint4 av1 = *(const uint4*)(ap + k0 + 8);
    float2 g0 = *(const float2*)&wge[(size_t)(k0 + s_kg + 0) * II + s_nc];
    float2 g1 = *(const float2*)&wge[(size_t)(k0 + s_kg + 1) * II + s_nc];
    float2 g2 = *(const float2*)&wge[(size_t)(k0 + s_kg + 2) * II + s_nc];
    float2 g3 = *(const float2*)&wge[(size_t)(k0 + s_kg + 3) * II + s_nc];
    float2 u0 = *(const float2*)&wue[(size_t)(k0 + s_kg + 0) * II + s_nc];
    float2 u1 = *(const float2*)&wue[(size_t)(k0 + s_kg + 1) * II + s_nc];
    float2 u2 = *(const float2*)&wue[(size_t)(k0 + s_kg + 2) * II + s_nc];
    float2 u3 = *(const float2*)&wue[(size_t)(k0 + s_kg + 3) * II + s_nc];
    *(uint4*)&Ah[s_arow][s_acol]     = av0;
    *(uint4*)&Ah[s_arow][s_acol + 8] = av1;
    *(ushort4*)&Gh[s_nc][s_kg]     = make_ushort4(f2b(g0.x), f2b(g1.x), f2b(g2.x), f2b(g3.x));
    *(ushort4*)&Gh[s_nc + 1][s_kg] = make_ushort4(f2b(g0.y), f2b(g1.y), f2b(g2.y), f2b(g3.y));
    *(ushort4*)&Uh[s_nc][s_kg]     = make_ushort4(f2b(u0.x), f2b(u1.x), f2b(u2.x), f2b(u3.x));
    *(ushort4*)&Uh[s_nc + 1][s_kg] = make_ushort4(f2b(u0.y), f2b(u1.y), f2b(u2.y), f2b(u3.y));
    __syncthreads();
    bf16x8 af[4];
#pragma unroll
    for (int fm = 0; fm < 4; ++fm) af[fm] = ld_frag(&Ah[wm + fm*16 + lr][lk]);
#pragma unroll
    for (int nf = 0; nf < 2; ++nf) {
      bf16x8 bg = ld_frag(&Gh[wn + nf*16 + lr][lk]);
      bf16x8 bu = ld_frag(&Uh[wn + nf*16 + lr][lk]);
#pragma unroll
      for (int fm = 0; fm < 4; ++fm) {
        accg[fm][nf] = __builtin_amdgcn_mfma_f32_16x16x32_bf16(af[fm], bg, accg[fm][nf], 0, 0, 0);
        accu[fm][nf] = __builtin_amdgcn_mfma_f32_16x16x32_bf16(af[fm], bu, accu[fm][nf], 0, 0, 0);
      }
    }
    __syncthreads();
  }
  int ob = offs[e];
#pragma unroll
  for (int fm = 0; fm < 4; ++fm)
#pragma unroll
    for (int nf = 0; nf < 2; ++nf)
#pragma unroll
      for (int r = 0; r < 4; ++r) {
        int m = m0 + wm + fm*16 + (lane >> 4) * 4 + r;
        if (m < ce) {
          float g = accg[fm][nf][r], u = accu[fm][nf][r];
          float sv = (g / (1.f + __expf(-g))) * u;
          act[(size_t)(ob + m) * II + n0 + wn + nf*16 + (lane & 15)] = f2b(sv);
        }
      }
}

// ---------------- MoE down MFMA (r2 verbatim) ----------------
__global__ __launch_bounds__(256) void k_down_mfma(const u16* __restrict__ act,
    const float* __restrict__ wd, const int* __restrict__ cnt, const int* __restrict__ offs,
    float* __restrict__ eo) {
  int e = blockIdx.z;
  int ce = cnt[e];
  int m0 = blockIdx.y * 128;
  if (m0 >= ce) return;
  int n0 = blockIdx.x * 64;
  __shared__ __align__(16) u16 Ah[128][56];
  __shared__ __align__(16) u16 Bh[64][56];
  int tid = threadIdx.x;
  int ob = offs[e];
  int s_arow = tid >> 1, s_acol = (tid & 1) * 16;
  int s_nc = (tid & 31) * 2, s_kg = (tid >> 5) * 4;
  int mrow = m0 + s_arow; if (mrow >= ce) mrow = ce - 1;
  const u16* ap = act + (size_t)(ob + mrow) * II + s_acol;
  const float* wde = wd + (size_t)e * II * DD + n0;
  int lane = tid & 63, w = tid >> 6;
  int wm = (w & 1) * 64, wn = (w >> 1) * 32;
  int lr = lane & 15, lk = (lane >> 4) * 8;
  f32x4 acc[4][2] = {};
  for (int k0 = 0; k0 < II; k0 += 32) {
    uint4 av0 = *(const uint4*)(ap + k0);
    uint4 av1 = *(const uint4*)(ap + k0 + 8);
    float2 b0 = *(const float2*)&wde[(size_t)(k0 + s_kg + 0) * DD + s_nc];
    float2 b1 = *(const float2*)&wde[(size_t)(k0 + s_kg + 1) * DD + s_nc];
    float2 b2 = *(const float2*)&wde[(size_t)(k0 + s_kg + 2) * DD + s_nc];
    float2 b3 = *(const float2*)&wde[(size_t)(k0 + s_kg + 3) * DD + s_nc];
    *(uint4*)&Ah[s_arow][s_acol]     = av0;
    *(uint4*)&Ah[s_arow][s_acol + 8] = av1;
    *(ushort4*)&Bh[s_nc][s_kg]     = make_ushort4(f2b(b0.x), f2b(b1.x), f2b(b2.x), f2b(b3.x));
    *(ushort4*)&Bh[s_nc + 1][s_kg] = make_ushort4(f2b(b0.y), f2b(b1.y), f2b(b2.y), f2b(b3.y));
    __syncthreads();
    bf16x8 af[4];
#pragma unroll
    for (int fm = 0; fm < 4; ++fm) af[fm] = ld_frag(&Ah[wm + fm*16 + lr][lk]);
#pragma unroll
    for (int nf = 0; nf < 2; ++nf) {
      bf16x8 bb = ld_frag(&Bh[wn + nf*16 + lr][lk]);
#pragma unroll
      for (int fm = 0; fm < 4; ++fm)
        acc[fm][nf] = __builtin_amdgcn_mfma_f32_16x16x32_bf16(af[fm], bb, acc[fm][nf], 0, 0, 0);
    }
    __syncthreads();
  }
#pragma unroll
  for (int fm = 0; fm < 4; ++fm)
#pragma unroll
    for (int nf = 0; nf < 2; ++nf)
#pragma unroll
      for (int r = 0; r < 4; ++r) {
        int m = m0 + wm + fm*16 + (lane >> 4) * 4 + r;
        if (m < ce)
          eo[(size_t)(ob + m) * DD + n0 + wn + nf*16 + (lane & 15)] = acc[fm][nf][r];
      }
}

// ---------------- final combine ----------------
__global__ __launch_bounds__(256) void k_final(const float* __restrict__ x2,
    const float* __restrict__ eo, const int* __restrict__ tokslot,
    const float* __restrict__ topw, const int* __restrict__ offs, float* __restrict__ out) {
  int tok = blockIdx.x, tid = threadIdx.x;
  int c0 = tokslot[tok * 2], c1 = tokslot[tok * 2 + 1];
  int s0 = offs[c0 >> 11] + (c0 & 2047);
  int s1 = offs[c1 >> 11] + (c1 & 2047);
  float w0 = topw[tok * 2], w1 = topw[tok * 2 + 1];
  float4 a = ((const float4*)(x2 + (size_t)tok * DD))[tid];
  float4 e0 = ((const float4*)(eo + (size_t)s0 * DD))[tid];
  float4 e1 = ((const float4*)(eo + (size_t)s1 * DD))[tid];
  float4 o = make_float4(a.x + w0*e0.x + w1*e1.x, a.y + w0*e0.y + w1*e1.y,
                         a.z + w0*e0.z + w1*e1.z, a.w + w0*e0.w + w1*e1.w);
  ((float4*)(out + (size_t)tok * DD))[tid] = o;
}

__global__ void k_aux(const int* __restrict__ cnt, const float* __restrict__ psum,
                      float* __restrict__ out) {
  if (threadIdx.x == 0) {
    float a = 0.f;
    for (int e = 0; e < 16; ++e)
      a += ((float)cnt[e] * (1.0f / 4096.0f)) * (psum[e] * (1.0f / 2048.0f));
    out[(size_t)TT * DD] = 16.0f * a;
  }
}

extern "C" void kernel_launch(void* const* d_in, const int* in_sizes, int n_in,
                              void* d_out, int out_size, void* d_ws, size_t ws_size,
                              hipStream_t stream) {
  const float* x    = (const float*)d_in[0];
  const float* cosb = (const float*)d_in[1];
  const float* sinb = (const float*)d_in[2];
  const float* ln1w = (const float*)d_in[3];
  const float* wq   = (const float*)d_in[4];
  const float* wk   = (const float*)d_in[5];
  const float* wv   = (const float*)d_in[6];
  const float* wo   = (const float*)d_in[7];
  const float* qnw  = (const float*)d_in[8];
  const float* knw  = (const float*)d_in[9];
  const float* ln2w = (const float*)d_in[10];
  const float* rw   = (const float*)d_in[11];
  const float* wg   = (const float*)d_in[12];
  const float* wu   = (const float*)d_in[13];
  const float* wd   = (const float*)d_in[14];
  float* out = (float*)d_out;

  float* W = (float*)d_ws;
  int*   cnt     = (int*)W;
  int*   offs    = (int*)(W + 16);
  float* psum    = W + 32;
  int*   tokslot = (int*)(W + 64);
  float* topw    = W + 4160;
  int*   listTok = (int*)(W + 8256);
  float* logits  = W + 41024;
  size_t o = 81920;
#define ALLOC_F(name, n)   float* name = W + o; o += (n);
#define ALLOC_U16(name, n) u16* name = (u16*)(W + o); o += ((size_t)(n) + 1) / 2;
  ALLOC_U16(h0, 2097152) ALLOC_U16(h1, 2097152)
  ALLOC_F(qb, 2097152) ALLOC_F(kb, 524288) ALLOC_F(vb, 524288)
  ALLOC_U16(wqt0, 1048576) ALLOC_U16(wqt1, 1048576)
  ALLOC_U16(wkt0, 262144) ALLOC_U16(wkt1, 262144)
  ALLOC_U16(wvt0, 262144) ALLOC_U16(wvt1, 262144)
  ALLOC_U16(wot0, 1048576) ALLOC_U16(wot1, 1048576)
  ALLOC_U16(qs0, 2097152) ALLOC_U16(qs1, 2097152)
  ALLOC_U16(ks0, 524288) ALLOC_U16(ks1, 524288)
  ALLOC_U16(vt0, 524288) ALLOC_U16(vt1, 524288)
  ALLOC_U16(at0, 2097152) ALLOC_U16(at1, 2097152)
  ALLOC_F(x2, 2097152)
  ALLOC_U16(tbh, 2097152)
  ALLOC_U16(act, 5767168)
  ALLOC_F(eo, 4194304)
#undef ALLOC_F
#undef ALLOC_U16

  k_zero<<<1, 64, 0, stream>>>(cnt, psum);
  k_rmsnorm_split2<<<TT, 256, 0, stream>>>(x, ln1w, h0, h1);
  k_transpose_split2<<<dim3(16, 16), 256, 0, stream>>>(wq, wqt0, wqt1, 1024, 1024);
  k_transpose_split2<<<dim3(4, 16), 256, 0, stream>>>(wk, wkt0, wkt1, 1024, 256);
  k_transpose_split2<<<dim3(4, 16), 256, 0, stream>>>(wv, wvt0, wvt1, 1024, 256);
  k_transpose_split2<<<dim3(16, 16), 256, 0, stream>>>(wo, wot0, wot1, 1024, 1024);
  k_qkv_s2<<<dim3(24, 16), 256, 0, stream>>>(h0, h1,
      wqt0, wqt1, wkt0, wkt1, wvt0, wvt1, qb, kb, vb);
  k_qknorm_rope_split2<<<dim3(TT, 5), 256, 0, stream>>>(qb, kb, qnw, knw, cosb, sinb,
      qs0, qs1, ks0, ks1);
  k_splitv2<<<dim3(16, 8), 256, 0, stream>>>(vb, vt0, vt1);
  k_flash<<<dim3(8, 32), 256, 0, stream>>>(qs0, qs1, ks0, ks1, vt0, vt1, at0, at1);
  k_wo_s2<<<dim3(16, 16), 256, 0, stream>>>(at0, at1, wot0, wot1, x, x2);
  k_rmsnorm_logits<<<TT, 256, 0, stream>>>(x2, ln2w, rw, tbh, logits);
  k_route<<<TT / 256, 256, 0, stream>>>(logits, cnt, listTok, tokslot, topw, psum);
  k_prefix<<<1, 1, 0, stream>>>(cnt, offs);
  k_gu_mfma<<<dim3(22, 16, 16), 256, 0, stream>>>(tbh, wg, wu, cnt, offs, listTok, act);
  k_down_mfma<<<dim3(16, 16, 16), 256, 0, stream>>>(act, wd, cnt, offs, eo);
  k_final<<<TT, 256, 0, stream>>>(x2, eo, tokslot, topw, offs, out);
  k_aux<<<1, 1, 0, stream>>>(cnt, psum, out);
}